// Round 10
// baseline (1580.566 us; speedup 1.0000x reference)
//
#include <hip/hip_runtime.h>
#include <math.h>

// ---------------- constants ----------------
static constexpr int kB = 128;
static constexpr int kT = 50;

// ---------- packed transpose [N][O][C] -> [N][C][O] + afeat zero-fill ----------
struct TDesc { const float* src; float* dst; int O; int C; int total; };
struct TPack { TDesc d[15]; };
__global__ void k_transpose_pack(TPack p, float* __restrict__ za) {
    if (blockIdx.y == 15) {   // zero afeat (196608 floats, atomicAdd target)
        for (int i = blockIdx.x * 256 + threadIdx.x; i < 196608; i += 76800)
            za[i] = 0.f;
        return;
    }
    TDesc t = p.d[blockIdx.y];
    int idx = blockIdx.x * 256 + threadIdx.x;
    if (idx >= t.total) return;
    int o = idx % t.O; int r = idx / t.O; int c = r % t.C; int n = r / t.C;
    t.dst[idx] = t.src[((size_t)n * t.O + o) * t.C + c];
}

// ---------- embedding lookup + input-side GRU GEMM, 8 rows/block ----------
__global__ void __launch_bounds__(320) k_gi(const int* __restrict__ tokens,
        const float* __restrict__ emb, const float* __restrict__ w_ih,
        const float* __restrict__ b_ih, float* __restrict__ GI) {
    int r0 = blockIdx.x * 8;
    int tid = threadIdx.x;
    __shared__ float er[8][200];
    for (int e = tid; e < 1600; e += 320) {
        int r = e / 200, c = e - r * 200;
        er[r][c] = emb[(size_t)tokens[r0 + r] * 200 + c];
    }
    __syncthreads();
    if (tid < 300) {
        float acc[8];
        float bv = b_ih[tid];
        #pragma unroll
        for (int r = 0; r < 8; ++r) acc[r] = bv;
        for (int k4 = 0; k4 < 50; ++k4) {
            float4 w4 = *(const float4*)(w_ih + (size_t)tid * 200 + k4 * 4);
            #pragma unroll
            for (int r = 0; r < 8; ++r) {
                float4 x4 = *(const float4*)&er[r][k4 * 4];
                acc[r] += w4.x * x4.x + w4.y * x4.y + w4.z * x4.z + w4.w * x4.w;
            }
        }
        #pragma unroll
        for (int r = 0; r < 8; ++r)
            GI[(size_t)(r0 + r) * 300 + tid] = acc[r];
    }
}

// ---------- FAT: gru (blocks 0..127, latency-bound) + stem (blocks 128..) ----------
// gru overlaps the stem's large grid instead of running serially after it.
// gru adapted to 256 threads: rows 0..255 by tid, rows 256..299 by tid<44;
// w_hh read from global each step (L1/L2-cached) to keep fat-kernel VGPR low.
__global__ void __launch_bounds__(256) k_fat_stem_gru(
    const float* __restrict__ mt, const float* __restrict__ mf,
    const float* __restrict__ mc,
    const float* __restrict__ w1a, const float* __restrict__ b1a,
    const float* __restrict__ g1a, const float* __restrict__ be1a,
    const float* __restrict__ m1a, const float* __restrict__ v1a,
    const float* __restrict__ w1b, const float* __restrict__ b1b,
    const float* __restrict__ g1b, const float* __restrict__ be1b,
    const float* __restrict__ m1b, const float* __restrict__ v1b,
    float* __restrict__ out, int total,
    const float* __restrict__ GI, const float* __restrict__ w_hh,
    const float* __restrict__ b_hh, float* __restrict__ outs) {
    if (blockIdx.x < 128) {
        // ================= gru path =================
        const int b = blockIdx.x, tid = threadIdx.x;
        __shared__ float hs[100];
        __shared__ float gH[300];
        const float bias0 = b_hh[tid];                       // row tid (tid<256<300)
        const float bias1 = (tid < 44) ? b_hh[256 + tid] : 0.f;
        if (tid < 100) hs[tid] = 0.f;
        __syncthreads();
        for (int t = 0; t < kT; ++t) {
            {
                float gh = bias0;
                const float* wr = w_hh + (size_t)tid * 100;
                #pragma unroll
                for (int k4 = 0; k4 < 25; ++k4) {
                    float4 w4 = *(const float4*)(wr + k4 * 4);
                    float4 h4 = *(const float4*)&hs[k4 * 4];
                    gh += w4.x * h4.x + w4.y * h4.y + w4.z * h4.z + w4.w * h4.w;
                }
                gH[tid] = gh;
            }
            if (tid < 44) {
                float gh = bias1;
                const float* wr = w_hh + (size_t)(256 + tid) * 100;
                #pragma unroll
                for (int k4 = 0; k4 < 25; ++k4) {
                    float4 w4 = *(const float4*)(wr + k4 * 4);
                    float4 h4 = *(const float4*)&hs[k4 * 4];
                    gh += w4.x * h4.x + w4.y * h4.y + w4.z * h4.z + w4.w * h4.w;
                }
                gH[256 + tid] = gh;
            }
            __syncthreads();
            if (tid < 100) {
                const float* gi = GI + ((size_t)b * kT + t) * 300;
                float r = 1.f / (1.f + expf(-(gi[tid] + gH[tid])));
                float z = 1.f / (1.f + expf(-(gi[100 + tid] + gH[100 + tid])));
                float nn = tanhf(gi[200 + tid] + r * gH[200 + tid]);
                float h2 = (1.f - z) * nn + z * hs[tid];
                hs[tid] = h2;
                outs[((size_t)b * kT + t) * 100 + tid] = h2;
            }
            __syncthreads();
        }
        return;
    }
    // ================= stem path =================
    int idx = (blockIdx.x - 128) * 256 + threadIdx.x;
    if (idx >= total) return;
    int ox = idx % 156; int t = idx / 156;
    int oy = t % 25; t /= 25;
    int ch = t % 24; int b = t / 24;
    int grp = ch >> 3, c = ch & 7;
    const float* src; int Hc, Wc;
    const float *wb, *cb, *g, *be, *m, *v;
    if (grp == 0) { src = mt; Hc = 196; Wc = 39; wb = w1a + c * 10;
                    cb = b1a; g = g1a; be = be1a; m = m1a; v = v1a; }
    else          { src = (grp == 1 ? mf : mc); Hc = 199; Wc = 35; wb = w1b + c * 12;
                    cb = b1b; g = g1b; be = be1b; m = m1b; v = v1b; }
    float s = g[c] * rsqrtf(v[c] + 1e-5f);
    float bias = (cb[c] - m[c]) * s + be[c];
    float sy = (oy + 0.5f) * ((float)Hc / 25.f) - 0.5f;
    float sx = (ox + 0.5f) * ((float)Wc / 156.f) - 0.5f;
    float fy0 = floorf(sy), fx0 = floorf(sx);
    float fy = sy - fy0, fx = sx - fx0;
    int y0 = (int)fy0, x0 = (int)fx0;
    int y0c = min(max(y0, 0), Hc - 1), y1c = min(max(y0 + 1, 0), Hc - 1);
    int x0c = min(max(x0, 0), Wc - 1), x1c = min(max(x0 + 1, 0), Wc - 1);
    bool xs = (x1c == x0c), ys = (y1c == y0c);
    const float* p = src + (size_t)b * 8000;   // input 200 x 40
    float t00, t01, t10, t11;
    if (grp == 0) {
        float W[6][3];
        #pragma unroll
        for (int r = 0; r < 6; ++r) {
            int rr = min(y0c + r, 199);
            #pragma unroll
            for (int cc = 0; cc < 3; ++cc)
                W[r][cc] = p[rr * 40 + min(x0c + cc, 39)];
        }
        float a00 = 0.f, a01 = 0.f, a10 = 0.f, a11 = 0.f;
        #pragma unroll
        for (int ky = 0; ky < 5; ++ky)
            #pragma unroll
            for (int kx = 0; kx < 2; ++kx) {
                float wv = wb[ky * 2 + kx];
                a00 += W[ky][kx] * wv;     a01 += W[ky][kx + 1] * wv;
                a10 += W[ky + 1][kx] * wv; a11 += W[ky + 1][kx + 1] * wv;
            }
        t00 = a00;
        t01 = xs ? a00 : a01;
        t10 = ys ? a00 : a10;
        t11 = xs ? (ys ? a00 : a10) : (ys ? a01 : a11);
    } else {
        float W[3][7];
        #pragma unroll
        for (int r = 0; r < 3; ++r) {
            int rr = min(y0c + r, 199);
            #pragma unroll
            for (int cc = 0; cc < 7; ++cc)
                W[r][cc] = p[rr * 40 + min(x0c + cc, 39)];
        }
        float a00 = 0.f, a01 = 0.f, a10 = 0.f, a11 = 0.f;
        #pragma unroll
        for (int ky = 0; ky < 2; ++ky)
            #pragma unroll
            for (int kx = 0; kx < 6; ++kx) {
                float wv = wb[ky * 6 + kx];
                a00 += W[ky][kx] * wv;     a01 += W[ky][kx + 1] * wv;
                a10 += W[ky + 1][kx] * wv; a11 += W[ky + 1][kx + 1] * wv;
            }
        t00 = a00;
        t01 = xs ? a00 : a01;
        t10 = ys ? a00 : a10;
        t11 = xs ? (ys ? a00 : a10) : (ys ? a01 : a11);
    }
    float r00 = fmaxf(t00 * s + bias, 0.f), r01 = fmaxf(t01 * s + bias, 0.f);
    float r10 = fmaxf(t10 * s + bias, 0.f), r11 = fmaxf(t11 * s + bias, 0.f);
    out[idx] = r00 * (1.f - fy) * (1.f - fx) + r01 * (1.f - fy) * fx
             + r10 * fy * (1.f - fx) + r11 * fy * fx;
}

// ---------- LDS-tiled 3x3 conv, pad 1, fused BN(eval) + ReLU ----------
template<int CIN, int CI_T, int H, int W, int ROWS, int NPX>
__global__ void __launch_bounds__(256) k_conv3x3_tiled(
    const float* __restrict__ in, const float* __restrict__ wT,
    const float* __restrict__ cb, const float* __restrict__ g,
    const float* __restrict__ be, const float* __restrict__ m,
    const float* __restrict__ v, float* __restrict__ out, int COUT) {
    constexpr int WP = W + 2;
    constexpr int RP = ROWS + 2;
    constexpr int STAGE = CI_T * RP * WP;
    __shared__ float sx[STAGE];
    __shared__ float sw[CI_T * 9 * 8];
    const int b = blockIdx.x, rt = blockIdx.y, oc0 = blockIdx.z * 8;
    const int row0 = rt * ROWS;
    const int tid = threadIdx.x;

    int off[NPX]; bool val[NPX];
    #pragma unroll
    for (int j = 0; j < NPX; ++j) {
        int px = tid + j * 256;
        int oy = px / W, ox = px - oy * W;
        bool ok = (px < ROWS * W) && (row0 + oy < H);
        val[j] = ok;
        off[j] = ok ? (oy * WP + ox) : 0;
    }

    float acc[NPX][8];
    #pragma unroll
    for (int j = 0; j < NPX; ++j)
        #pragma unroll
        for (int o = 0; o < 8; ++o) acc[j][o] = 0.f;

    for (int c0 = 0; c0 < CIN; c0 += CI_T) {
        __syncthreads();
        for (int e = tid; e < STAGE; e += 256) {
            int ci = e / (RP * WP);
            int rem = e - ci * RP * WP;
            int r = rem / WP;
            int xx = rem - r * WP;
            int iy = row0 - 1 + r;
            int ix = xx - 1;
            float vv = 0.f;
            if (iy >= 0 && iy < H && ix >= 0 && ix < W)
                vv = in[((size_t)(b * CIN + c0 + ci) * H + iy) * W + ix];
            sx[e] = vv;
        }
        for (int e = tid; e < CI_T * 9 * 8; e += 256) {
            int rk = e >> 3;
            int o = e & 7;
            sw[e] = wT[((size_t)c0 * 9 + rk) * COUT + oc0 + o];
        }
        __syncthreads();
        #pragma unroll 1
        for (int cl = 0; cl < CI_T; ++cl) {
            const float* sxc = sx + cl * RP * WP;
            #pragma unroll
            for (int k = 0; k < 9; ++k) {
                const int ky = k / 3, kx = k % 3;
                const float4 wa = *(const float4*)(sw + (cl * 9 + k) * 8);
                const float4 wb = *(const float4*)(sw + (cl * 9 + k) * 8 + 4);
                #pragma unroll
                for (int j = 0; j < NPX; ++j) {
                    float xv = sxc[off[j] + ky * WP + kx];
                    acc[j][0] += xv * wa.x; acc[j][1] += xv * wa.y;
                    acc[j][2] += xv * wa.z; acc[j][3] += xv * wa.w;
                    acc[j][4] += xv * wb.x; acc[j][5] += xv * wb.y;
                    acc[j][6] += xv * wb.z; acc[j][7] += xv * wb.w;
                }
            }
        }
    }
    float sc[8], bi[8];
    #pragma unroll
    for (int o = 0; o < 8; ++o) {
        float s = g[oc0 + o] * rsqrtf(v[oc0 + o] + 1e-5f);
        sc[o] = s; bi[o] = (cb[oc0 + o] - m[oc0 + o]) * s + be[oc0 + o];
    }
    #pragma unroll
    for (int j = 0; j < NPX; ++j) if (val[j]) {
        int px = tid + j * 256;
        int oy = row0 + px / W, ox = px % W;
        #pragma unroll
        for (int o = 0; o < 8; ++o)
            out[((size_t)(b * COUT + oc0 + o) * H + oy) * W + ox] =
                fmaxf(acc[j][o] * sc[o] + bi[o], 0.f);
    }
}

// ---------- 2x2 maxpool stride 2 (VALID) ----------
__global__ void k_maxpool(const float* __restrict__ in, float* __restrict__ out,
                          int C, int Hin, int Win, int Hout, int Wout, int total) {
    int idx = blockIdx.x * blockDim.x + threadIdx.x;
    if (idx >= total) return;
    int ox = idx % Wout; int t = idx / Wout;
    int oy = t % Hout; t /= Hout;
    int c = t % C; int b = t / C;
    const float* p = in + ((size_t)(b * C + c) * Hin + 2 * oy) * Win + 2 * ox;
    float m0 = fmaxf(p[0], p[1]);
    float m1 = fmaxf(p[Win], p[Win + 1]);
    out[idx] = fmaxf(m0, m1);
}

// ---------- FAT: audio attn (blocks 0..4095) + text attn (4096..6143) + xgap ----------
// Audio occupies ~2 blocks/CU (22% occupancy) — text and xgap blocks fill the
// idle wave slots of the same launch instead of running serially after it.
__global__ void __launch_bounds__(256, 2) k_fat_attn(
    const float* __restrict__ x,
    const float* __restrict__ wq1, const float* __restrict__ bq1,
    const float* __restrict__ wk1, const float* __restrict__ bk1,
    const float* __restrict__ wv1, const float* __restrict__ bv1,
    const float* __restrict__ wq2, const float* __restrict__ bq2,
    const float* __restrict__ wk2, const float* __restrict__ bk2,
    const float* __restrict__ wv2, const float* __restrict__ bv2,
    float* __restrict__ afeat,
    const float* __restrict__ outs,
    const float* __restrict__ wqt1, const float* __restrict__ bqt1,
    const float* __restrict__ wkt1, const float* __restrict__ bkt1,
    const float* __restrict__ wvt1, const float* __restrict__ bvt1,
    const float* __restrict__ wqt2, const float* __restrict__ bqt2,
    const float* __restrict__ wkt2, const float* __restrict__ bkt2,
    const float* __restrict__ wvt2, const float* __restrict__ bvt2,
    float* __restrict__ tfeat, float* __restrict__ xgap) {
    __shared__ float smem[6656];   // 26624 B union: audio sxc+sw | text rows+wred
    const int bx = blockIdx.x;
    const int tid = threadIdx.x;

    if (bx >= 6144) {
        // ================= xgap path =================
        int b = bx - 6144;
        int wave = tid >> 6, lane = tid & 63;
        for (int c = wave; c < 96; c += 4) {
            const float* row = x + ((size_t)b * 96 + c) * 234;
            float s = 0.f;
            for (int p = lane; p < 234; p += 64) s += row[p];
            #pragma unroll
            for (int off = 1; off < 64; off <<= 1) s += __shfl_xor(s, off);
            if (lane == 0) xgap[b * 96 + c] = s * (1.f / 234.f);
        }
        return;
    }
    if (bx >= 4096) {
        // ================= text path (v10 structure, 256 thr) =================
        int a = bx - 4096;
        int b = a & 127, rem = a >> 7;
        int stage = rem & 1, n = rem >> 1;
        const float* wq = stage ? wqt2 : wqt1; const float* bq = stage ? bqt2 : bqt1;
        const float* wk = stage ? wkt2 : wkt1; const float* bk = stage ? bkt2 : bkt1;
        const float* wv = stage ? wvt2 : wvt1; const float* bv = stage ? bvt2 : bvt1;
        bool act = tid < 96;
        int oo = act ? tid : 0;
        const float* wqc = wq + n * 9600 + oo;
        const float* wkc = wk + n * 9600 + oo;
        const float* wvc = wv + n * 9600 + oo;
        float bqv = act ? bq[n * 96 + tid] : 0.f;
        float bkv = act ? bk[n * 96 + tid] : 0.f;
        float bvv = act ? bv[n * 96 + tid] : 0.f;
        float* rows = smem;           // [10][100]
        float* wredM = smem + 1000;   // [2][10]
        float* wredS = smem + 1020;   // [2][10]
        float acc = 0.f;
        int wave = tid >> 6, lane = tid & 63;
        for (int tile = 0; tile < 5; ++tile) {
            int t0 = tile * 10;
            __syncthreads();
            for (int e = tid; e < 1000; e += 256) {
                int tt = e / 100, c = e - tt * 100;
                rows[tt * 100 + c] = outs[((size_t)b * kT + t0 + tt) * 100 + c];
            }
            __syncthreads();
            float q[10], k[10], v[10];
            #pragma unroll
            for (int tt = 0; tt < 10; ++tt) { q[tt] = bqv; k[tt] = bkv; v[tt] = bvv; }
            for (int c4 = 0; c4 < 25; ++c4) {
                int cb = c4 * 384;
                float q0 = wqc[cb], q1 = wqc[cb + 96], q2 = wqc[cb + 192], q3 = wqc[cb + 288];
                float k0 = wkc[cb], k1 = wkc[cb + 96], k2 = wkc[cb + 192], k3 = wkc[cb + 288];
                float v0 = wvc[cb], v1 = wvc[cb + 96], v2 = wvc[cb + 192], v3 = wvc[cb + 288];
                #pragma unroll
                for (int tt = 0; tt < 10; ++tt) {
                    float4 x4 = *(const float4*)&rows[tt * 100 + c4 * 4];
                    q[tt] += q0 * x4.x + q1 * x4.y + q2 * x4.z + q3 * x4.w;
                    k[tt] += k0 * x4.x + k1 * x4.y + k2 * x4.z + k3 * x4.w;
                    v[tt] += v0 * x4.x + v1 * x4.y + v2 * x4.z + v3 * x4.w;
                }
            }
            float s_[10], e_[10];
            #pragma unroll
            for (int tt = 0; tt < 10; ++tt) s_[tt] = act ? q[tt] * k[tt] : -1e30f;
            #pragma unroll
            for (int tt = 0; tt < 10; ++tt) {
                float m = s_[tt];
                #pragma unroll
                for (int off = 1; off < 64; off <<= 1) m = fmaxf(m, __shfl_xor(m, off));
                if (lane == 0 && wave < 2) wredM[wave * 10 + tt] = m;
            }
            __syncthreads();
            #pragma unroll
            for (int tt = 0; tt < 10; ++tt) {
                float mx = fmaxf(wredM[tt], wredM[10 + tt]);
                e_[tt] = expf(s_[tt] - mx);
            }
            #pragma unroll
            for (int tt = 0; tt < 10; ++tt) {
                float sm = e_[tt];
                #pragma unroll
                for (int off = 1; off < 64; off <<= 1) sm += __shfl_xor(sm, off);
                if (lane == 0 && wave < 2) wredS[wave * 10 + tt] = sm;
            }
            __syncthreads();
            #pragma unroll
            for (int tt = 0; tt < 10; ++tt) {
                float sm = wredS[tt] + wredS[10 + tt];
                acc += e_[tt] / sm * v[tt];
            }
        }
        if (act) tfeat[b * 1536 + stage * 768 + n * 96 + tid] = acc;
        return;
    }

    // ================= audio path (v10, verbatim) =================
    const int a = bx;
    const int xp = a & 255;
    const int b = xp >> 1, pt = xp & 1;
    const int n = (a >> 8) & 7, stage = a >> 11;
    const float* wq = (stage ? wq2 : wq1) + n * 9216;   // [c][o] transposed
    const float* wk = (stage ? wk2 : wk1) + n * 9216;
    const float* wv = (stage ? wv2 : wv1) + n * 9216;
    const float* bqn = (stage ? bq2 : bq1) + n * 96;
    const float* bkn = (stage ? bk2 : bk1) + n * 96;
    const float* bvn = (stage ? bv2 : bv1) + n * 96;
    const int to = tid >> 4, tpg = tid & 15;   // o_base = to*6
    const int ob = to * 6;
    const int pA = tpg * 4;                    // cols pA..pA+3 and 64+pA..64+pA+3
    const int p0 = pt * 128;

    float* sxc = smem;          //  8KB  x chunk [16 c][128 p]
    float* sw = smem + 2048;    // 18KB  weights [3 mats][16 c][96 o]
    float* sred = sw;           // epilogue overlay

    const float* xb = x + (size_t)b * (96 * 234) + p0;

    float qa[6][8], ka[6][8], va[6][8];
    #pragma unroll
    for (int j = 0; j < 6; ++j) {
        float bq_ = bqn[ob + j], bk_ = bkn[ob + j], bv_ = bvn[ob + j];
        #pragma unroll
        for (int i = 0; i < 8; ++i) { qa[j][i] = bq_; ka[j][i] = bk_; va[j][i] = bv_; }
    }

    for (int c0 = 0; c0 < 96; c0 += 16) {
        __syncthreads();
        {   // stage x chunk: 1024 float2 (row stride 936B, 8B-aligned; 234 even)
            #pragma unroll
            for (int it = 0; it < 4; ++it) {
                int e2 = tid + it * 256;
                int r = e2 >> 6, c2 = (e2 & 63) * 2;
                float2 v = make_float2(0.f, 0.f);
                if (p0 + c2 < 234) v = *(const float2*)(xb + (c0 + r) * 234 + c2);
                *(float2*)(sxc + r * 128 + c2) = v;
            }
        }
        for (int e4 = tid; e4 < 1152; e4 += 256) {
            int mat = (e4 >= 768) ? 2 : (e4 >= 384 ? 1 : 0);
            int r4 = e4 - mat * 384;
            const float* wsrc = (mat == 0) ? wq : (mat == 1 ? wk : wv);
            *(float4*)(sw + mat * 1536 + r4 * 4) = *(const float4*)(wsrc + c0 * 96 + r4 * 4);
        }
        __syncthreads();
        #pragma unroll 2
        for (int cc = 0; cc < 16; ++cc) {
            float4 xa = *(const float4*)(sxc + cc * 128 + pA);
            float4 xc = *(const float4*)(sxc + cc * 128 + 64 + pA);
            const float* wr = sw + cc * 96 + ob;
            float2 q01 = *(const float2*)(wr);
            float2 q23 = *(const float2*)(wr + 2);
            float2 q45 = *(const float2*)(wr + 4);
            float2 k01 = *(const float2*)(wr + 1536);
            float2 k23 = *(const float2*)(wr + 1538);
            float2 k45 = *(const float2*)(wr + 1540);
            float2 v01 = *(const float2*)(wr + 3072);
            float2 v23 = *(const float2*)(wr + 3074);
            float2 v45 = *(const float2*)(wr + 3076);
            float wqv[6] = {q01.x, q01.y, q23.x, q23.y, q45.x, q45.y};
            float wkv[6] = {k01.x, k01.y, k23.x, k23.y, k45.x, k45.y};
            float wvv[6] = {v01.x, v01.y, v23.x, v23.y, v45.x, v45.y};
            #pragma unroll
            for (int j = 0; j < 6; ++j) {
                qa[j][0] += wqv[j] * xa.x; qa[j][1] += wqv[j] * xa.y;
                qa[j][2] += wqv[j] * xa.z; qa[j][3] += wqv[j] * xa.w;
                qa[j][4] += wqv[j] * xc.x; qa[j][5] += wqv[j] * xc.y;
                qa[j][6] += wqv[j] * xc.z; qa[j][7] += wqv[j] * xc.w;
                ka[j][0] += wkv[j] * xa.x; ka[j][1] += wkv[j] * xa.y;
                ka[j][2] += wkv[j] * xa.z; ka[j][3] += wkv[j] * xa.w;
                ka[j][4] += wkv[j] * xc.x; ka[j][5] += wkv[j] * xc.y;
                ka[j][6] += wkv[j] * xc.z; ka[j][7] += wkv[j] * xc.w;
                va[j][0] += wvv[j] * xa.x; va[j][1] += wvv[j] * xa.y;
                va[j][2] += wvv[j] * xa.z; va[j][3] += wvv[j] * xa.w;
                va[j][4] += wvv[j] * xc.x; va[j][5] += wvv[j] * xc.y;
                va[j][6] += wvv[j] * xc.z; va[j][7] += wvv[j] * xc.w;
            }
        }
    }

    int col[8];
    #pragma unroll
    for (int i = 0; i < 4; ++i) { col[i] = pA + i; col[4 + i] = 64 + pA + i; }

    float pmx[8];
    #pragma unroll
    for (int i = 0; i < 8; ++i) pmx[i] = -1e30f;
    #pragma unroll
    for (int j = 0; j < 6; ++j)
        #pragma unroll
        for (int i = 0; i < 8; ++i) {
            float sv = qa[j][i] * ka[j][i];
            qa[j][i] = sv;
            pmx[i] = fmaxf(pmx[i], sv);
        }
    __syncthreads();
    #pragma unroll
    for (int i = 0; i < 8; ++i) sred[to * 128 + col[i]] = pmx[i];
    __syncthreads();
    float m_[8];
    #pragma unroll
    for (int i = 0; i < 8; ++i) {
        float mm = -1e30f;
        for (int t = 0; t < 16; ++t) mm = fmaxf(mm, sred[t * 128 + col[i]]);
        m_[i] = mm;
    }
    __syncthreads();
    float z[8];
    #pragma unroll
    for (int i = 0; i < 8; ++i) z[i] = 0.f;
    #pragma unroll
    for (int j = 0; j < 6; ++j)
        #pragma unroll
        for (int i = 0; i < 8; ++i) {
            float e = __expf(qa[j][i] - m_[i]);
            qa[j][i] = e;
            z[i] += e;
        }
    #pragma unroll
    for (int i = 0; i < 8; ++i) sred[to * 128 + col[i]] = z[i];
    __syncthreads();
    float rz[8];
    #pragma unroll
    for (int i = 0; i < 8; ++i) {
        float zs = 0.f;
        for (int t = 0; t < 16; ++t) zs += sred[t * 128 + col[i]];
        rz[i] = (p0 + col[i] < 234) ? 1.f / zs : 0.f;
    }
    __syncthreads();
    #pragma unroll
    for (int j = 0; j < 6; ++j) {
        float po = 0.f;
        #pragma unroll
        for (int i = 0; i < 8; ++i) po += qa[j][i] * rz[i] * va[j][i];
        sred[(ob + j) * 16 + tpg] = po;
    }
    __syncthreads();
    if (tid < 96) {
        float ssum = 0.f;
        #pragma unroll
        for (int t = 0; t < 16; ++t) ssum += sred[tid * 16 + t];
        atomicAdd(afeat + b * 1536 + n * 192 + stage * 96 + tid, ssum * (1.f / 234.f));
    }
}

// ---------- cross-modal gated fusion + final logits ----------
__global__ void __launch_bounds__(128) k_final(const float* __restrict__ xgap,
    const float* __restrict__ outs, const float* __restrict__ afeat,
    const float* __restrict__ tfeat,
    const float* __restrict__ w_fa, const float* __restrict__ b_fa,
    const float* __restrict__ w_ft, const float* __restrict__ b_ft,
    const float* __restrict__ w_e, const float* __restrict__ b_e,
    float* __restrict__ out) {
    int b = blockIdx.x; int tid = threadIdx.x;
    __shared__ float xg[96], hv[100], st[100], sa[96], aat[96], atba[100];
    __shared__ float redm[2], reds[2];
    if (tid < 96) xg[tid] = xgap[b * 96 + tid];
    if (tid < 100) hv[tid] = outs[(size_t)(b * kT + kT - 1) * 100 + tid];
    __syncthreads();
    if (tid < 100) {
        float acc = b_fa[tid];
        const float* wr = w_fa + tid * 96;
        for (int c = 0; c < 96; ++c) acc += wr[c] * xg[c];
        st[tid] = acc;
    }
    if (tid < 96) {
        float acc = b_ft[tid];
        const float* wr = w_ft + tid * 100;
        for (int c = 0; c < 100; ++c) acc += wr[c] * hv[c];
        sa[tid] = acc;
    }
    __syncthreads();
    if (tid == 0) {
        float mxv = -1e30f; for (int i = 0; i < 100; ++i) mxv = fmaxf(mxv, st[i]);
        float s = 0.f; for (int i = 0; i < 100; ++i) s += expf(st[i] - mxv);
        redm[0] = mxv; reds[0] = s;
    }
    if (tid == 1) {
        float mxv = -1e30f; for (int i = 0; i < 96; ++i) mxv = fmaxf(mxv, sa[i]);
        float s = 0.f; for (int i = 0; i < 96; ++i) s += expf(sa[i] - mxv);
        redm[1] = mxv; reds[1] = s;
    }
    __syncthreads();
    if (tid < 100) atba[tid] = expf(st[tid] - redm[0]) / reds[0] * hv[tid];
    if (tid < 96)  aat[tid]  = expf(sa[tid] - redm[1]) / reds[1] * xg[tid];
    __syncthreads();
    float a0 = 0.f, a1 = 0.f, a2 = 0.f, a3 = 0.f;
    for (int col = tid; col < 3268; col += 128) {
        float f;
        if (col < 1536)      f = afeat[b * 1536 + col];
        else if (col < 3072) f = tfeat[b * 1536 + col - 1536];
        else if (col < 3168) f = aat[col - 3072];
        else                 f = atba[col - 3168];
        a0 += w_e[col] * f;            a1 += w_e[3268 + col] * f;
        a2 += w_e[2 * 3268 + col] * f; a3 += w_e[3 * 3268 + col] * f;
    }
    __shared__ float r4[4][128];
    r4[0][tid] = a0; r4[1][tid] = a1; r4[2][tid] = a2; r4[3][tid] = a3;
    __syncthreads();
    if (tid < 4) {
        float s = 0.f;
        for (int i = 0; i < 128; ++i) s += r4[tid][i];
        out[b * 4 + tid] = s + b_e[tid];
    }
}

// =====================================================================
extern "C" void kernel_launch(void* const* d_in, const int* in_sizes, int n_in,
                              void* d_out, int out_size, void* d_ws, size_t ws_size,
                              hipStream_t stream) {
    (void)in_sizes; (void)n_in; (void)out_size; (void)ws_size;
    const float* mfcc_t = (const float*)d_in[0];
    const float* mfcc_f = (const float*)d_in[1];
    const float* mfcc_c = (const float*)d_in[2];
    const int*   tokens = (const int*)d_in[3];
    const float *w1a = (const float*)d_in[5],  *b1a = (const float*)d_in[6],
                *g1a = (const float*)d_in[7],  *be1a = (const float*)d_in[8],
                *m1a = (const float*)d_in[9],  *v1a = (const float*)d_in[10];
    const float *w1b = (const float*)d_in[11], *b1b = (const float*)d_in[12],
                *g1b = (const float*)d_in[13], *be1b = (const float*)d_in[14],
                *m1b = (const float*)d_in[15], *v1b = (const float*)d_in[16];
    const float *w2 = (const float*)d_in[17], *b2 = (const float*)d_in[18],
                *g2 = (const float*)d_in[19], *be2 = (const float*)d_in[20],
                *m2 = (const float*)d_in[21], *v2 = (const float*)d_in[22];
    const float *w3 = (const float*)d_in[23], *b3 = (const float*)d_in[24],
                *g3 = (const float*)d_in[25], *be3 = (const float*)d_in[26],
                *m3 = (const float*)d_in[27], *v3 = (const float*)d_in[28];
    const float *w4 = (const float*)d_in[29], *b4 = (const float*)d_in[30],
                *g4 = (const float*)d_in[31], *be4 = (const float*)d_in[32],
                *m4 = (const float*)d_in[33], *v4 = (const float*)d_in[34];
    const float *wq_a1 = (const float*)d_in[35], *bq_a1 = (const float*)d_in[36],
                *wk_a1 = (const float*)d_in[37], *bk_a1 = (const float*)d_in[38],
                *wv_a1 = (const float*)d_in[39], *bv_a1 = (const float*)d_in[40];
    const float *wq_a2 = (const float*)d_in[41], *bq_a2 = (const float*)d_in[42],
                *wk_a2 = (const float*)d_in[43], *bk_a2 = (const float*)d_in[44],
                *wv_a2 = (const float*)d_in[45], *bv_a2 = (const float*)d_in[46];
    const float *emb  = (const float*)d_in[47];
    const float *w_ih = (const float*)d_in[48], *w_hh = (const float*)d_in[49],
                *b_ih = (const float*)d_in[50], *b_hh = (const float*)d_in[51];
    const float *wq_t1 = (const float*)d_in[52], *bq_t1 = (const float*)d_in[53],
                *wk_t1 = (const float*)d_in[54], *bk_t1 = (const float*)d_in[55],
                *wv_t1 = (const float*)d_in[56], *bv_t1 = (const float*)d_in[57];
    const float *wq_t2 = (const float*)d_in[58], *bq_t2 = (const float*)d_in[59],
                *wk_t2 = (const float*)d_in[60], *bk_t2 = (const float*)d_in[61],
                *wv_t2 = (const float*)d_in[62], *bv_t2 = (const float*)d_in[63];
    const float *w_fa = (const float*)d_in[64], *b_fa = (const float*)d_in[65],
                *w_ft = (const float*)d_in[66], *b_ft = (const float*)d_in[67],
                *w_e  = (const float*)d_in[68], *b_e  = (const float*)d_in[69];

    float* ws = (float*)d_ws;
    const size_t Z0 = 0;                 // GI (early) -> c2 -> c3 -> x4
    const size_t Z1 = 22091776ull;       // x1 -> p2 -> p3
    const size_t OUTS  = 34072576ull;    // GRU outputs (written early by fat gru)
    const size_t AFEAT = 34712576ull;
    const size_t TFEAT = 34909184ull;    // conv-wT (early) then text features
    const size_t XGAP  = 35105792ull;
    const size_t WT    = 35118080ull;
    float* GI = ws + Z0;                 // dead until conv2 overwrites Z0
    float* X1 = ws + Z1;
    float* C2 = ws + Z0;  float* P2 = ws + Z1;
    float* C3 = ws + Z0;  float* P3 = ws + Z1;
    float* X4 = ws + Z0;
    float* outs  = ws + OUTS;
    float* afeat = ws + AFEAT;
    float* tfeat = ws + TFEAT;
    float* xgap  = ws + XGAP;
    // audio transposed weights [n][c][o], 73728 floats each
    float* wqa1t = ws + WT;
    float* wka1t = wqa1t + 73728; float* wva1t = wka1t + 73728;
    float* wqa2t = wva1t + 73728; float* wka2t = wqa2t + 73728; float* wva2t = wka2t + 73728;
    // text transposed weights [n][c][o], 76800 floats each
    float* wqt1t = wva2t + 73728;
    float* wkt1t = wqt1t + 76800; float* wvt1t = wkt1t + 76800;
    float* wqt2t = wvt1t + 76800; float* wkt2t = wqt2t + 76800; float* wvt2t = wkt2t + 76800;
    // conv weight transposes parked in the tfeat region (dead until k_fat_attn;
    // convs consume them before the text path writes tfeat)
    float* wT2 = tfeat;           //  6,912
    float* wT3 = tfeat + 6912;    // 18,432
    float* wT4 = tfeat + 25344;   // 55,296

    // ----- all weight transposes + afeat zero-fill in ONE launch -----
    TPack tp;
    tp.d[0]  = {wq_a1, wqa1t, 96, 96, 73728};
    tp.d[1]  = {wk_a1, wka1t, 96, 96, 73728};
    tp.d[2]  = {wv_a1, wva1t, 96, 96, 73728};
    tp.d[3]  = {wq_a2, wqa2t, 96, 96, 73728};
    tp.d[4]  = {wk_a2, wka2t, 96, 96, 73728};
    tp.d[5]  = {wv_a2, wva2t, 96, 96, 73728};
    tp.d[6]  = {w2, wT2, 32, 216, 6912};
    tp.d[7]  = {w3, wT3, 64, 288, 18432};
    tp.d[8]  = {w4, wT4, 96, 576, 55296};
    tp.d[9]  = {wq_t1, wqt1t, 96, 100, 76800};
    tp.d[10] = {wk_t1, wkt1t, 96, 100, 76800};
    tp.d[11] = {wv_t1, wvt1t, 96, 100, 76800};
    tp.d[12] = {wq_t2, wqt2t, 96, 100, 76800};
    tp.d[13] = {wk_t2, wkt2t, 96, 100, 76800};
    tp.d[14] = {wv_t2, wvt2t, 96, 100, 76800};
    k_transpose_pack<<<dim3(300, 16), 256, 0, stream>>>(tp, afeat);

    // ----- text-branch input GEMM (GI at Z0, dead until conv2) -----
    k_gi<<<kB * kT / 8, 320, 0, stream>>>(tokens, emb, w_ih, b_ih, GI);

    // ----- FAT: gru (128 blocks, first) + stem (46800 blocks) -----
    k_fat_stem_gru<<<46928, 256, 0, stream>>>(mfcc_t, mfcc_f, mfcc_c,
        w1a, b1a, g1a, be1a, m1a, v1a,
        w1b, b1b, g1b, be1b, m1b, v1b, X1, 11980800,
        GI, w_hh, b_hh, outs);

    // ----- conv chain -----
    k_conv3x3_tiled<24, 8, 25, 156, 9, 6><<<dim3(128, 3, 4), 256, 0, stream>>>(
        X1, wT2, b2, g2, be2, m2, v2, C2, 32);
    k_maxpool<<<14976, 256, 0, stream>>>(C2, P2, 32, 25, 156, 12, 78, 3833856);
    k_conv3x3_tiled<32, 8, 12, 78, 12, 4><<<dim3(128, 1, 8), 256, 0, stream>>>(
        P2, wT3, b3, g3, be3, m3, v3, C3, 64);
    k_maxpool<<<7488, 256, 0, stream>>>(C3, P3, 64, 12, 78, 6, 39, 1916928);
    k_conv3x3_tiled<64, 16, 6, 39, 6, 1><<<dim3(128, 1, 12), 256, 0, stream>>>(
        P3, wT4, b4, g4, be4, m4, v4, X4, 96);

    // ----- FAT: audio attn (first) + text attn + xgap in one launch -----
    k_fat_attn<<<6272, 256, 0, stream>>>(X4,
        wqa1t, bq_a1, wka1t, bk_a1, wva1t, bv_a1,
        wqa2t, bq_a2, wka2t, bk_a2, wva2t, bv_a2, afeat,
        outs,
        wqt1t, bq_t1, wkt1t, bk_t1, wvt1t, bv_t1,
        wqt2t, bq_t2, wkt2t, bk_t2, wvt2t, bv_t2, tfeat, xgap);

    // ----- fusion + logits -----
    k_final<<<kB, 128, 0, stream>>>(xgap, outs, afeat, tfeat,
                                    w_fa, b_fa, w_ft, b_ft, w_e, b_e, (float*)d_out);
}

// Round 11
// 1419.303 us; speedup vs baseline: 1.1136x; 1.1136x over previous
//
#include <hip/hip_runtime.h>
#include <math.h>

// ---------------- constants ----------------
static constexpr int kB = 128;
static constexpr int kT = 50;

// ---------- packed transpose [N][O][C] -> [N][C][O] + afeat zero-fill ----------
struct TDesc { const float* src; float* dst; int O; int C; int total; };
struct TPack { TDesc d[15]; };
__global__ void k_transpose_pack(TPack p, float* __restrict__ za) {
    if (blockIdx.y == 15) {   // zero afeat (196608 floats, atomicAdd target)
        for (int i = blockIdx.x * 256 + threadIdx.x; i < 196608; i += 76800)
            za[i] = 0.f;
        return;
    }
    TDesc t = p.d[blockIdx.y];
    int idx = blockIdx.x * 256 + threadIdx.x;
    if (idx >= t.total) return;
    int o = idx % t.O; int r = idx / t.O; int c = r % t.C; int n = r / t.C;
    t.dst[idx] = t.src[((size_t)n * t.O + o) * t.C + c];
}

// ---------- embedding lookup + input-side GRU GEMM, 8 rows/block ----------
__global__ void __launch_bounds__(320) k_gi(const int* __restrict__ tokens,
        const float* __restrict__ emb, const float* __restrict__ w_ih,
        const float* __restrict__ b_ih, float* __restrict__ GI) {
    int r0 = blockIdx.x * 8;
    int tid = threadIdx.x;
    __shared__ float er[8][200];
    for (int e = tid; e < 1600; e += 320) {
        int r = e / 200, c = e - r * 200;
        er[r][c] = emb[(size_t)tokens[r0 + r] * 200 + c];
    }
    __syncthreads();
    if (tid < 300) {
        float acc[8];
        float bv = b_ih[tid];
        #pragma unroll
        for (int r = 0; r < 8; ++r) acc[r] = bv;
        for (int k4 = 0; k4 < 50; ++k4) {
            float4 w4 = *(const float4*)(w_ih + (size_t)tid * 200 + k4 * 4);
            #pragma unroll
            for (int r = 0; r < 8; ++r) {
                float4 x4 = *(const float4*)&er[r][k4 * 4];
                acc[r] += w4.x * x4.x + w4.y * x4.y + w4.z * x4.z + w4.w * x4.w;
            }
        }
        #pragma unroll
        for (int r = 0; r < 8; ++r)
            GI[(size_t)(r0 + r) * 300 + tid] = acc[r];
    }
}

// ---------- FAT: gru (blocks 0..127, latency-bound) + stem (blocks 128..) ----------
// gru overlaps the stem's large grid instead of running serially after it.
// (kept from v12 — passed correctness; v13 measures whether it was the saver)
__global__ void __launch_bounds__(256) k_fat_stem_gru(
    const float* __restrict__ mt, const float* __restrict__ mf,
    const float* __restrict__ mc,
    const float* __restrict__ w1a, const float* __restrict__ b1a,
    const float* __restrict__ g1a, const float* __restrict__ be1a,
    const float* __restrict__ m1a, const float* __restrict__ v1a,
    const float* __restrict__ w1b, const float* __restrict__ b1b,
    const float* __restrict__ g1b, const float* __restrict__ be1b,
    const float* __restrict__ m1b, const float* __restrict__ v1b,
    float* __restrict__ out, int total,
    const float* __restrict__ GI, const float* __restrict__ w_hh,
    const float* __restrict__ b_hh, float* __restrict__ outs) {
    if (blockIdx.x < 128) {
        // ================= gru path =================
        const int b = blockIdx.x, tid = threadIdx.x;
        __shared__ float hs[100];
        __shared__ float gH[300];
        const float bias0 = b_hh[tid];                       // row tid (tid<256<300)
        const float bias1 = (tid < 44) ? b_hh[256 + tid] : 0.f;
        if (tid < 100) hs[tid] = 0.f;
        __syncthreads();
        for (int t = 0; t < kT; ++t) {
            {
                float gh = bias0;
                const float* wr = w_hh + (size_t)tid * 100;
                #pragma unroll
                for (int k4 = 0; k4 < 25; ++k4) {
                    float4 w4 = *(const float4*)(wr + k4 * 4);
                    float4 h4 = *(const float4*)&hs[k4 * 4];
                    gh += w4.x * h4.x + w4.y * h4.y + w4.z * h4.z + w4.w * h4.w;
                }
                gH[tid] = gh;
            }
            if (tid < 44) {
                float gh = bias1;
                const float* wr = w_hh + (size_t)(256 + tid) * 100;
                #pragma unroll
                for (int k4 = 0; k4 < 25; ++k4) {
                    float4 w4 = *(const float4*)(wr + k4 * 4);
                    float4 h4 = *(const float4*)&hs[k4 * 4];
                    gh += w4.x * h4.x + w4.y * h4.y + w4.z * h4.z + w4.w * h4.w;
                }
                gH[256 + tid] = gh;
            }
            __syncthreads();
            if (tid < 100) {
                const float* gi = GI + ((size_t)b * kT + t) * 300;
                float r = 1.f / (1.f + expf(-(gi[tid] + gH[tid])));
                float z = 1.f / (1.f + expf(-(gi[100 + tid] + gH[100 + tid])));
                float nn = tanhf(gi[200 + tid] + r * gH[200 + tid]);
                float h2 = (1.f - z) * nn + z * hs[tid];
                hs[tid] = h2;
                outs[((size_t)b * kT + t) * 100 + tid] = h2;
            }
            __syncthreads();
        }
        return;
    }
    // ================= stem path =================
    int idx = (blockIdx.x - 128) * 256 + threadIdx.x;
    if (idx >= total) return;
    int ox = idx % 156; int t = idx / 156;
    int oy = t % 25; t /= 25;
    int ch = t % 24; int b = t / 24;
    int grp = ch >> 3, c = ch & 7;
    const float* src; int Hc, Wc;
    const float *wb, *cb, *g, *be, *m, *v;
    if (grp == 0) { src = mt; Hc = 196; Wc = 39; wb = w1a + c * 10;
                    cb = b1a; g = g1a; be = be1a; m = m1a; v = v1a; }
    else          { src = (grp == 1 ? mf : mc); Hc = 199; Wc = 35; wb = w1b + c * 12;
                    cb = b1b; g = g1b; be = be1b; m = m1b; v = v1b; }
    float s = g[c] * rsqrtf(v[c] + 1e-5f);
    float bias = (cb[c] - m[c]) * s + be[c];
    float sy = (oy + 0.5f) * ((float)Hc / 25.f) - 0.5f;
    float sx = (ox + 0.5f) * ((float)Wc / 156.f) - 0.5f;
    float fy0 = floorf(sy), fx0 = floorf(sx);
    float fy = sy - fy0, fx = sx - fx0;
    int y0 = (int)fy0, x0 = (int)fx0;
    int y0c = min(max(y0, 0), Hc - 1), y1c = min(max(y0 + 1, 0), Hc - 1);
    int x0c = min(max(x0, 0), Wc - 1), x1c = min(max(x0 + 1, 0), Wc - 1);
    bool xs = (x1c == x0c), ys = (y1c == y0c);
    const float* p = src + (size_t)b * 8000;   // input 200 x 40
    float t00, t01, t10, t11;
    if (grp == 0) {
        float W[6][3];
        #pragma unroll
        for (int r = 0; r < 6; ++r) {
            int rr = min(y0c + r, 199);
            #pragma unroll
            for (int cc = 0; cc < 3; ++cc)
                W[r][cc] = p[rr * 40 + min(x0c + cc, 39)];
        }
        float a00 = 0.f, a01 = 0.f, a10 = 0.f, a11 = 0.f;
        #pragma unroll
        for (int ky = 0; ky < 5; ++ky)
            #pragma unroll
            for (int kx = 0; kx < 2; ++kx) {
                float wv = wb[ky * 2 + kx];
                a00 += W[ky][kx] * wv;     a01 += W[ky][kx + 1] * wv;
                a10 += W[ky + 1][kx] * wv; a11 += W[ky + 1][kx + 1] * wv;
            }
        t00 = a00;
        t01 = xs ? a00 : a01;
        t10 = ys ? a00 : a10;
        t11 = xs ? (ys ? a00 : a10) : (ys ? a01 : a11);
    } else {
        float W[3][7];
        #pragma unroll
        for (int r = 0; r < 3; ++r) {
            int rr = min(y0c + r, 199);
            #pragma unroll
            for (int cc = 0; cc < 7; ++cc)
                W[r][cc] = p[rr * 40 + min(x0c + cc, 39)];
        }
        float a00 = 0.f, a01 = 0.f, a10 = 0.f, a11 = 0.f;
        #pragma unroll
        for (int ky = 0; ky < 2; ++ky)
            #pragma unroll
            for (int kx = 0; kx < 6; ++kx) {
                float wv = wb[ky * 6 + kx];
                a00 += W[ky][kx] * wv;     a01 += W[ky][kx + 1] * wv;
                a10 += W[ky + 1][kx] * wv; a11 += W[ky + 1][kx + 1] * wv;
            }
        t00 = a00;
        t01 = xs ? a00 : a01;
        t10 = ys ? a00 : a10;
        t11 = xs ? (ys ? a00 : a10) : (ys ? a01 : a11);
    }
    float r00 = fmaxf(t00 * s + bias, 0.f), r01 = fmaxf(t01 * s + bias, 0.f);
    float r10 = fmaxf(t10 * s + bias, 0.f), r11 = fmaxf(t11 * s + bias, 0.f);
    out[idx] = r00 * (1.f - fy) * (1.f - fx) + r01 * (1.f - fy) * fx
             + r10 * fy * (1.f - fx) + r11 * fy * fx;
}

// ---------- LDS-tiled 3x3 conv, pad 1, fused BN(eval) + ReLU ----------
template<int CIN, int CI_T, int H, int W, int ROWS, int NPX>
__global__ void __launch_bounds__(256) k_conv3x3_tiled(
    const float* __restrict__ in, const float* __restrict__ wT,
    const float* __restrict__ cb, const float* __restrict__ g,
    const float* __restrict__ be, const float* __restrict__ m,
    const float* __restrict__ v, float* __restrict__ out, int COUT) {
    constexpr int WP = W + 2;
    constexpr int RP = ROWS + 2;
    constexpr int STAGE = CI_T * RP * WP;
    __shared__ float sx[STAGE];
    __shared__ float sw[CI_T * 9 * 8];
    const int b = blockIdx.x, rt = blockIdx.y, oc0 = blockIdx.z * 8;
    const int row0 = rt * ROWS;
    const int tid = threadIdx.x;

    int off[NPX]; bool val[NPX];
    #pragma unroll
    for (int j = 0; j < NPX; ++j) {
        int px = tid + j * 256;
        int oy = px / W, ox = px - oy * W;
        bool ok = (px < ROWS * W) && (row0 + oy < H);
        val[j] = ok;
        off[j] = ok ? (oy * WP + ox) : 0;
    }

    float acc[NPX][8];
    #pragma unroll
    for (int j = 0; j < NPX; ++j)
        #pragma unroll
        for (int o = 0; o < 8; ++o) acc[j][o] = 0.f;

    for (int c0 = 0; c0 < CIN; c0 += CI_T) {
        __syncthreads();
        for (int e = tid; e < STAGE; e += 256) {
            int ci = e / (RP * WP);
            int rem = e - ci * RP * WP;
            int r = rem / WP;
            int xx = rem - r * WP;
            int iy = row0 - 1 + r;
            int ix = xx - 1;
            float vv = 0.f;
            if (iy >= 0 && iy < H && ix >= 0 && ix < W)
                vv = in[((size_t)(b * CIN + c0 + ci) * H + iy) * W + ix];
            sx[e] = vv;
        }
        for (int e = tid; e < CI_T * 9 * 8; e += 256) {
            int rk = e >> 3;
            int o = e & 7;
            sw[e] = wT[((size_t)c0 * 9 + rk) * COUT + oc0 + o];
        }
        __syncthreads();
        #pragma unroll 1
        for (int cl = 0; cl < CI_T; ++cl) {
            const float* sxc = sx + cl * RP * WP;
            #pragma unroll
            for (int k = 0; k < 9; ++k) {
                const int ky = k / 3, kx = k % 3;
                const float4 wa = *(const float4*)(sw + (cl * 9 + k) * 8);
                const float4 wb = *(const float4*)(sw + (cl * 9 + k) * 8 + 4);
                #pragma unroll
                for (int j = 0; j < NPX; ++j) {
                    float xv = sxc[off[j] + ky * WP + kx];
                    acc[j][0] += xv * wa.x; acc[j][1] += xv * wa.y;
                    acc[j][2] += xv * wa.z; acc[j][3] += xv * wa.w;
                    acc[j][4] += xv * wb.x; acc[j][5] += xv * wb.y;
                    acc[j][6] += xv * wb.z; acc[j][7] += xv * wb.w;
                }
            }
        }
    }
    float sc[8], bi[8];
    #pragma unroll
    for (int o = 0; o < 8; ++o) {
        float s = g[oc0 + o] * rsqrtf(v[oc0 + o] + 1e-5f);
        sc[o] = s; bi[o] = (cb[oc0 + o] - m[oc0 + o]) * s + be[oc0 + o];
    }
    #pragma unroll
    for (int j = 0; j < NPX; ++j) if (val[j]) {
        int px = tid + j * 256;
        int oy = row0 + px / W, ox = px % W;
        #pragma unroll
        for (int o = 0; o < 8; ++o)
            out[((size_t)(b * COUT + oc0 + o) * H + oy) * W + ox] =
                fmaxf(acc[j][o] * sc[o] + bi[o], 0.f);
    }
}

// ---------- 2x2 maxpool stride 2 (VALID) ----------
__global__ void k_maxpool(const float* __restrict__ in, float* __restrict__ out,
                          int C, int Hin, int Win, int Hout, int Wout, int total) {
    int idx = blockIdx.x * blockDim.x + threadIdx.x;
    if (idx >= total) return;
    int ox = idx % Wout; int t = idx / Wout;
    int oy = t % Hout; t /= Hout;
    int c = t % C; int b = t / C;
    const float* p = in + ((size_t)(b * C + c) * Hin + 2 * oy) * Win + 2 * ox;
    float m0 = fmaxf(p[0], p[1]);
    float m1 = fmaxf(p[Win], p[Win + 1]);
    out[idx] = fmaxf(m0, m1);
}

// ---------- spatial GAP of X4: xgap[b][c] = mean_p x[b][c][p] ----------
__global__ void __launch_bounds__(256) k_xgap(const float* __restrict__ x,
                                              float* __restrict__ xgap) {
    int b = blockIdx.x, tid = threadIdx.x;
    int wave = tid >> 6, lane = tid & 63;
    for (int c = wave; c < 96; c += 4) {
        const float* row = x + ((size_t)b * 96 + c) * 234;
        float s = 0.f;
        for (int p = lane; p < 234; p += 64) s += row[p];
        #pragma unroll
        for (int off = 1; off < 64; off <<= 1) s += __shfl_xor(s, off);
        if (lane == 0) xgap[b * 96 + c] = s * (1.f / 234.f);
    }
}

// ---------- fused audio attention (both stages) + spatial GAP of attn out ----------
// v10 (kept): v8 structure + conflict-free column split. 395us standalone.
__global__ void __launch_bounds__(256, 2) k_audio_attn(
    const float* __restrict__ x,
    const float* __restrict__ wq1, const float* __restrict__ bq1,
    const float* __restrict__ wk1, const float* __restrict__ bk1,
    const float* __restrict__ wv1, const float* __restrict__ bv1,
    const float* __restrict__ wq2, const float* __restrict__ bq2,
    const float* __restrict__ wk2, const float* __restrict__ bk2,
    const float* __restrict__ wv2, const float* __restrict__ bv2,
    float* __restrict__ afeat) {
    const int b = blockIdx.x >> 1, pt = blockIdx.x & 1;
    const int n = blockIdx.y, stage = blockIdx.z;
    const float* wq = (stage ? wq2 : wq1) + n * 9216;   // [c][o] transposed
    const float* wk = (stage ? wk2 : wk1) + n * 9216;
    const float* wv = (stage ? wv2 : wv1) + n * 9216;
    const float* bqn = (stage ? bq2 : bq1) + n * 96;
    const float* bkn = (stage ? bk2 : bk1) + n * 96;
    const float* bvn = (stage ? bv2 : bv1) + n * 96;
    const int tid = threadIdx.x;
    const int to = tid >> 4, tpg = tid & 15;   // o_base = to*6
    const int ob = to * 6;
    const int pA = tpg * 4;                    // cols pA..pA+3 and 64+pA..64+pA+3
    const int p0 = pt * 128;

    __shared__ float sxc[16 * 128];  //  8KB  x chunk [16 c][128 p]
    __shared__ float sw[4608];       // 18KB  weights [3 mats][16 c][96 o]
    float* sred = sw;                // epilogue overlay

    const float* xb = x + (size_t)b * (96 * 234) + p0;

    float qa[6][8], ka[6][8], va[6][8];
    #pragma unroll
    for (int j = 0; j < 6; ++j) {
        float bq_ = bqn[ob + j], bk_ = bkn[ob + j], bv_ = bvn[ob + j];
        #pragma unroll
        for (int i = 0; i < 8; ++i) { qa[j][i] = bq_; ka[j][i] = bk_; va[j][i] = bv_; }
    }

    for (int c0 = 0; c0 < 96; c0 += 16) {
        __syncthreads();
        {   // stage x chunk: 1024 float2 (row stride 936B, 8B-aligned; 234 even)
            #pragma unroll
            for (int it = 0; it < 4; ++it) {
                int e2 = tid + it * 256;
                int r = e2 >> 6, c2 = (e2 & 63) * 2;
                float2 v = make_float2(0.f, 0.f);
                if (p0 + c2 < 234) v = *(const float2*)(xb + (c0 + r) * 234 + c2);
                *(float2*)(sxc + r * 128 + c2) = v;
            }
        }
        for (int e4 = tid; e4 < 1152; e4 += 256) {
            int mat = (e4 >= 768) ? 2 : (e4 >= 384 ? 1 : 0);
            int r4 = e4 - mat * 384;
            const float* wsrc = (mat == 0) ? wq : (mat == 1 ? wk : wv);
            *(float4*)(sw + mat * 1536 + r4 * 4) = *(const float4*)(wsrc + c0 * 96 + r4 * 4);
        }
        __syncthreads();
        #pragma unroll 2
        for (int cc = 0; cc < 16; ++cc) {
            float4 xa = *(const float4*)(sxc + cc * 128 + pA);
            float4 xc = *(const float4*)(sxc + cc * 128 + 64 + pA);
            const float* wr = sw + cc * 96 + ob;
            float2 q01 = *(const float2*)(wr);
            float2 q23 = *(const float2*)(wr + 2);
            float2 q45 = *(const float2*)(wr + 4);
            float2 k01 = *(const float2*)(wr + 1536);
            float2 k23 = *(const float2*)(wr + 1538);
            float2 k45 = *(const float2*)(wr + 1540);
            float2 v01 = *(const float2*)(wr + 3072);
            float2 v23 = *(const float2*)(wr + 3074);
            float2 v45 = *(const float2*)(wr + 3076);
            float wqv[6] = {q01.x, q01.y, q23.x, q23.y, q45.x, q45.y};
            float wkv[6] = {k01.x, k01.y, k23.x, k23.y, k45.x, k45.y};
            float wvv[6] = {v01.x, v01.y, v23.x, v23.y, v45.x, v45.y};
            #pragma unroll
            for (int j = 0; j < 6; ++j) {
                qa[j][0] += wqv[j] * xa.x; qa[j][1] += wqv[j] * xa.y;
                qa[j][2] += wqv[j] * xa.z; qa[j][3] += wqv[j] * xa.w;
                qa[j][4] += wqv[j] * xc.x; qa[j][5] += wqv[j] * xc.y;
                qa[j][6] += wqv[j] * xc.z; qa[j][7] += wqv[j] * xc.w;
                ka[j][0] += wkv[j] * xa.x; ka[j][1] += wkv[j] * xa.y;
                ka[j][2] += wkv[j] * xa.z; ka[j][3] += wkv[j] * xa.w;
                ka[j][4] += wkv[j] * xc.x; ka[j][5] += wkv[j] * xc.y;
                ka[j][6] += wkv[j] * xc.z; ka[j][7] += wkv[j] * xc.w;
                va[j][0] += wvv[j] * xa.x; va[j][1] += wvv[j] * xa.y;
                va[j][2] += wvv[j] * xa.z; va[j][3] += wvv[j] * xa.w;
                va[j][4] += wvv[j] * xc.x; va[j][5] += wvv[j] * xc.y;
                va[j][6] += wvv[j] * xc.z; va[j][7] += wvv[j] * xc.w;
            }
        }
    }

    int col[8];
    #pragma unroll
    for (int i = 0; i < 4; ++i) { col[i] = pA + i; col[4 + i] = 64 + pA + i; }

    float pmx[8];
    #pragma unroll
    for (int i = 0; i < 8; ++i) pmx[i] = -1e30f;
    #pragma unroll
    for (int j = 0; j < 6; ++j)
        #pragma unroll
        for (int i = 0; i < 8; ++i) {
            float sv = qa[j][i] * ka[j][i];
            qa[j][i] = sv;
            pmx[i] = fmaxf(pmx[i], sv);
        }
    __syncthreads();
    #pragma unroll
    for (int i = 0; i < 8; ++i) sred[to * 128 + col[i]] = pmx[i];
    __syncthreads();
    float m_[8];
    #pragma unroll
    for (int i = 0; i < 8; ++i) {
        float mm = -1e30f;
        for (int t = 0; t < 16; ++t) mm = fmaxf(mm, sred[t * 128 + col[i]]);
        m_[i] = mm;
    }
    __syncthreads();
    float z[8];
    #pragma unroll
    for (int i = 0; i < 8; ++i) z[i] = 0.f;
    #pragma unroll
    for (int j = 0; j < 6; ++j)
        #pragma unroll
        for (int i = 0; i < 8; ++i) {
            float e = __expf(qa[j][i] - m_[i]);
            qa[j][i] = e;
            z[i] += e;
        }
    #pragma unroll
    for (int i = 0; i < 8; ++i) sred[to * 128 + col[i]] = z[i];
    __syncthreads();
    float rz[8];
    #pragma unroll
    for (int i = 0; i < 8; ++i) {
        float zs = 0.f;
        for (int t = 0; t < 16; ++t) zs += sred[t * 128 + col[i]];
        rz[i] = (p0 + col[i] < 234) ? 1.f / zs : 0.f;
    }
    __syncthreads();
    #pragma unroll
    for (int j = 0; j < 6; ++j) {
        float po = 0.f;
        #pragma unroll
        for (int i = 0; i < 8; ++i) po += qa[j][i] * rz[i] * va[j][i];
        sred[(ob + j) * 16 + tpg] = po;
    }
    __syncthreads();
    if (tid < 96) {
        float ssum = 0.f;
        #pragma unroll
        for (int t = 0; t < 16; ++t) ssum += sred[tid * 16 + t];
        atomicAdd(afeat + b * 1536 + n * 192 + stage * 96 + tid, ssum * (1.f / 234.f));
    }
}

// ---------- fused text attention (both stages), t-tiled, shuffle softmax ----------
// Round-8 proven version (128 thr, 4.5KB LDS, high occupancy).
__global__ void __launch_bounds__(128) k_text_attn(const float* __restrict__ outs,
    const float* __restrict__ wq1, const float* __restrict__ bq1,
    const float* __restrict__ wk1, const float* __restrict__ bk1,
    const float* __restrict__ wv1, const float* __restrict__ bv1,
    const float* __restrict__ wq2, const float* __restrict__ bq2,
    const float* __restrict__ wk2, const float* __restrict__ bk2,
    const float* __restrict__ wv2, const float* __restrict__ bv2,
    float* __restrict__ tfeat) {
    int b = blockIdx.x, stage = blockIdx.y, n = blockIdx.z;
    const float* wq = stage ? wq2 : wq1; const float* bq = stage ? bq2 : bq1;
    const float* wk = stage ? wk2 : wk1; const float* bk = stage ? bk2 : bk1;
    const float* wv = stage ? wv2 : wv1; const float* bv = stage ? bv2 : bv1;
    int tid = threadIdx.x;
    bool act = tid < 96;
    int oo = act ? tid : 0;
    // transposed layout: w[n*9600 + c*96 + o]
    const float* wqc = wq + n * 9600 + oo;
    const float* wkc = wk + n * 9600 + oo;
    const float* wvc = wv + n * 9600 + oo;
    float bqv = act ? bq[n * 96 + tid] : 0.f;
    float bkv = act ? bk[n * 96 + tid] : 0.f;
    float bvv = act ? bv[n * 96 + tid] : 0.f;
    __shared__ float rows[10][100];
    __shared__ float wredM[2][10], wredS[2][10];
    float acc = 0.f;
    int wave = tid >> 6, lane = tid & 63;
    for (int tile = 0; tile < 5; ++tile) {
        int t0 = tile * 10;
        __syncthreads();
        for (int e = tid; e < 1000; e += 128) {
            int tt = e / 100, c = e - tt * 100;
            rows[tt][c] = outs[((size_t)b * kT + t0 + tt) * 100 + c];
        }
        __syncthreads();
        float q[10], k[10], v[10];
        #pragma unroll
        for (int tt = 0; tt < 10; ++tt) { q[tt] = bqv; k[tt] = bkv; v[tt] = bvv; }
        for (int c4 = 0; c4 < 25; ++c4) {
            int cb = c4 * 4 * 96;
            float q0 = wqc[cb], q1 = wqc[cb + 96], q2 = wqc[cb + 192], q3 = wqc[cb + 288];
            float k0 = wkc[cb], k1 = wkc[cb + 96], k2 = wkc[cb + 192], k3 = wkc[cb + 288];
            float v0 = wvc[cb], v1 = wvc[cb + 96], v2 = wvc[cb + 192], v3 = wvc[cb + 288];
            #pragma unroll
            for (int tt = 0; tt < 10; ++tt) {
                float4 x4 = *(const float4*)&rows[tt][c4 * 4];
                q[tt] += q0 * x4.x + q1 * x4.y + q2 * x4.z + q3 * x4.w;
                k[tt] += k0 * x4.x + k1 * x4.y + k2 * x4.z + k3 * x4.w;
                v[tt] += v0 * x4.x + v1 * x4.y + v2 * x4.z + v3 * x4.w;
            }
        }
        float s[10], e_[10];
        #pragma unroll
        for (int tt = 0; tt < 10; ++tt) s[tt] = act ? q[tt] * k[tt] : -1e30f;
        #pragma unroll
        for (int tt = 0; tt < 10; ++tt) {
            float m = s[tt];
            #pragma unroll
            for (int off = 1; off < 64; off <<= 1) m = fmaxf(m, __shfl_xor(m, off));
            if (lane == 0) wredM[wave][tt] = m;
        }
        __syncthreads();
        #pragma unroll
        for (int tt = 0; tt < 10; ++tt) {
            float mx = fmaxf(wredM[0][tt], wredM[1][tt]);
            e_[tt] = expf(s[tt] - mx);
        }
        #pragma unroll
        for (int tt = 0; tt < 10; ++tt) {
            float sm = e_[tt];
            #pragma unroll
            for (int off = 1; off < 64; off <<= 1) sm += __shfl_xor(sm, off);
            if (lane == 0) wredS[wave][tt] = sm;
        }
        __syncthreads();
        #pragma unroll
        for (int tt = 0; tt < 10; ++tt) {
            float sm = wredS[0][tt] + wredS[1][tt];
            acc += e_[tt] / sm * v[tt];
        }
    }
    if (act) tfeat[b * 1536 + stage * 768 + n * 96 + tid] = acc;
}

// ---------- cross-modal gated fusion + final logits ----------
__global__ void __launch_bounds__(128) k_final(const float* __restrict__ xgap,
    const float* __restrict__ outs, const float* __restrict__ afeat,
    const float* __restrict__ tfeat,
    const float* __restrict__ w_fa, const float* __restrict__ b_fa,
    const float* __restrict__ w_ft, const float* __restrict__ b_ft,
    const float* __restrict__ w_e, const float* __restrict__ b_e,
    float* __restrict__ out) {
    int b = blockIdx.x; int tid = threadIdx.x;
    __shared__ float xg[96], hv[100], st[100], sa[96], aat[96], atba[100];
    __shared__ float redm[2], reds[2];
    if (tid < 96) xg[tid] = xgap[b * 96 + tid];
    if (tid < 100) hv[tid] = outs[(size_t)(b * kT + kT - 1) * 100 + tid];
    __syncthreads();
    if (tid < 100) {
        float acc = b_fa[tid];
        const float* wr = w_fa + tid * 96;
        for (int c = 0; c < 96; ++c) acc += wr[c] * xg[c];
        st[tid] = acc;
    }
    if (tid < 96) {
        float acc = b_ft[tid];
        const float* wr = w_ft + tid * 100;
        for (int c = 0; c < 100; ++c) acc += wr[c] * hv[c];
        sa[tid] = acc;
    }
    __syncthreads();
    if (tid == 0) {
        float mxv = -1e30f; for (int i = 0; i < 100; ++i) mxv = fmaxf(mxv, st[i]);
        float s = 0.f; for (int i = 0; i < 100; ++i) s += expf(st[i] - mxv);
        redm[0] = mxv; reds[0] = s;
    }
    if (tid == 1) {
        float mxv = -1e30f; for (int i = 0; i < 96; ++i) mxv = fmaxf(mxv, sa[i]);
        float s = 0.f; for (int i = 0; i < 96; ++i) s += expf(sa[i] - mxv);
        redm[1] = mxv; reds[1] = s;
    }
    __syncthreads();
    if (tid < 100) atba[tid] = expf(st[tid] - redm[0]) / reds[0] * hv[tid];
    if (tid < 96)  aat[tid]  = expf(sa[tid] - redm[1]) / reds[1] * xg[tid];
    __syncthreads();
    float a0 = 0.f, a1 = 0.f, a2 = 0.f, a3 = 0.f;
    for (int col = tid; col < 3268; col += 128) {
        float f;
        if (col < 1536)      f = afeat[b * 1536 + col];
        else if (col < 3072) f = tfeat[b * 1536 + col - 1536];
        else if (col < 3168) f = aat[col - 3072];
        else                 f = atba[col - 3168];
        a0 += w_e[col] * f;            a1 += w_e[3268 + col] * f;
        a2 += w_e[2 * 3268 + col] * f; a3 += w_e[3 * 3268 + col] * f;
    }
    __shared__ float r4[4][128];
    r4[0][tid] = a0; r4[1][tid] = a1; r4[2][tid] = a2; r4[3][tid] = a3;
    __syncthreads();
    if (tid < 4) {
        float s = 0.f;
        for (int i = 0; i < 128; ++i) s += r4[tid][i];
        out[b * 4 + tid] = s + b_e[tid];
    }
}

// =====================================================================
extern "C" void kernel_launch(void* const* d_in, const int* in_sizes, int n_in,
                              void* d_out, int out_size, void* d_ws, size_t ws_size,
                              hipStream_t stream) {
    (void)in_sizes; (void)n_in; (void)out_size; (void)ws_size;
    const float* mfcc_t = (const float*)d_in[0];
    const float* mfcc_f = (const float*)d_in[1];
    const float* mfcc_c = (const float*)d_in[2];
    const int*   tokens = (const int*)d_in[3];
    const float *w1a = (const float*)d_in[5],  *b1a = (const float*)d_in[6],
                *g1a = (const float*)d_in[7],  *be1a = (const float*)d_in[8],
                *m1a = (const float*)d_in[9],  *v1a = (const float*)d_in[10];
    const float *w1b = (const float*)d_in[11], *b1b = (const float*)d_in[12],
                *g1b = (const float*)d_in[13], *be1b = (const float*)d_in[14],
                *m1b = (const float*)d_in[15], *v1b = (const float*)d_in[16];
    const float *w2 = (const float*)d_in[17], *b2 = (const float*)d_in[18],
                *g2 = (const float*)d_in[19], *be2 = (const float*)d_in[20],
                *m2 = (const float*)d_in[21], *v2 = (const float*)d_in[22];
    const float *w3 = (const float*)d_in[23], *b3 = (const float*)d_in[24],
                *g3 = (const float*)d_in[25], *be3 = (const float*)d_in[26],
                *m3 = (const float*)d_in[27], *v3 = (const float*)d_in[28];
    const float *w4 = (const float*)d_in[29], *b4 = (const float*)d_in[30],
                *g4 = (const float*)d_in[31], *be4 = (const float*)d_in[32],
                *m4 = (const float*)d_in[33], *v4 = (const float*)d_in[34];
    const float *wq_a1 = (const float*)d_in[35], *bq_a1 = (const float*)d_in[36],
                *wk_a1 = (const float*)d_in[37], *bk_a1 = (const float*)d_in[38],
                *wv_a1 = (const float*)d_in[39], *bv_a1 = (const float*)d_in[40];
    const float *wq_a2 = (const float*)d_in[41], *bq_a2 = (const float*)d_in[42],
                *wk_a2 = (const float*)d_in[43], *bk_a2 = (const float*)d_in[44],
                *wv_a2 = (const float*)d_in[45], *bv_a2 = (const float*)d_in[46];
    const float *emb  = (const float*)d_in[47];
    const float *w_ih = (const float*)d_in[48], *w_hh = (const float*)d_in[49],
                *b_ih = (const float*)d_in[50], *b_hh = (const float*)d_in[51];
    const float *wq_t1 = (const float*)d_in[52], *bq_t1 = (const float*)d_in[53],
                *wk_t1 = (const float*)d_in[54], *bk_t1 = (const float*)d_in[55],
                *wv_t1 = (const float*)d_in[56], *bv_t1 = (const float*)d_in[57];
    const float *wq_t2 = (const float*)d_in[58], *bq_t2 = (const float*)d_in[59],
                *wk_t2 = (const float*)d_in[60], *bk_t2 = (const float*)d_in[61],
                *wv_t2 = (const float*)d_in[62], *bv_t2 = (const float*)d_in[63];
    const float *w_fa = (const float*)d_in[64], *b_fa = (const float*)d_in[65],
                *w_ft = (const float*)d_in[66], *b_ft = (const float*)d_in[67],
                *w_e  = (const float*)d_in[68], *b_e  = (const float*)d_in[69];

    float* ws = (float*)d_ws;
    const size_t Z0 = 0;                 // GI (early) -> c2 -> c3 -> x4
    const size_t Z1 = 22091776ull;       // x1 -> p2 -> p3
    const size_t OUTS  = 34072576ull;    // GRU outputs (written early by fat gru)
    const size_t AFEAT = 34712576ull;
    const size_t TFEAT = 34909184ull;    // conv-wT (early) then text features
    const size_t XGAP  = 35105792ull;
    const size_t WT    = 35118080ull;
    float* GI = ws + Z0;                 // dead until conv2 overwrites Z0
    float* X1 = ws + Z1;
    float* C2 = ws + Z0;  float* P2 = ws + Z1;
    float* C3 = ws + Z0;  float* P3 = ws + Z1;
    float* X4 = ws + Z0;
    float* outs  = ws + OUTS;
    float* afeat = ws + AFEAT;
    float* tfeat = ws + TFEAT;
    float* xgap  = ws + XGAP;
    // audio transposed weights [n][c][o], 73728 floats each
    float* wqa1t = ws + WT;
    float* wka1t = wqa1t + 73728; float* wva1t = wka1t + 73728;
    float* wqa2t = wva1t + 73728; float* wka2t = wqa2t + 73728; float* wva2t = wka2t + 73728;
    // text transposed weights [n][c][o], 76800 floats each
    float* wqt1t = wva2t + 73728;
    float* wkt1t = wqt1t + 76800; float* wvt1t = wkt1t + 76800;
    float* wqt2t = wvt1t + 76800; float* wkt2t = wqt2t + 76800; float* wvt2t = wkt2t + 76800;
    // conv weight transposes parked in the tfeat region (dead until text_attn;
    // convs consume them before the text path writes tfeat)
    float* wT2 = tfeat;           //  6,912
    float* wT3 = tfeat + 6912;    // 18,432
    float* wT4 = tfeat + 25344;   // 55,296

    // ----- all weight transposes + afeat zero-fill in ONE launch -----
    TPack tp;
    tp.d[0]  = {wq_a1, wqa1t, 96, 96, 73728};
    tp.d[1]  = {wk_a1, wka1t, 96, 96, 73728};
    tp.d[2]  = {wv_a1, wva1t, 96, 96, 73728};
    tp.d[3]  = {wq_a2, wqa2t, 96, 96, 73728};
    tp.d[4]  = {wk_a2, wka2t, 96, 96, 73728};
    tp.d[5]  = {wv_a2, wva2t, 96, 96, 73728};
    tp.d[6]  = {w2, wT2, 32, 216, 6912};
    tp.d[7]  = {w3, wT3, 64, 288, 18432};
    tp.d[8]  = {w4, wT4, 96, 576, 55296};
    tp.d[9]  = {wq_t1, wqt1t, 96, 100, 76800};
    tp.d[10] = {wk_t1, wkt1t, 96, 100, 76800};
    tp.d[11] = {wv_t1, wvt1t, 96, 100, 76800};
    tp.d[12] = {wq_t2, wqt2t, 96, 100, 76800};
    tp.d[13] = {wk_t2, wkt2t, 96, 100, 76800};
    tp.d[14] = {wv_t2, wvt2t, 96, 100, 76800};
    k_transpose_pack<<<dim3(300, 16), 256, 0, stream>>>(tp, afeat);

    // ----- text-branch input GEMM (GI at Z0, dead until conv2) -----
    k_gi<<<kB * kT / 8, 320, 0, stream>>>(tokens, emb, w_ih, b_ih, GI);

    // ----- FAT: gru (128 blocks, first) + stem (46800 blocks) -----
    k_fat_stem_gru<<<46928, 256, 0, stream>>>(mfcc_t, mfcc_f, mfcc_c,
        w1a, b1a, g1a, be1a, m1a, v1a,
        w1b, b1b, g1b, be1b, m1b, v1b, X1, 11980800,
        GI, w_hh, b_hh, outs);

    // ----- conv chain -----
    k_conv3x3_tiled<24, 8, 25, 156, 9, 6><<<dim3(128, 3, 4), 256, 0, stream>>>(
        X1, wT2, b2, g2, be2, m2, v2, C2, 32);
    k_maxpool<<<14976, 256, 0, stream>>>(C2, P2, 32, 25, 156, 12, 78, 3833856);
    k_conv3x3_tiled<32, 8, 12, 78, 12, 4><<<dim3(128, 1, 8), 256, 0, stream>>>(
        P2, wT3, b3, g3, be3, m3, v3, C3, 64);
    k_maxpool<<<7488, 256, 0, stream>>>(C3, P3, 64, 12, 78, 6, 39, 1916928);
    k_conv3x3_tiled<64, 16, 6, 39, 6, 1><<<dim3(128, 1, 12), 256, 0, stream>>>(
        P3, wT4, b4, g4, be4, m4, v4, X4, 96);

    // ----- text attention + xgap (independent of audio; run before it) -----
    k_text_attn<<<dim3(kB, 2, 8), 128, 0, stream>>>(outs,
        wqt1t, bq_t1, wkt1t, bk_t1, wvt1t, bv_t1,
        wqt2t, bq_t2, wkt2t, bk_t2, wvt2t, bv_t2, tfeat);
    k_xgap<<<kB, 256, 0, stream>>>(X4, xgap);

    // ----- audio attention v10 (standalone, proven 395us) -----
    k_audio_attn<<<dim3(kB * 2, 8, 2), 256, 0, stream>>>(X4,
        wqa1t, bq_a1, wka1t, bk_a1, wva1t, bv_a1,
        wqa2t, bq_a2, wka2t, bk_a2, wva2t, bv_a2, afeat);

    // ----- fusion + logits -----
    k_final<<<kB, 128, 0, stream>>>(xgap, outs, afeat, tfeat,
                                    w_fa, b_fa, w_ft, b_ft, w_e, b_e, (float*)d_out);
}

// Round 13
// 1345.863 us; speedup vs baseline: 1.1744x; 1.0546x over previous
//
#include <hip/hip_runtime.h>
#include <math.h>

// ---------------- constants ----------------
static constexpr int kB = 128;
static constexpr int kT = 50;

// ---------- packed transpose [N][O][C] -> [N][C][O] + afeat zero-fill ----------
struct TDesc { const float* src; float* dst; int O; int C; int total; };
struct TPack { TDesc d[15]; };
__global__ void k_transpose_pack(TPack p, float* __restrict__ za) {
    if (blockIdx.y == 15) {   // zero afeat (196608 floats, atomicAdd target)
        for (int i = blockIdx.x * 256 + threadIdx.x; i < 196608; i += 76800)
            za[i] = 0.f;
        return;
    }
    TDesc t = p.d[blockIdx.y];
    int idx = blockIdx.x * 256 + threadIdx.x;
    if (idx >= t.total) return;
    int o = idx % t.O; int r = idx / t.O; int c = r % t.C; int n = r / t.C;
    t.dst[idx] = t.src[((size_t)n * t.O + o) * t.C + c];
}

// ---------- embedding lookup + input-side GRU GEMM, 8 rows/block ----------
__global__ void __launch_bounds__(320) k_gi(const int* __restrict__ tokens,
        const float* __restrict__ emb, const float* __restrict__ w_ih,
        const float* __restrict__ b_ih, float* __restrict__ GI) {
    int r0 = blockIdx.x * 8;
    int tid = threadIdx.x;
    __shared__ float er[8][200];
    for (int e = tid; e < 1600; e += 320) {
        int r = e / 200, c = e - r * 200;
        er[r][c] = emb[(size_t)tokens[r0 + r] * 200 + c];
    }
    __syncthreads();
    if (tid < 300) {
        float acc[8];
        float bv = b_ih[tid];
        #pragma unroll
        for (int r = 0; r < 8; ++r) acc[r] = bv;
        for (int k4 = 0; k4 < 50; ++k4) {
            float4 w4 = *(const float4*)(w_ih + (size_t)tid * 200 + k4 * 4);
            #pragma unroll
            for (int r = 0; r < 8; ++r) {
                float4 x4 = *(const float4*)&er[r][k4 * 4];
                acc[r] += w4.x * x4.x + w4.y * x4.y + w4.z * x4.z + w4.w * x4.w;
            }
        }
        #pragma unroll
        for (int r = 0; r < 8; ++r)
            GI[(size_t)(r0 + r) * 300 + tid] = acc[r];
    }
}

// ---------- FAT: gru (blocks 0..127) + stem (blocks 128..) ----------
// gru writes outs TRANSPOSED: outs_T[b][c][t] (scattered 200B-stride stores,
// hidden in the latency-bound recurrence) so k_text_attn can stage
// t-contiguous tiles exactly like the audio kernel stages p-contiguous x.
__global__ void __launch_bounds__(256) k_fat_stem_gru(
    const float* __restrict__ mt, const float* __restrict__ mf,
    const float* __restrict__ mc,
    const float* __restrict__ w1a, const float* __restrict__ b1a,
    const float* __restrict__ g1a, const float* __restrict__ be1a,
    const float* __restrict__ m1a, const float* __restrict__ v1a,
    const float* __restrict__ w1b, const float* __restrict__ b1b,
    const float* __restrict__ g1b, const float* __restrict__ be1b,
    const float* __restrict__ m1b, const float* __restrict__ v1b,
    float* __restrict__ out, int total,
    const float* __restrict__ GI, const float* __restrict__ w_hh,
    const float* __restrict__ b_hh, float* __restrict__ outsT) {
    if (blockIdx.x < 128) {
        // ================= gru path =================
        const int b = blockIdx.x, tid = threadIdx.x;
        __shared__ float hs[100];
        __shared__ float gH[300];
        const float bias0 = b_hh[tid];
        const float bias1 = (tid < 44) ? b_hh[256 + tid] : 0.f;
        if (tid < 100) hs[tid] = 0.f;
        __syncthreads();
        for (int t = 0; t < kT; ++t) {
            {
                float gh = bias0;
                const float* wr = w_hh + (size_t)tid * 100;
                #pragma unroll
                for (int k4 = 0; k4 < 25; ++k4) {
                    float4 w4 = *(const float4*)(wr + k4 * 4);
                    float4 h4 = *(const float4*)&hs[k4 * 4];
                    gh += w4.x * h4.x + w4.y * h4.y + w4.z * h4.z + w4.w * h4.w;
                }
                gH[tid] = gh;
            }
            if (tid < 44) {
                float gh = bias1;
                const float* wr = w_hh + (size_t)(256 + tid) * 100;
                #pragma unroll
                for (int k4 = 0; k4 < 25; ++k4) {
                    float4 w4 = *(const float4*)(wr + k4 * 4);
                    float4 h4 = *(const float4*)&hs[k4 * 4];
                    gh += w4.x * h4.x + w4.y * h4.y + w4.z * h4.z + w4.w * h4.w;
                }
                gH[256 + tid] = gh;
            }
            __syncthreads();
            if (tid < 100) {
                const float* gi = GI + ((size_t)b * kT + t) * 300;
                float r = 1.f / (1.f + expf(-(gi[tid] + gH[tid])));
                float z = 1.f / (1.f + expf(-(gi[100 + tid] + gH[100 + tid])));
                float nn = tanhf(gi[200 + tid] + r * gH[200 + tid]);
                float h2 = (1.f - z) * nn + z * hs[tid];
                hs[tid] = h2;
                outsT[((size_t)b * 100 + tid) * kT + t] = h2;   // transposed
            }
            __syncthreads();
        }
        return;
    }
    // ================= stem path =================
    int idx = (blockIdx.x - 128) * 256 + threadIdx.x;
    if (idx >= total) return;
    int ox = idx % 156; int t = idx / 156;
    int oy = t % 25; t /= 25;
    int ch = t % 24; int b = t / 24;
    int grp = ch >> 3, c = ch & 7;
    const float* src; int Hc, Wc;
    const float *wb, *cb, *g, *be, *m, *v;
    if (grp == 0) { src = mt; Hc = 196; Wc = 39; wb = w1a + c * 10;
                    cb = b1a; g = g1a; be = be1a; m = m1a; v = v1a; }
    else          { src = (grp == 1 ? mf : mc); Hc = 199; Wc = 35; wb = w1b + c * 12;
                    cb = b1b; g = g1b; be = be1b; m = m1b; v = v1b; }
    float s = g[c] * rsqrtf(v[c] + 1e-5f);
    float bias = (cb[c] - m[c]) * s + be[c];
    float sy = (oy + 0.5f) * ((float)Hc / 25.f) - 0.5f;
    float sx = (ox + 0.5f) * ((float)Wc / 156.f) - 0.5f;
    float fy0 = floorf(sy), fx0 = floorf(sx);
    float fy = sy - fy0, fx = sx - fx0;
    int y0 = (int)fy0, x0 = (int)fx0;
    int y0c = min(max(y0, 0), Hc - 1), y1c = min(max(y0 + 1, 0), Hc - 1);
    int x0c = min(max(x0, 0), Wc - 1), x1c = min(max(x0 + 1, 0), Wc - 1);
    bool xs = (x1c == x0c), ys = (y1c == y0c);
    const float* p = src + (size_t)b * 8000;   // input 200 x 40
    float t00, t01, t10, t11;
    if (grp == 0) {
        float W[6][3];
        #pragma unroll
        for (int r = 0; r < 6; ++r) {
            int rr = min(y0c + r, 199);
            #pragma unroll
            for (int cc = 0; cc < 3; ++cc)
                W[r][cc] = p[rr * 40 + min(x0c + cc, 39)];
        }
        float a00 = 0.f, a01 = 0.f, a10 = 0.f, a11 = 0.f;
        #pragma unroll
        for (int ky = 0; ky < 5; ++ky)
            #pragma unroll
            for (int kx = 0; kx < 2; ++kx) {
                float wv = wb[ky * 2 + kx];
                a00 += W[ky][kx] * wv;     a01 += W[ky][kx + 1] * wv;
                a10 += W[ky + 1][kx] * wv; a11 += W[ky + 1][kx + 1] * wv;
            }
        t00 = a00;
        t01 = xs ? a00 : a01;
        t10 = ys ? a00 : a10;
        t11 = xs ? (ys ? a00 : a10) : (ys ? a01 : a11);
    } else {
        float W[3][7];
        #pragma unroll
        for (int r = 0; r < 3; ++r) {
            int rr = min(y0c + r, 199);
            #pragma unroll
            for (int cc = 0; cc < 7; ++cc)
                W[r][cc] = p[rr * 40 + min(x0c + cc, 39)];
        }
        float a00 = 0.f, a01 = 0.f, a10 = 0.f, a11 = 0.f;
        #pragma unroll
        for (int ky = 0; ky < 2; ++ky)
            #pragma unroll
            for (int kx = 0; kx < 6; ++kx) {
                float wv = wb[ky * 6 + kx];
                a00 += W[ky][kx] * wv;     a01 += W[ky][kx + 1] * wv;
                a10 += W[ky + 1][kx] * wv; a11 += W[ky + 1][kx + 1] * wv;
            }
        t00 = a00;
        t01 = xs ? a00 : a01;
        t10 = ys ? a00 : a10;
        t11 = xs ? (ys ? a00 : a10) : (ys ? a01 : a11);
    }
    float r00 = fmaxf(t00 * s + bias, 0.f), r01 = fmaxf(t01 * s + bias, 0.f);
    float r10 = fmaxf(t10 * s + bias, 0.f), r11 = fmaxf(t11 * s + bias, 0.f);
    out[idx] = r00 * (1.f - fy) * (1.f - fx) + r01 * (1.f - fy) * fx
             + r10 * fy * (1.f - fx) + r11 * fy * fx;
}

// ---------- LDS-tiled 3x3 conv, pad 1, fused BN(eval) + ReLU ----------
template<int CIN, int CI_T, int H, int W, int ROWS, int NPX>
__global__ void __launch_bounds__(256) k_conv3x3_tiled(
    const float* __restrict__ in, const float* __restrict__ wT,
    const float* __restrict__ cb, const float* __restrict__ g,
    const float* __restrict__ be, const float* __restrict__ m,
    const float* __restrict__ v, float* __restrict__ out, int COUT) {
    constexpr int WP = W + 2;
    constexpr int RP = ROWS + 2;
    constexpr int STAGE = CI_T * RP * WP;
    __shared__ float sx[STAGE];
    __shared__ float sw[CI_T * 9 * 8];
    const int b = blockIdx.x, rt = blockIdx.y, oc0 = blockIdx.z * 8;
    const int row0 = rt * ROWS;
    const int tid = threadIdx.x;

    int off[NPX]; bool val[NPX];
    #pragma unroll
    for (int j = 0; j < NPX; ++j) {
        int px = tid + j * 256;
        int oy = px / W, ox = px - oy * W;
        bool ok = (px < ROWS * W) && (row0 + oy < H);
        val[j] = ok;
        off[j] = ok ? (oy * WP + ox) : 0;
    }

    float acc[NPX][8];
    #pragma unroll
    for (int j = 0; j < NPX; ++j)
        #pragma unroll
        for (int o = 0; o < 8; ++o) acc[j][o] = 0.f;

    for (int c0 = 0; c0 < CIN; c0 += CI_T) {
        __syncthreads();
        for (int e = tid; e < STAGE; e += 256) {
            int ci = e / (RP * WP);
            int rem = e - ci * RP * WP;
            int r = rem / WP;
            int xx = rem - r * WP;
            int iy = row0 - 1 + r;
            int ix = xx - 1;
            float vv = 0.f;
            if (iy >= 0 && iy < H && ix >= 0 && ix < W)
                vv = in[((size_t)(b * CIN + c0 + ci) * H + iy) * W + ix];
            sx[e] = vv;
        }
        for (int e = tid; e < CI_T * 9 * 8; e += 256) {
            int rk = e >> 3;
            int o = e & 7;
            sw[e] = wT[((size_t)c0 * 9 + rk) * COUT + oc0 + o];
        }
        __syncthreads();
        #pragma unroll 1
        for (int cl = 0; cl < CI_T; ++cl) {
            const float* sxc = sx + cl * RP * WP;
            #pragma unroll
            for (int k = 0; k < 9; ++k) {
                const int ky = k / 3, kx = k % 3;
                const float4 wa = *(const float4*)(sw + (cl * 9 + k) * 8);
                const float4 wb = *(const float4*)(sw + (cl * 9 + k) * 8 + 4);
                #pragma unroll
                for (int j = 0; j < NPX; ++j) {
                    float xv = sxc[off[j] + ky * WP + kx];
                    acc[j][0] += xv * wa.x; acc[j][1] += xv * wa.y;
                    acc[j][2] += xv * wa.z; acc[j][3] += xv * wa.w;
                    acc[j][4] += xv * wb.x; acc[j][5] += xv * wb.y;
                    acc[j][6] += xv * wb.z; acc[j][7] += xv * wb.w;
                }
            }
        }
    }
    float sc[8], bi[8];
    #pragma unroll
    for (int o = 0; o < 8; ++o) {
        float s = g[oc0 + o] * rsqrtf(v[oc0 + o] + 1e-5f);
        sc[o] = s; bi[o] = (cb[oc0 + o] - m[oc0 + o]) * s + be[oc0 + o];
    }
    #pragma unroll
    for (int j = 0; j < NPX; ++j) if (val[j]) {
        int px = tid + j * 256;
        int oy = row0 + px / W, ox = px % W;
        #pragma unroll
        for (int o = 0; o < 8; ++o)
            out[((size_t)(b * COUT + oc0 + o) * H + oy) * W + ox] =
                fmaxf(acc[j][o] * sc[o] + bi[o], 0.f);
    }
}

// ---------- 2x2 maxpool stride 2 (VALID) ----------
__global__ void k_maxpool(const float* __restrict__ in, float* __restrict__ out,
                          int C, int Hin, int Win, int Hout, int Wout, int total) {
    int idx = blockIdx.x * blockDim.x + threadIdx.x;
    if (idx >= total) return;
    int ox = idx % Wout; int t = idx / Wout;
    int oy = t % Hout; t /= Hout;
    int c = t % C; int b = t / C;
    const float* p = in + ((size_t)(b * C + c) * Hin + 2 * oy) * Win + 2 * ox;
    float m0 = fmaxf(p[0], p[1]);
    float m1 = fmaxf(p[Win], p[Win + 1]);
    out[idx] = fmaxf(m0, m1);
}

// ---------- spatial GAP of X4: xgap[b][c] = mean_p x[b][c][p] ----------
__global__ void __launch_bounds__(256) k_xgap(const float* __restrict__ x,
                                              float* __restrict__ xgap) {
    int b = blockIdx.x, tid = threadIdx.x;
    int wave = tid >> 6, lane = tid & 63;
    for (int c = wave; c < 96; c += 4) {
        const float* row = x + ((size_t)b * 96 + c) * 234;
        float s = 0.f;
        for (int p = lane; p < 234; p += 64) s += row[p];
        #pragma unroll
        for (int off = 1; off < 64; off <<= 1) s += __shfl_xor(s, off);
        if (lane == 0) xgap[b * 96 + c] = s * (1.f / 234.f);
    }
}

// ---------- fused audio attention (both stages) + spatial GAP of attn out ----------
// v10 (kept): v8 structure + conflict-free column split. ~390us standalone.
__global__ void __launch_bounds__(256, 2) k_audio_attn(
    const float* __restrict__ x,
    const float* __restrict__ wq1, const float* __restrict__ bq1,
    const float* __restrict__ wk1, const float* __restrict__ bk1,
    const float* __restrict__ wv1, const float* __restrict__ bv1,
    const float* __restrict__ wq2, const float* __restrict__ bq2,
    const float* __restrict__ wk2, const float* __restrict__ bk2,
    const float* __restrict__ wv2, const float* __restrict__ bv2,
    float* __restrict__ afeat) {
    const int b = blockIdx.x >> 1, pt = blockIdx.x & 1;
    const int n = blockIdx.y, stage = blockIdx.z;
    const float* wq = (stage ? wq2 : wq1) + n * 9216;   // [c][o] transposed
    const float* wk = (stage ? wk2 : wk1) + n * 9216;
    const float* wv = (stage ? wv2 : wv1) + n * 9216;
    const float* bqn = (stage ? bq2 : bq1) + n * 96;
    const float* bkn = (stage ? bk2 : bk1) + n * 96;
    const float* bvn = (stage ? bv2 : bv1) + n * 96;
    const int tid = threadIdx.x;
    const int to = tid >> 4, tpg = tid & 15;   // o_base = to*6
    const int ob = to * 6;
    const int pA = tpg * 4;                    // cols pA..pA+3 and 64+pA..64+pA+3
    const int p0 = pt * 128;

    __shared__ float sxc[16 * 128];  //  8KB  x chunk [16 c][128 p]
    __shared__ float sw[4608];       // 18KB  weights [3 mats][16 c][96 o]
    float* sred = sw;                // epilogue overlay

    const float* xb = x + (size_t)b * (96 * 234) + p0;

    float qa[6][8], ka[6][8], va[6][8];
    #pragma unroll
    for (int j = 0; j < 6; ++j) {
        float bq_ = bqn[ob + j], bk_ = bkn[ob + j], bv_ = bvn[ob + j];
        #pragma unroll
        for (int i = 0; i < 8; ++i) { qa[j][i] = bq_; ka[j][i] = bk_; va[j][i] = bv_; }
    }

    for (int c0 = 0; c0 < 96; c0 += 16) {
        __syncthreads();
        {   // stage x chunk: 1024 float2 (row stride 936B, 8B-aligned; 234 even)
            #pragma unroll
            for (int it = 0; it < 4; ++it) {
                int e2 = tid + it * 256;
                int r = e2 >> 6, c2 = (e2 & 63) * 2;
                float2 v = make_float2(0.f, 0.f);
                if (p0 + c2 < 234) v = *(const float2*)(xb + (c0 + r) * 234 + c2);
                *(float2*)(sxc + r * 128 + c2) = v;
            }
        }
        for (int e4 = tid; e4 < 1152; e4 += 256) {
            int mat = (e4 >= 768) ? 2 : (e4 >= 384 ? 1 : 0);
            int r4 = e4 - mat * 384;
            const float* wsrc = (mat == 0) ? wq : (mat == 1 ? wk : wv);
            *(float4*)(sw + mat * 1536 + r4 * 4) = *(const float4*)(wsrc + c0 * 96 + r4 * 4);
        }
        __syncthreads();
        #pragma unroll 2
        for (int cc = 0; cc < 16; ++cc) {
            float4 xa = *(const float4*)(sxc + cc * 128 + pA);
            float4 xc = *(const float4*)(sxc + cc * 128 + 64 + pA);
            const float* wr = sw + cc * 96 + ob;
            float2 q01 = *(const float2*)(wr);
            float2 q23 = *(const float2*)(wr + 2);
            float2 q45 = *(const float2*)(wr + 4);
            float2 k01 = *(const float2*)(wr + 1536);
            float2 k23 = *(const float2*)(wr + 1538);
            float2 k45 = *(const float2*)(wr + 1540);
            float2 v01 = *(const float2*)(wr + 3072);
            float2 v23 = *(const float2*)(wr + 3074);
            float2 v45 = *(const float2*)(wr + 3076);
            float wqv[6] = {q01.x, q01.y, q23.x, q23.y, q45.x, q45.y};
            float wkv[6] = {k01.x, k01.y, k23.x, k23.y, k45.x, k45.y};
            float wvv[6] = {v01.x, v01.y, v23.x, v23.y, v45.x, v45.y};
            #pragma unroll
            for (int j = 0; j < 6; ++j) {
                qa[j][0] += wqv[j] * xa.x; qa[j][1] += wqv[j] * xa.y;
                qa[j][2] += wqv[j] * xa.z; qa[j][3] += wqv[j] * xa.w;
                qa[j][4] += wqv[j] * xc.x; qa[j][5] += wqv[j] * xc.y;
                qa[j][6] += wqv[j] * xc.z; qa[j][7] += wqv[j] * xc.w;
                ka[j][0] += wkv[j] * xa.x; ka[j][1] += wkv[j] * xa.y;
                ka[j][2] += wkv[j] * xa.z; ka[j][3] += wkv[j] * xa.w;
                ka[j][4] += wkv[j] * xc.x; ka[j][5] += wkv[j] * xc.y;
                ka[j][6] += wkv[j] * xc.z; ka[j][7] += wkv[j] * xc.w;
                va[j][0] += wvv[j] * xa.x; va[j][1] += wvv[j] * xa.y;
                va[j][2] += wvv[j] * xa.z; va[j][3] += wvv[j] * xa.w;
                va[j][4] += wvv[j] * xc.x; va[j][5] += wvv[j] * xc.y;
                va[j][6] += wvv[j] * xc.z; va[j][7] += wvv[j] * xc.w;
            }
        }
    }

    int col[8];
    #pragma unroll
    for (int i = 0; i < 4; ++i) { col[i] = pA + i; col[4 + i] = 64 + pA + i; }

    float pmx[8];
    #pragma unroll
    for (int i = 0; i < 8; ++i) pmx[i] = -1e30f;
    #pragma unroll
    for (int j = 0; j < 6; ++j)
        #pragma unroll
        for (int i = 0; i < 8; ++i) {
            float sv = qa[j][i] * ka[j][i];
            qa[j][i] = sv;
            pmx[i] = fmaxf(pmx[i], sv);
        }
    __syncthreads();
    #pragma unroll
    for (int i = 0; i < 8; ++i) sred[to * 128 + col[i]] = pmx[i];
    __syncthreads();
    float m_[8];
    #pragma unroll
    for (int i = 0; i < 8; ++i) {
        float mm = -1e30f;
        for (int t = 0; t < 16; ++t) mm = fmaxf(mm, sred[t * 128 + col[i]]);
        m_[i] = mm;
    }
    __syncthreads();
    float z[8];
    #pragma unroll
    for (int i = 0; i < 8; ++i) z[i] = 0.f;
    #pragma unroll
    for (int j = 0; j < 6; ++j)
        #pragma unroll
        for (int i = 0; i < 8; ++i) {
            float e = __expf(qa[j][i] - m_[i]);
            qa[j][i] = e;
            z[i] += e;
        }
    #pragma unroll
    for (int i = 0; i < 8; ++i) sred[to * 128 + col[i]] = z[i];
    __syncthreads();
    float rz[8];
    #pragma unroll
    for (int i = 0; i < 8; ++i) {
        float zs = 0.f;
        for (int t = 0; t < 16; ++t) zs += sred[t * 128 + col[i]];
        rz[i] = (p0 + col[i] < 234) ? 1.f / zs : 0.f;
    }
    __syncthreads();
    #pragma unroll
    for (int j = 0; j < 6; ++j) {
        float po = 0.f;
        #pragma unroll
        for (int i = 0; i < 8; ++i) po += qa[j][i] * rz[i] * va[j][i];
        sred[(ob + j) * 16 + tpg] = po;
    }
    __syncthreads();
    if (tid < 96) {
        float ssum = 0.f;
        #pragma unroll
        for (int t = 0; t < 16; ++t) ssum += sred[tid * 16 + t];
        atomicAdd(afeat + b * 1536 + n * 192 + stage * 96 + tid, ssum * (1.f / 234.f));
    }
}

// ---------- text attention v14: audio-v10 clone over outs_T ----------
// Block = (b, stage, n); 256 thr = 16 o-grp (To=6) x 16 t-grp (Tt=4, 64-wide,
// t>=50 masked). x tile [20c][64t] staged from outs_T (t-contiguous); weights
// [3][20c][96o] staged per chunk (LDS-broadcast reads replace the old 1500
// dependent global loads/thread). Column softmax over o via 16-partial LDS
// tree; per-o sum over t via LDS tree; direct (non-atomic) tfeat store.
__global__ void __launch_bounds__(256, 2) k_text_attn(
    const float* __restrict__ outsT,
    const float* __restrict__ wq1, const float* __restrict__ bq1,
    const float* __restrict__ wk1, const float* __restrict__ bk1,
    const float* __restrict__ wv1, const float* __restrict__ bv1,
    const float* __restrict__ wq2, const float* __restrict__ bq2,
    const float* __restrict__ wk2, const float* __restrict__ bk2,
    const float* __restrict__ wv2, const float* __restrict__ bv2,
    float* __restrict__ tfeat) {
    const int b = blockIdx.x, stage = blockIdx.y, n = blockIdx.z;
    const float* wq = (stage ? wq2 : wq1) + n * 9600;   // [c][o] transposed
    const float* wk = (stage ? wk2 : wk1) + n * 9600;
    const float* wv = (stage ? wv2 : wv1) + n * 9600;
    const float* bqn = (stage ? bq2 : bq1) + n * 96;
    const float* bkn = (stage ? bk2 : bk1) + n * 96;
    const float* bvn = (stage ? bv2 : bv1) + n * 96;
    const int tid = threadIdx.x;
    const int to = tid >> 4, tpg = tid & 15;   // o_base = to*6, t_base = tpg*4
    const int ob = to * 6;
    const int tA = tpg * 4;

    __shared__ float sxc[20 * 64];   //  5KB  rows chunk [20 c][64 t] (t>=50 pad 0)
    __shared__ float sw[5760];       // 22.5KB weights [3 mats][20 c][96 o]
    float* sred = sw;                // epilogue overlay (16*64=1024, 96*16=1536)

    const float* xb = outsT + (size_t)b * (100 * kT);

    float qa[6][4], ka[6][4], va[6][4];
    #pragma unroll
    for (int j = 0; j < 6; ++j) {
        float bq_ = bqn[ob + j], bk_ = bkn[ob + j], bv_ = bvn[ob + j];
        #pragma unroll
        for (int i = 0; i < 4; ++i) { qa[j][i] = bq_; ka[j][i] = bk_; va[j][i] = bv_; }
    }

    for (int c0 = 0; c0 < 100; c0 += 20) {
        __syncthreads();
        // stage rows chunk: 1280 scalars (lane t contiguous; t>=50 -> 0)
        for (int e = tid; e < 1280; e += 256) {
            int r = e >> 6, tt = e & 63;
            sxc[e] = (tt < kT) ? xb[(c0 + r) * kT + tt] : 0.f;
        }
        // stage weights: 3 mats x 20 c x 96 o = 1440 float4
        for (int e4 = tid; e4 < 1440; e4 += 256) {
            int mat = (e4 >= 960) ? 2 : (e4 >= 480 ? 1 : 0);
            int r4 = e4 - mat * 480;
            const float* wsrc = (mat == 0) ? wq : (mat == 1 ? wk : wv);
            *(float4*)(sw + mat * 1920 + r4 * 4) = *(const float4*)(wsrc + c0 * 96 + r4 * 4);
        }
        __syncthreads();
        #pragma unroll 4
        for (int cc = 0; cc < 20; ++cc) {
            float4 xa = *(const float4*)(sxc + cc * 64 + tA);
            const float* wr = sw + cc * 96 + ob;
            float2 q01 = *(const float2*)(wr);
            float2 q23 = *(const float2*)(wr + 2);
            float2 q45 = *(const float2*)(wr + 4);
            float2 k01 = *(const float2*)(wr + 1920);
            float2 k23 = *(const float2*)(wr + 1922);
            float2 k45 = *(const float2*)(wr + 1924);
            float2 v01 = *(const float2*)(wr + 3840);
            float2 v23 = *(const float2*)(wr + 3842);
            float2 v45 = *(const float2*)(wr + 3844);
            float wqv[6] = {q01.x, q01.y, q23.x, q23.y, q45.x, q45.y};
            float wkv[6] = {k01.x, k01.y, k23.x, k23.y, k45.x, k45.y};
            float wvv[6] = {v01.x, v01.y, v23.x, v23.y, v45.x, v45.y};
            #pragma unroll
            for (int j = 0; j < 6; ++j) {
                qa[j][0] += wqv[j] * xa.x; qa[j][1] += wqv[j] * xa.y;
                qa[j][2] += wqv[j] * xa.z; qa[j][3] += wqv[j] * xa.w;
                ka[j][0] += wkv[j] * xa.x; ka[j][1] += wkv[j] * xa.y;
                ka[j][2] += wkv[j] * xa.z; ka[j][3] += wkv[j] * xa.w;
                va[j][0] += wvv[j] * xa.x; va[j][1] += wvv[j] * xa.y;
                va[j][2] += wvv[j] * xa.z; va[j][3] += wvv[j] * xa.w;
            }
        }
    }

    // ---- scores in-place, column softmax over o (per t-col) ----
    float pmx[4] = {-1e30f, -1e30f, -1e30f, -1e30f};
    #pragma unroll
    for (int j = 0; j < 6; ++j)
        #pragma unroll
        for (int i = 0; i < 4; ++i) {
            float sv = qa[j][i] * ka[j][i];
            qa[j][i] = sv;
            pmx[i] = fmaxf(pmx[i], sv);
        }
    __syncthreads();   // main-loop LDS reads done before sred overlay writes
    #pragma unroll
    for (int i = 0; i < 4; ++i) sred[to * 64 + tA + i] = pmx[i];
    __syncthreads();
    float m_[4];
    #pragma unroll
    for (int i = 0; i < 4; ++i) {
        float mm = -1e30f;
        for (int t = 0; t < 16; ++t) mm = fmaxf(mm, sred[t * 64 + tA + i]);
        m_[i] = mm;
    }
    __syncthreads();
    float z[4] = {0.f, 0.f, 0.f, 0.f};
    #pragma unroll
    for (int j = 0; j < 6; ++j)
        #pragma unroll
        for (int i = 0; i < 4; ++i) {
            float e = __expf(qa[j][i] - m_[i]);
            qa[j][i] = e;
            z[i] += e;
        }
    #pragma unroll
    for (int i = 0; i < 4; ++i) sred[to * 64 + tA + i] = z[i];
    __syncthreads();
    float rz[4];
    #pragma unroll
    for (int i = 0; i < 4; ++i) {
        float zs = 0.f;
        for (int t = 0; t < 16; ++t) zs += sred[t * 64 + tA + i];
        rz[i] = (tA + i < kT) ? 1.f / zs : 0.f;   // mask pad t-columns
    }
    __syncthreads();
    // ---- per-o partial sums over own 4 t's, reduce across tpg ----
    #pragma unroll
    for (int j = 0; j < 6; ++j) {
        float po = qa[j][0] * rz[0] * va[j][0]
                 + qa[j][1] * rz[1] * va[j][1]
                 + qa[j][2] * rz[2] * va[j][2]
                 + qa[j][3] * rz[3] * va[j][3];
        sred[(ob + j) * 16 + tpg] = po;
    }
    __syncthreads();
    if (tid < 96) {
        float ssum = 0.f;
        #pragma unroll
        for (int t = 0; t < 16; ++t) ssum += sred[tid * 16 + t];
        tfeat[b * 1536 + stage * 768 + n * 96 + tid] = ssum;
    }
}

// ---------- cross-modal gated fusion + final logits ----------
__global__ void __launch_bounds__(128) k_final(const float* __restrict__ xgap,
    const float* __restrict__ outsT, const float* __restrict__ afeat,
    const float* __restrict__ tfeat,
    const float* __restrict__ w_fa, const float* __restrict__ b_fa,
    const float* __restrict__ w_ft, const float* __restrict__ b_ft,
    const float* __restrict__ w_e, const float* __restrict__ b_e,
    float* __restrict__ out) {
    int b = blockIdx.x; int tid = threadIdx.x;
    __shared__ float xg[96], hv[100], st[100], sa[96], aat[96], atba[100];
    __shared__ float redm[2], reds[2];
    if (tid < 96) xg[tid] = xgap[b * 96 + tid];
    if (tid < 100) hv[tid] = outsT[((size_t)b * 100 + tid) * kT + (kT - 1)];
    __syncthreads();
    if (tid < 100) {
        float acc = b_fa[tid];
        const float* wr = w_fa + tid * 96;
        for (int c = 0; c < 96; ++c) acc += wr[c] * xg[c];
        st[tid] = acc;
    }
    if (tid < 96) {
        float acc = b_ft[tid];
        const float* wr = w_ft + tid * 100;
        for (int c = 0; c < 100; ++c) acc += wr[c] * hv[c];
        sa[tid] = acc;
    }
    __syncthreads();
    if (tid == 0) {
        float mxv = -1e30f; for (int i = 0; i < 100; ++i) mxv = fmaxf(mxv, st[i]);
        float s = 0.f; for (int i = 0; i < 100; ++i) s += expf(st[i] - mxv);
        redm[0] = mxv; reds[0] = s;
    }
    if (tid == 1) {
        float mxv = -1e30f; for (int i = 0; i < 96; ++i) mxv = fmaxf(mxv, sa[i]);
        float s = 0.f; for (int i = 0; i < 96; ++i) s += expf(sa[i] - mxv);
        redm[1] = mxv; reds[1] = s;
    }
    __syncthreads();
    if (tid < 100) atba[tid] = expf(st[tid] - redm[0]) / reds[0] * hv[tid];
    if (tid < 96)  aat[tid]  = expf(sa[tid] - redm[1]) / reds[1] * xg[tid];
    __syncthreads();
    float a0 = 0.f, a1 = 0.f, a2 = 0.f, a3 = 0.f;
    for (int col = tid; col < 3268; col += 128) {
        float f;
        if (col < 1536)      f = afeat[b * 1536 + col];
        else if (col < 3072) f = tfeat[b * 1536 + col - 1536];
        else if (col < 3168) f = aat[col - 3072];
        else                 f = atba[col - 3168];
        a0 += w_e[col] * f;            a1 += w_e[3268 + col] * f;
        a2 += w_e[2 * 3268 + col] * f; a3 += w_e[3 * 3268 + col] * f;
    }
    __shared__ float r4[4][128];
    r4[0][tid] = a0; r4[1][tid] = a1; r4[2][tid] = a2; r4[3][tid] = a3;
    __syncthreads();
    if (tid < 4) {
        float s = 0.f;
        for (int i = 0; i < 128; ++i) s += r4[tid][i];
        out[b * 4 + tid] = s + b_e[tid];
    }
}

// =====================================================================
extern "C" void kernel_launch(void* const* d_in, const int* in_sizes, int n_in,
                              void* d_out, int out_size, void* d_ws, size_t ws_size,
                              hipStream_t stream) {
    (void)in_sizes; (void)n_in; (void)out_size; (void)ws_size;
    const float* mfcc_t = (const float*)d_in[0];
    const float* mfcc_f = (const float*)d_in[1];
    const float* mfcc_c = (const float*)d_in[2];
    const int*   tokens = (const int*)d_in[3];
    const float *w1a = (const float*)d_in[5],  *b1a = (const float*)d_in[6],
                *g1a = (const float*)d_in[7],  *be1a = (const float*)d_in[8],
                *m1a = (const float*)d_in[9],  *v1a = (const float*)d_in[10];
    const float *w1b = (const float*)d_in[11], *b1b = (const float*)d_in[12],
                *g1b = (const float*)d_in[13], *be1b = (const float*)d_in[14],
                *m1b = (const float*)d_in[15], *v1b = (const float*)d_in[16];
    const float *w2 = (const float*)d_in[17], *b2 = (const float*)d_in[18],
                *g2 = (const float*)d_in[19], *be2 = (const float*)d_in[20],
                *m2 = (const float*)d_in[21], *v2 = (const float*)d_in[22];
    const float *w3 = (const float*)d_in[23], *b3 = (const float*)d_in[24],
                *g3 = (const float*)d_in[25], *be3 = (const float*)d_in[26],
                *m3 = (const float*)d_in[27], *v3 = (const float*)d_in[28];
    const float *w4 = (const float*)d_in[29], *b4 = (const float*)d_in[30],
                *g4 = (const float*)d_in[31], *be4 = (const float*)d_in[32],
                *m4 = (const float*)d_in[33], *v4 = (const float*)d_in[34];
    const float *wq_a1 = (const float*)d_in[35], *bq_a1 = (const float*)d_in[36],
                *wk_a1 = (const float*)d_in[37], *bk_a1 = (const float*)d_in[38],
                *wv_a1 = (const float*)d_in[39], *bv_a1 = (const float*)d_in[40];
    const float *wq_a2 = (const float*)d_in[41], *bq_a2 = (const float*)d_in[42],
                *wk_a2 = (const float*)d_in[43], *bk_a2 = (const float*)d_in[44],
                *wv_a2 = (const float*)d_in[45], *bv_a2 = (const float*)d_in[46];
    const float *emb  = (const float*)d_in[47];
    const float *w_ih = (const float*)d_in[48], *w_hh = (const float*)d_in[49],
                *b_ih = (const float*)d_in[50], *b_hh = (const float*)d_in[51];
    const float *wq_t1 = (const float*)d_in[52], *bq_t1 = (const float*)d_in[53],
                *wk_t1 = (const float*)d_in[54], *bk_t1 = (const float*)d_in[55],
                *wv_t1 = (const float*)d_in[56], *bv_t1 = (const float*)d_in[57];
    const float *wq_t2 = (const float*)d_in[58], *bq_t2 = (const float*)d_in[59],
                *wk_t2 = (const float*)d_in[60], *bk_t2 = (const float*)d_in[61],
                *wv_t2 = (const float*)d_in[62], *bv_t2 = (const float*)d_in[63];
    const float *w_fa = (const float*)d_in[64], *b_fa = (const float*)d_in[65],
                *w_ft = (const float*)d_in[66], *b_ft = (const float*)d_in[67],
                *w_e  = (const float*)d_in[68], *b_e  = (const float*)d_in[69];

    float* ws = (float*)d_ws;
    const size_t Z0 = 0;                 // GI (early) -> c2 -> c3 -> x4
    const size_t Z1 = 22091776ull;       // x1 -> p2 -> p3
    const size_t OUTS  = 34072576ull;    // outs_T[b][c][t] (written early by fat gru)
    const size_t AFEAT = 34712576ull;
    const size_t TFEAT = 34909184ull;    // conv-wT (early) then text features
    const size_t XGAP  = 35105792ull;
    const size_t WT    = 35118080ull;
    float* GI = ws + Z0;                 // dead until conv2 overwrites Z0
    float* X1 = ws + Z1;
    float* C2 = ws + Z0;  float* P2 = ws + Z1;
    float* C3 = ws + Z0;  float* P3 = ws + Z1;
    float* X4 = ws + Z0;
    float* outsT = ws + OUTS;
    float* afeat = ws + AFEAT;
    float* tfeat = ws + TFEAT;
    float* xgap  = ws + XGAP;
    // audio transposed weights [n][c][o], 73728 floats each
    float* wqa1t = ws + WT;
    float* wka1t = wqa1t + 73728; float* wva1t = wka1t + 73728;
    float* wqa2t = wva1t + 73728; float* wka2t = wqa2t + 73728; float* wva2t = wka2t + 73728;
    // text transposed weights [n][c][o], 76800 floats each
    float* wqt1t = wva2t + 73728;
    float* wkt1t = wqt1t + 76800; float* wvt1t = wkt1t + 76800;
    float* wqt2t = wvt1t + 76800; float* wkt2t = wqt2t + 76800; float* wvt2t = wkt2t + 76800;
    // conv weight transposes parked in the tfeat region (dead until text_attn;
    // convs consume them before the text path writes tfeat)
    float* wT2 = tfeat;           //  6,912
    float* wT3 = tfeat + 6912;    // 18,432
    float* wT4 = tfeat + 25344;   // 55,296

    // ----- all weight transposes + afeat zero-fill in ONE launch -----
    TPack tp;
    tp.d[0]  = {wq_a1, wqa1t, 96, 96, 73728};
    tp.d[1]  = {wk_a1, wka1t, 96, 96, 73728};
    tp.d[2]  = {wv_a1, wva1t, 96, 96, 73728};
    tp.d[3]  = {wq_a2, wqa2t, 96, 96, 73728};
    tp.d[4]  = {wk_a2, wka2t, 96, 96, 73728};
    tp.d[5]  = {wv_a2, wva2t, 96, 96, 73728};
    tp.d[6]  = {w2, wT2, 32, 216, 6912};
    tp.d[7]  = {w3, wT3, 64, 288, 18432};
    tp.d[8]  = {w4, wT4, 96, 576, 55296};
    tp.d[9]  = {wq_t1, wqt1t, 96, 100, 76800};
    tp.d[10] = {wk_t1, wkt1t, 96, 100, 76800};
    tp.d[11] = {wv_t1, wvt1t, 96, 100, 76800};
    tp.d[12] = {wq_t2, wqt2t, 96, 100, 76800};
    tp.d[13] = {wk_t2, wkt2t, 96, 100, 76800};
    tp.d[14] = {wv_t2, wvt2t, 96, 100, 76800};
    k_transpose_pack<<<dim3(300, 16), 256, 0, stream>>>(tp, afeat);

    // ----- text-branch input GEMM (GI at Z0, dead until conv2) -----
    k_gi<<<kB * kT / 8, 320, 0, stream>>>(tokens, emb, w_ih, b_ih, GI);

    // ----- FAT: gru (128 blocks, writes outs_T) + stem (46800 blocks) -----
    k_fat_stem_gru<<<46928, 256, 0, stream>>>(mfcc_t, mfcc_f, mfcc_c,
        w1a, b1a, g1a, be1a, m1a, v1a,
        w1b, b1b, g1b, be1b, m1b, v1b, X1, 11980800,
        GI, w_hh, b_hh, outsT);

    // ----- conv chain -----
    k_conv3x3_tiled<24, 8, 25, 156, 9, 6><<<dim3(128, 3, 4), 256, 0, stream>>>(
        X1, wT2, b2, g2, be2, m2, v2, C2, 32);
    k_maxpool<<<14976, 256, 0, stream>>>(C2, P2, 32, 25, 156, 12, 78, 3833856);
    k_conv3x3_tiled<32, 8, 12, 78, 12, 4><<<dim3(128, 1, 8), 256, 0, stream>>>(
        P2, wT3, b3, g3, be3, m3, v3, C3, 64);
    k_maxpool<<<7488, 256, 0, stream>>>(C3, P3, 64, 12, 78, 6, 39, 1916928);
    k_conv3x3_tiled<64, 16, 6, 39, 6, 1><<<dim3(128, 1, 12), 256, 0, stream>>>(
        P3, wT4, b4, g4, be4, m4, v4, X4, 96);

    // ----- text attention v14 (audio-v10 clone) + xgap -----
    k_text_attn<<<dim3(kB, 2, 8), 256, 0, stream>>>(outsT,
        wqt1t, bq_t1, wkt1t, bk_t1, wvt1t, bv_t1,
        wqt2t, bq_t2, wkt2t, bk_t2, wvt2t, bv_t2, tfeat);
    k_xgap<<<kB, 256, 0, stream>>>(X4, xgap);

    // ----- audio attention v10 (standalone, proven ~390us) -----
    k_audio_attn<<<dim3(kB * 2, 8, 2), 256, 0, stream>>>(X4,
        wqa1t, bq_a1, wka1t, bk_a1, wva1t, bv_a1,
        wqa2t, bq_a2, wka2t, bk_a2, wva2t, bv_a2, afeat);

    // ----- fusion + logits -----
    k_final<<<kB, 128, 0, stream>>>(xgap, outsT, afeat, tfeat,
                                    w_fa, b_fa, w_ft, b_ft, w_e, b_e, (float*)d_out);
}

// Round 14
// 1299.028 us; speedup vs baseline: 1.2167x; 1.0361x over previous
//
#include <hip/hip_runtime.h>
#include <math.h>

// ---------------- constants ----------------
static constexpr int kB = 128;
static constexpr int kT = 50;

// ---------- packed transpose [N][O][C] -> [N][C][O] + afeat zero-fill ----------
struct TDesc { const float* src; float* dst; int O; int C; int total; };
struct TPack { TDesc d[15]; };
__global__ void k_transpose_pack(TPack p, float* __restrict__ za) {
    if (blockIdx.y == 15) {   // zero afeat (196608 floats, atomicAdd target)
        for (int i = blockIdx.x * 256 + threadIdx.x; i < 196608; i += 76800)
            za[i] = 0.f;
        return;
    }
    TDesc t = p.d[blockIdx.y];
    int idx = blockIdx.x * 256 + threadIdx.x;
    if (idx >= t.total) return;
    int o = idx % t.O; int r = idx / t.O; int c = r % t.C; int n = r / t.C;
    t.dst[idx] = t.src[((size_t)n * t.O + o) * t.C + c];
}

// ---------- embedding lookup + input-side GRU GEMM, 8 rows/block ----------
__global__ void __launch_bounds__(320) k_gi(const int* __restrict__ tokens,
        const float* __restrict__ emb, const float* __restrict__ w_ih,
        const float* __restrict__ b_ih, float* __restrict__ GI) {
    int r0 = blockIdx.x * 8;
    int tid = threadIdx.x;
    __shared__ float er[8][200];
    for (int e = tid; e < 1600; e += 320) {
        int r = e / 200, c = e - r * 200;
        er[r][c] = emb[(size_t)tokens[r0 + r] * 200 + c];
    }
    __syncthreads();
    if (tid < 300) {
        float acc[8];
        float bv = b_ih[tid];
        #pragma unroll
        for (int r = 0; r < 8; ++r) acc[r] = bv;
        for (int k4 = 0; k4 < 50; ++k4) {
            float4 w4 = *(const float4*)(w_ih + (size_t)tid * 200 + k4 * 4);
            #pragma unroll
            for (int r = 0; r < 8; ++r) {
                float4 x4 = *(const float4*)&er[r][k4 * 4];
                acc[r] += w4.x * x4.x + w4.y * x4.y + w4.z * x4.z + w4.w * x4.w;
            }
        }
        #pragma unroll
        for (int r = 0; r < 8; ++r)
            GI[(size_t)(r0 + r) * 300 + tid] = acc[r];
    }
}

// ---------- FAT: gru (blocks 0..127) + stem (blocks 128..) ----------
// gru writes outs TRANSPOSED: outs_T[b][c][t] so k_text_attn can stage
// t-contiguous tiles exactly like the audio kernel stages p-contiguous x.
__global__ void __launch_bounds__(256) k_fat_stem_gru(
    const float* __restrict__ mt, const float* __restrict__ mf,
    const float* __restrict__ mc,
    const float* __restrict__ w1a, const float* __restrict__ b1a,
    const float* __restrict__ g1a, const float* __restrict__ be1a,
    const float* __restrict__ m1a, const float* __restrict__ v1a,
    const float* __restrict__ w1b, const float* __restrict__ b1b,
    const float* __restrict__ g1b, const float* __restrict__ be1b,
    const float* __restrict__ m1b, const float* __restrict__ v1b,
    float* __restrict__ out, int total,
    const float* __restrict__ GI, const float* __restrict__ w_hh,
    const float* __restrict__ b_hh, float* __restrict__ outsT) {
    if (blockIdx.x < 128) {
        // ================= gru path =================
        const int b = blockIdx.x, tid = threadIdx.x;
        __shared__ float hs[100];
        __shared__ float gH[300];
        const float bias0 = b_hh[tid];
        const float bias1 = (tid < 44) ? b_hh[256 + tid] : 0.f;
        if (tid < 100) hs[tid] = 0.f;
        __syncthreads();
        for (int t = 0; t < kT; ++t) {
            {
                float gh = bias0;
                const float* wr = w_hh + (size_t)tid * 100;
                #pragma unroll
                for (int k4 = 0; k4 < 25; ++k4) {
                    float4 w4 = *(const float4*)(wr + k4 * 4);
                    float4 h4 = *(const float4*)&hs[k4 * 4];
                    gh += w4.x * h4.x + w4.y * h4.y + w4.z * h4.z + w4.w * h4.w;
                }
                gH[tid] = gh;
            }
            if (tid < 44) {
                float gh = bias1;
                const float* wr = w_hh + (size_t)(256 + tid) * 100;
                #pragma unroll
                for (int k4 = 0; k4 < 25; ++k4) {
                    float4 w4 = *(const float4*)(wr + k4 * 4);
                    float4 h4 = *(const float4*)&hs[k4 * 4];
                    gh += w4.x * h4.x + w4.y * h4.y + w4.z * h4.z + w4.w * h4.w;
                }
                gH[256 + tid] = gh;
            }
            __syncthreads();
            if (tid < 100) {
                const float* gi = GI + ((size_t)b * kT + t) * 300;
                float r = 1.f / (1.f + expf(-(gi[tid] + gH[tid])));
                float z = 1.f / (1.f + expf(-(gi[100 + tid] + gH[100 + tid])));
                float nn = tanhf(gi[200 + tid] + r * gH[200 + tid]);
                float h2 = (1.f - z) * nn + z * hs[tid];
                hs[tid] = h2;
                outsT[((size_t)b * 100 + tid) * kT + t] = h2;   // transposed
            }
            __syncthreads();
        }
        return;
    }
    // ================= stem path =================
    int idx = (blockIdx.x - 128) * 256 + threadIdx.x;
    if (idx >= total) return;
    int ox = idx % 156; int t = idx / 156;
    int oy = t % 25; t /= 25;
    int ch = t % 24; int b = t / 24;
    int grp = ch >> 3, c = ch & 7;
    const float* src; int Hc, Wc;
    const float *wb, *cb, *g, *be, *m, *v;
    if (grp == 0) { src = mt; Hc = 196; Wc = 39; wb = w1a + c * 10;
                    cb = b1a; g = g1a; be = be1a; m = m1a; v = v1a; }
    else          { src = (grp == 1 ? mf : mc); Hc = 199; Wc = 35; wb = w1b + c * 12;
                    cb = b1b; g = g1b; be = be1b; m = m1b; v = v1b; }
    float s = g[c] * rsqrtf(v[c] + 1e-5f);
    float bias = (cb[c] - m[c]) * s + be[c];
    float sy = (oy + 0.5f) * ((float)Hc / 25.f) - 0.5f;
    float sx = (ox + 0.5f) * ((float)Wc / 156.f) - 0.5f;
    float fy0 = floorf(sy), fx0 = floorf(sx);
    float fy = sy - fy0, fx = sx - fx0;
    int y0 = (int)fy0, x0 = (int)fx0;
    int y0c = min(max(y0, 0), Hc - 1), y1c = min(max(y0 + 1, 0), Hc - 1);
    int x0c = min(max(x0, 0), Wc - 1), x1c = min(max(x0 + 1, 0), Wc - 1);
    bool xs = (x1c == x0c), ys = (y1c == y0c);
    const float* p = src + (size_t)b * 8000;   // input 200 x 40
    float t00, t01, t10, t11;
    if (grp == 0) {
        float W[6][3];
        #pragma unroll
        for (int r = 0; r < 6; ++r) {
            int rr = min(y0c + r, 199);
            #pragma unroll
            for (int cc = 0; cc < 3; ++cc)
                W[r][cc] = p[rr * 40 + min(x0c + cc, 39)];
        }
        float a00 = 0.f, a01 = 0.f, a10 = 0.f, a11 = 0.f;
        #pragma unroll
        for (int ky = 0; ky < 5; ++ky)
            #pragma unroll
            for (int kx = 0; kx < 2; ++kx) {
                float wv = wb[ky * 2 + kx];
                a00 += W[ky][kx] * wv;     a01 += W[ky][kx + 1] * wv;
                a10 += W[ky + 1][kx] * wv; a11 += W[ky + 1][kx + 1] * wv;
            }
        t00 = a00;
        t01 = xs ? a00 : a01;
        t10 = ys ? a00 : a10;
        t11 = xs ? (ys ? a00 : a10) : (ys ? a01 : a11);
    } else {
        float W[3][7];
        #pragma unroll
        for (int r = 0; r < 3; ++r) {
            int rr = min(y0c + r, 199);
            #pragma unroll
            for (int cc = 0; cc < 7; ++cc)
                W[r][cc] = p[rr * 40 + min(x0c + cc, 39)];
        }
        float a00 = 0.f, a01 = 0.f, a10 = 0.f, a11 = 0.f;
        #pragma unroll
        for (int ky = 0; ky < 2; ++ky)
            #pragma unroll
            for (int kx = 0; kx < 6; ++kx) {
                float wv = wb[ky * 6 + kx];
                a00 += W[ky][kx] * wv;     a01 += W[ky][kx + 1] * wv;
                a10 += W[ky + 1][kx] * wv; a11 += W[ky + 1][kx + 1] * wv;
            }
        t00 = a00;
        t01 = xs ? a00 : a01;
        t10 = ys ? a00 : a10;
        t11 = xs ? (ys ? a00 : a10) : (ys ? a01 : a11);
    }
    float r00 = fmaxf(t00 * s + bias, 0.f), r01 = fmaxf(t01 * s + bias, 0.f);
    float r10 = fmaxf(t10 * s + bias, 0.f), r11 = fmaxf(t11 * s + bias, 0.f);
    out[idx] = r00 * (1.f - fy) * (1.f - fx) + r01 * (1.f - fy) * fx
             + r10 * fy * (1.f - fx) + r11 * fy * fx;
}

// ---------- LDS-tiled 3x3 conv, pad 1, BN(eval)+ReLU, 16-oc blocks,
//            optional fused 2x2/2 maxpool (POOL) ----------
// 16 oc per block: per (cl,k) the same NPX x-reads + 4 w-float4 reads feed
// 2x the FMAs of the old 8-oc version (conv LDS-instr count ~halved).
// POOL: per-oc scatter of ReLU'd tile into sx (free after main loop) then
// 2x2 max by the first PH*PW threads -> pooled write (intermediate C-buffer
// and separate maxpool kernel eliminated). ROWS even; conv2 skips dead row 24.
template<int CIN, int CI_T, int H, int W, int ROWS, int NPX, bool POOL>
__global__ void __launch_bounds__(256) k_conv16(
    const float* __restrict__ in, const float* __restrict__ wT,
    const float* __restrict__ cb, const float* __restrict__ g,
    const float* __restrict__ be, const float* __restrict__ m,
    const float* __restrict__ v, float* __restrict__ out, int COUT, int PHT) {
    constexpr int WP = W + 2;
    constexpr int RP = ROWS + 2;
    constexpr int STAGE = CI_T * RP * WP;
    __shared__ float sx[STAGE];
    __shared__ float sw[CI_T * 9 * 16];
    const int b = blockIdx.x, rt = blockIdx.y, oc0 = blockIdx.z * 16;
    const int row0 = rt * ROWS;
    const int tid = threadIdx.x;

    int off[NPX]; bool val[NPX];
    #pragma unroll
    for (int j = 0; j < NPX; ++j) {
        int px = tid + j * 256;
        int oy = px / W, ox = px - oy * W;
        bool ok = (px < ROWS * W) && (row0 + oy < H);
        val[j] = ok;
        off[j] = ok ? (oy * WP + ox) : 0;
    }

    float acc[NPX][16];
    #pragma unroll
    for (int j = 0; j < NPX; ++j)
        #pragma unroll
        for (int o = 0; o < 16; ++o) acc[j][o] = 0.f;

    for (int c0 = 0; c0 < CIN; c0 += CI_T) {
        __syncthreads();
        for (int e = tid; e < STAGE; e += 256) {
            int ci = e / (RP * WP);
            int rem = e - ci * RP * WP;
            int r = rem / WP;
            int xx = rem - r * WP;
            int iy = row0 - 1 + r;
            int ix = xx - 1;
            float vv = 0.f;
            if (iy >= 0 && iy < H && ix >= 0 && ix < W)
                vv = in[((size_t)(b * CIN + c0 + ci) * H + iy) * W + ix];
            sx[e] = vv;
        }
        for (int e = tid; e < CI_T * 9 * 16; e += 256) {
            int rk = e >> 4;
            int o = e & 15;
            sw[e] = wT[((size_t)c0 * 9 + rk) * COUT + oc0 + o];
        }
        __syncthreads();
        #pragma unroll 1
        for (int cl = 0; cl < CI_T; ++cl) {
            const float* sxc = sx + cl * RP * WP;
            #pragma unroll
            for (int k = 0; k < 9; ++k) {
                const int ky = k / 3, kx = k % 3;
                const float* wb_ = sw + (cl * 9 + k) * 16;
                const float4 wa = *(const float4*)(wb_);
                const float4 wb2 = *(const float4*)(wb_ + 4);
                const float4 wc = *(const float4*)(wb_ + 8);
                const float4 wd = *(const float4*)(wb_ + 12);
                #pragma unroll
                for (int j = 0; j < NPX; ++j) {
                    float xv = sxc[off[j] + ky * WP + kx];
                    acc[j][0]  += xv * wa.x;  acc[j][1]  += xv * wa.y;
                    acc[j][2]  += xv * wa.z;  acc[j][3]  += xv * wa.w;
                    acc[j][4]  += xv * wb2.x; acc[j][5]  += xv * wb2.y;
                    acc[j][6]  += xv * wb2.z; acc[j][7]  += xv * wb2.w;
                    acc[j][8]  += xv * wc.x;  acc[j][9]  += xv * wc.y;
                    acc[j][10] += xv * wc.z;  acc[j][11] += xv * wc.w;
                    acc[j][12] += xv * wd.x;  acc[j][13] += xv * wd.y;
                    acc[j][14] += xv * wd.z;  acc[j][15] += xv * wd.w;
                }
            }
        }
    }
    float sc[16], bi[16];
    #pragma unroll
    for (int o = 0; o < 16; ++o) {
        float s = g[oc0 + o] * rsqrtf(v[oc0 + o] + 1e-5f);
        sc[o] = s; bi[o] = (cb[oc0 + o] - m[oc0 + o]) * s + be[oc0 + o];
    }
    if (!POOL) {
        #pragma unroll
        for (int j = 0; j < NPX; ++j) if (val[j]) {
            int px = tid + j * 256;
            int oy = row0 + px / W, ox = px % W;
            #pragma unroll
            for (int o = 0; o < 16; ++o)
                out[((size_t)(b * COUT + oc0 + o) * H + oy) * W + ox] =
                    fmaxf(acc[j][o] * sc[o] + bi[o], 0.f);
        }
    } else {
        constexpr int PH = ROWS / 2, PW = W / 2, PT = PH * PW;
        const int prow0 = rt * PH;
        for (int o = 0; o < 16; ++o) {
            __syncthreads();   // previous oc's max-reads done before scatter
            #pragma unroll
            for (int j = 0; j < NPX; ++j) if (val[j]) {
                int px = tid + j * 256;
                sx[px] = fmaxf(acc[j][o] * sc[o] + bi[o], 0.f);
            }
            __syncthreads();
            for (int e = tid; e < PT; e += 256) {
                int py = e / PW, pxl = e - py * PW;
                const float* r0 = sx + (2 * py) * W + 2 * pxl;
                float mv = fmaxf(fmaxf(r0[0], r0[1]), fmaxf(r0[W], r0[W + 1]));
                out[((size_t)(b * COUT + oc0 + o) * PHT + prow0 + py) * PW + pxl] = mv;
            }
        }
    }
}

// ---------- spatial GAP of X4: xgap[b][c] = mean_p x[b][c][p] ----------
__global__ void __launch_bounds__(256) k_xgap(const float* __restrict__ x,
                                              float* __restrict__ xgap) {
    int b = blockIdx.x, tid = threadIdx.x;
    int wave = tid >> 6, lane = tid & 63;
    for (int c = wave; c < 96; c += 4) {
        const float* row = x + ((size_t)b * 96 + c) * 234;
        float s = 0.f;
        for (int p = lane; p < 234; p += 64) s += row[p];
        #pragma unroll
        for (int off = 1; off < 64; off <<= 1) s += __shfl_xor(s, off);
        if (lane == 0) xgap[b * 96 + c] = s * (1.f / 234.f);
    }
}

// ---------- fused audio attention (both stages) ----------
// v10 (kept): v8 structure + conflict-free column split. ~390us standalone.
__global__ void __launch_bounds__(256, 2) k_audio_attn(
    const float* __restrict__ x,
    const float* __restrict__ wq1, const float* __restrict__ bq1,
    const float* __restrict__ wk1, const float* __restrict__ bk1,
    const float* __restrict__ wv1, const float* __restrict__ bv1,
    const float* __restrict__ wq2, const float* __restrict__ bq2,
    const float* __restrict__ wk2, const float* __restrict__ bk2,
    const float* __restrict__ wv2, const float* __restrict__ bv2,
    float* __restrict__ afeat) {
    const int b = blockIdx.x >> 1, pt = blockIdx.x & 1;
    const int n = blockIdx.y, stage = blockIdx.z;
    const float* wq = (stage ? wq2 : wq1) + n * 9216;   // [c][o] transposed
    const float* wk = (stage ? wk2 : wk1) + n * 9216;
    const float* wv = (stage ? wv2 : wv1) + n * 9216;
    const float* bqn = (stage ? bq2 : bq1) + n * 96;
    const float* bkn = (stage ? bk2 : bk1) + n * 96;
    const float* bvn = (stage ? bv2 : bv1) + n * 96;
    const int tid = threadIdx.x;
    const int to = tid >> 4, tpg = tid & 15;   // o_base = to*6
    const int ob = to * 6;
    const int pA = tpg * 4;                    // cols pA..pA+3 and 64+pA..64+pA+3
    const int p0 = pt * 128;

    __shared__ float sxc[16 * 128];  //  8KB  x chunk [16 c][128 p]
    __shared__ float sw[4608];       // 18KB  weights [3 mats][16 c][96 o]
    float* sred = sw;                // epilogue overlay

    const float* xb = x + (size_t)b * (96 * 234) + p0;

    float qa[6][8], ka[6][8], va[6][8];
    #pragma unroll
    for (int j = 0; j < 6; ++j) {
        float bq_ = bqn[ob + j], bk_ = bkn[ob + j], bv_ = bvn[ob + j];
        #pragma unroll
        for (int i = 0; i < 8; ++i) { qa[j][i] = bq_; ka[j][i] = bk_; va[j][i] = bv_; }
    }

    for (int c0 = 0; c0 < 96; c0 += 16) {
        __syncthreads();
        {   // stage x chunk: 1024 float2 (row stride 936B, 8B-aligned; 234 even)
            #pragma unroll
            for (int it = 0; it < 4; ++it) {
                int e2 = tid + it * 256;
                int r = e2 >> 6, c2 = (e2 & 63) * 2;
                float2 v = make_float2(0.f, 0.f);
                if (p0 + c2 < 234) v = *(const float2*)(xb + (c0 + r) * 234 + c2);
                *(float2*)(sxc + r * 128 + c2) = v;
            }
        }
        for (int e4 = tid; e4 < 1152; e4 += 256) {
            int mat = (e4 >= 768) ? 2 : (e4 >= 384 ? 1 : 0);
            int r4 = e4 - mat * 384;
            const float* wsrc = (mat == 0) ? wq : (mat == 1 ? wk : wv);
            *(float4*)(sw + mat * 1536 + r4 * 4) = *(const float4*)(wsrc + c0 * 96 + r4 * 4);
        }
        __syncthreads();
        #pragma unroll 2
        for (int cc = 0; cc < 16; ++cc) {
            float4 xa = *(const float4*)(sxc + cc * 128 + pA);
            float4 xc = *(const float4*)(sxc + cc * 128 + 64 + pA);
            const float* wr = sw + cc * 96 + ob;
            float2 q01 = *(const float2*)(wr);
            float2 q23 = *(const float2*)(wr + 2);
            float2 q45 = *(const float2*)(wr + 4);
            float2 k01 = *(const float2*)(wr + 1536);
            float2 k23 = *(const float2*)(wr + 1538);
            float2 k45 = *(const float2*)(wr + 1540);
            float2 v01 = *(const float2*)(wr + 3072);
            float2 v23 = *(const float2*)(wr + 3074);
            float2 v45 = *(const float2*)(wr + 3076);
            float wqv[6] = {q01.x, q01.y, q23.x, q23.y, q45.x, q45.y};
            float wkv[6] = {k01.x, k01.y, k23.x, k23.y, k45.x, k45.y};
            float wvv[6] = {v01.x, v01.y, v23.x, v23.y, v45.x, v45.y};
            #pragma unroll
            for (int j = 0; j < 6; ++j) {
                qa[j][0] += wqv[j] * xa.x; qa[j][1] += wqv[j] * xa.y;
                qa[j][2] += wqv[j] * xa.z; qa[j][3] += wqv[j] * xa.w;
                qa[j][4] += wqv[j] * xc.x; qa[j][5] += wqv[j] * xc.y;
                qa[j][6] += wqv[j] * xc.z; qa[j][7] += wqv[j] * xc.w;
                ka[j][0] += wkv[j] * xa.x; ka[j][1] += wkv[j] * xa.y;
                ka[j][2] += wkv[j] * xa.z; ka[j][3] += wkv[j] * xa.w;
                ka[j][4] += wkv[j] * xc.x; ka[j][5] += wkv[j] * xc.y;
                ka[j][6] += wkv[j] * xc.z; ka[j][7] += wkv[j] * xc.w;
                va[j][0] += wvv[j] * xa.x; va[j][1] += wvv[j] * xa.y;
                va[j][2] += wvv[j] * xa.z; va[j][3] += wvv[j] * xa.w;
                va[j][4] += wvv[j] * xc.x; va[j][5] += wvv[j] * xc.y;
                va[j][6] += wvv[j] * xc.z; va[j][7] += wvv[j] * xc.w;
            }
        }
    }

    int col[8];
    #pragma unroll
    for (int i = 0; i < 4; ++i) { col[i] = pA + i; col[4 + i] = 64 + pA + i; }

    float pmx[8];
    #pragma unroll
    for (int i = 0; i < 8; ++i) pmx[i] = -1e30f;
    #pragma unroll
    for (int j = 0; j < 6; ++j)
        #pragma unroll
        for (int i = 0; i < 8; ++i) {
            float sv = qa[j][i] * ka[j][i];
            qa[j][i] = sv;
            pmx[i] = fmaxf(pmx[i], sv);
        }
    __syncthreads();
    #pragma unroll
    for (int i = 0; i < 8; ++i) sred[to * 128 + col[i]] = pmx[i];
    __syncthreads();
    float m_[8];
    #pragma unroll
    for (int i = 0; i < 8; ++i) {
        float mm = -1e30f;
        for (int t = 0; t < 16; ++t) mm = fmaxf(mm, sred[t * 128 + col[i]]);
        m_[i] = mm;
    }
    __syncthreads();
    float z[8];
    #pragma unroll
    for (int i = 0; i < 8; ++i) z[i] = 0.f;
    #pragma unroll
    for (int j = 0; j < 6; ++j)
        #pragma unroll
        for (int i = 0; i < 8; ++i) {
            float e = __expf(qa[j][i] - m_[i]);
            qa[j][i] = e;
            z[i] += e;
        }
    #pragma unroll
    for (int i = 0; i < 8; ++i) sred[to * 128 + col[i]] = z[i];
    __syncthreads();
    float rz[8];
    #pragma unroll
    for (int i = 0; i < 8; ++i) {
        float zs = 0.f;
        for (int t = 0; t < 16; ++t) zs += sred[t * 128 + col[i]];
        rz[i] = (p0 + col[i] < 234) ? 1.f / zs : 0.f;
    }
    __syncthreads();
    #pragma unroll
    for (int j = 0; j < 6; ++j) {
        float po = 0.f;
        #pragma unroll
        for (int i = 0; i < 8; ++i) po += qa[j][i] * rz[i] * va[j][i];
        sred[(ob + j) * 16 + tpg] = po;
    }
    __syncthreads();
    if (tid < 96) {
        float ssum = 0.f;
        #pragma unroll
        for (int t = 0; t < 16; ++t) ssum += sred[tid * 16 + t];
        atomicAdd(afeat + b * 1536 + n * 192 + stage * 96 + tid, ssum * (1.f / 234.f));
    }
}

// ---------- text attention v14: audio-v10 clone over outs_T ----------
__global__ void __launch_bounds__(256, 2) k_text_attn(
    const float* __restrict__ outsT,
    const float* __restrict__ wq1, const float* __restrict__ bq1,
    const float* __restrict__ wk1, const float* __restrict__ bk1,
    const float* __restrict__ wv1, const float* __restrict__ bv1,
    const float* __restrict__ wq2, const float* __restrict__ bq2,
    const float* __restrict__ wk2, const float* __restrict__ bk2,
    const float* __restrict__ wv2, const float* __restrict__ bv2,
    float* __restrict__ tfeat) {
    const int b = blockIdx.x, stage = blockIdx.y, n = blockIdx.z;
    const float* wq = (stage ? wq2 : wq1) + n * 9600;   // [c][o] transposed
    const float* wk = (stage ? wk2 : wk1) + n * 9600;
    const float* wv = (stage ? wv2 : wv1) + n * 9600;
    const float* bqn = (stage ? bq2 : bq1) + n * 96;
    const float* bkn = (stage ? bk2 : bk1) + n * 96;
    const float* bvn = (stage ? bv2 : bv1) + n * 96;
    const int tid = threadIdx.x;
    const int to = tid >> 4, tpg = tid & 15;   // o_base = to*6, t_base = tpg*4
    const int ob = to * 6;
    const int tA = tpg * 4;

    __shared__ float sxc[20 * 64];   //  5KB  rows chunk [20 c][64 t] (t>=50 pad 0)
    __shared__ float sw[5760];       // 22.5KB weights [3 mats][20 c][96 o]
    float* sred = sw;                // epilogue overlay

    const float* xb = outsT + (size_t)b * (100 * kT);

    float qa[6][4], ka[6][4], va[6][4];
    #pragma unroll
    for (int j = 0; j < 6; ++j) {
        float bq_ = bqn[ob + j], bk_ = bkn[ob + j], bv_ = bvn[ob + j];
        #pragma unroll
        for (int i = 0; i < 4; ++i) { qa[j][i] = bq_; ka[j][i] = bk_; va[j][i] = bv_; }
    }

    for (int c0 = 0; c0 < 100; c0 += 20) {
        __syncthreads();
        for (int e = tid; e < 1280; e += 256) {
            int r = e >> 6, tt = e & 63;
            sxc[e] = (tt < kT) ? xb[(c0 + r) * kT + tt] : 0.f;
        }
        for (int e4 = tid; e4 < 1440; e4 += 256) {
            int mat = (e4 >= 960) ? 2 : (e4 >= 480 ? 1 : 0);
            int r4 = e4 - mat * 480;
            const float* wsrc = (mat == 0) ? wq : (mat == 1 ? wk : wv);
            *(float4*)(sw + mat * 1920 + r4 * 4) = *(const float4*)(wsrc + c0 * 96 + r4 * 4);
        }
        __syncthreads();
        #pragma unroll 4
        for (int cc = 0; cc < 20; ++cc) {
            float4 xa = *(const float4*)(sxc + cc * 64 + tA);
            const float* wr = sw + cc * 96 + ob;
            float2 q01 = *(const float2*)(wr);
            float2 q23 = *(const float2*)(wr + 2);
            float2 q45 = *(const float2*)(wr + 4);
            float2 k01 = *(const float2*)(wr + 1920);
            float2 k23 = *(const float2*)(wr + 1922);
            float2 k45 = *(const float2*)(wr + 1924);
            float2 v01 = *(const float2*)(wr + 3840);
            float2 v23 = *(const float2*)(wr + 3842);
            float2 v45 = *(const float2*)(wr + 3844);
            float wqv[6] = {q01.x, q01.y, q23.x, q23.y, q45.x, q45.y};
            float wkv[6] = {k01.x, k01.y, k23.x, k23.y, k45.x, k45.y};
            float wvv[6] = {v01.x, v01.y, v23.x, v23.y, v45.x, v45.y};
            #pragma unroll
            for (int j = 0; j < 6; ++j) {
                qa[j][0] += wqv[j] * xa.x; qa[j][1] += wqv[j] * xa.y;
                qa[j][2] += wqv[j] * xa.z; qa[j][3] += wqv[j] * xa.w;
                ka[j][0] += wkv[j] * xa.x; ka[j][1] += wkv[j] * xa.y;
                ka[j][2] += wkv[j] * xa.z; ka[j][3] += wkv[j] * xa.w;
                va[j][0] += wvv[j] * xa.x; va[j][1] += wvv[j] * xa.y;
                va[j][2] += wvv[j] * xa.z; va[j][3] += wvv[j] * xa.w;
            }
        }
    }

    float pmx[4] = {-1e30f, -1e30f, -1e30f, -1e30f};
    #pragma unroll
    for (int j = 0; j < 6; ++j)
        #pragma unroll
        for (int i = 0; i < 4; ++i) {
            float sv = qa[j][i] * ka[j][i];
            qa[j][i] = sv;
            pmx[i] = fmaxf(pmx[i], sv);
        }
    __syncthreads();
    #pragma unroll
    for (int i = 0; i < 4; ++i) sred[to * 64 + tA + i] = pmx[i];
    __syncthreads();
    float m_[4];
    #pragma unroll
    for (int i = 0; i < 4; ++i) {
        float mm = -1e30f;
        for (int t = 0; t < 16; ++t) mm = fmaxf(mm, sred[t * 64 + tA + i]);
        m_[i] = mm;
    }
    __syncthreads();
    float z[4] = {0.f, 0.f, 0.f, 0.f};
    #pragma unroll
    for (int j = 0; j < 6; ++j)
        #pragma unroll
        for (int i = 0; i < 4; ++i) {
            float e = __expf(qa[j][i] - m_[i]);
            qa[j][i] = e;
            z[i] += e;
        }
    #pragma unroll
    for (int i = 0; i < 4; ++i) sred[to * 64 + tA + i] = z[i];
    __syncthreads();
    float rz[4];
    #pragma unroll
    for (int i = 0; i < 4; ++i) {
        float zs = 0.f;
        for (int t = 0; t < 16; ++t) zs += sred[t * 64 + tA + i];
        rz[i] = (tA + i < kT) ? 1.f / zs : 0.f;
    }
    __syncthreads();
    #pragma unroll
    for (int j = 0; j < 6; ++j) {
        float po = qa[j][0] * rz[0] * va[j][0]
                 + qa[j][1] * rz[1] * va[j][1]
                 + qa[j][2] * rz[2] * va[j][2]
                 + qa[j][3] * rz[3] * va[j][3];
        sred[(ob + j) * 16 + tpg] = po;
    }
    __syncthreads();
    if (tid < 96) {
        float ssum = 0.f;
        #pragma unroll
        for (int t = 0; t < 16; ++t) ssum += sred[tid * 16 + t];
        tfeat[b * 1536 + stage * 768 + n * 96 + tid] = ssum;
    }
}

// ---------- cross-modal gated fusion + final logits ----------
__global__ void __launch_bounds__(128) k_final(const float* __restrict__ xgap,
    const float* __restrict__ outsT, const float* __restrict__ afeat,
    const float* __restrict__ tfeat,
    const float* __restrict__ w_fa, const float* __restrict__ b_fa,
    const float* __restrict__ w_ft, const float* __restrict__ b_ft,
    const float* __restrict__ w_e, const float* __restrict__ b_e,
    float* __restrict__ out) {
    int b = blockIdx.x; int tid = threadIdx.x;
    __shared__ float xg[96], hv[100], st[100], sa[96], aat[96], atba[100];
    __shared__ float redm[2], reds[2];
    if (tid < 96) xg[tid] = xgap[b * 96 + tid];
    if (tid < 100) hv[tid] = outsT[((size_t)b * 100 + tid) * kT + (kT - 1)];
    __syncthreads();
    if (tid < 100) {
        float acc = b_fa[tid];
        const float* wr = w_fa + tid * 96;
        for (int c = 0; c < 96; ++c) acc += wr[c] * xg[c];
        st[tid] = acc;
    }
    if (tid < 96) {
        float acc = b_ft[tid];
        const float* wr = w_ft + tid * 100;
        for (int c = 0; c < 100; ++c) acc += wr[c] * hv[c];
        sa[tid] = acc;
    }
    __syncthreads();
    if (tid == 0) {
        float mxv = -1e30f; for (int i = 0; i < 100; ++i) mxv = fmaxf(mxv, st[i]);
        float s = 0.f; for (int i = 0; i < 100; ++i) s += expf(st[i] - mxv);
        redm[0] = mxv; reds[0] = s;
    }
    if (tid == 1) {
        float mxv = -1e30f; for (int i = 0; i < 96; ++i) mxv = fmaxf(mxv, sa[i]);
        float s = 0.f; for (int i = 0; i < 96; ++i) s += expf(sa[i] - mxv);
        redm[1] = mxv; reds[1] = s;
    }
    __syncthreads();
    if (tid < 100) atba[tid] = expf(st[tid] - redm[0]) / reds[0] * hv[tid];
    if (tid < 96)  aat[tid]  = expf(sa[tid] - redm[1]) / reds[1] * xg[tid];
    __syncthreads();
    float a0 = 0.f, a1 = 0.f, a2 = 0.f, a3 = 0.f;
    for (int col = tid; col < 3268; col += 128) {
        float f;
        if (col < 1536)      f = afeat[b * 1536 + col];
        else if (col < 3072) f = tfeat[b * 1536 + col - 1536];
        else if (col < 3168) f = aat[col - 3072];
        else                 f = atba[col - 3168];
        a0 += w_e[col] * f;            a1 += w_e[3268 + col] * f;
        a2 += w_e[2 * 3268 + col] * f; a3 += w_e[3 * 3268 + col] * f;
    }
    __shared__ float r4[4][128];
    r4[0][tid] = a0; r4[1][tid] = a1; r4[2][tid] = a2; r4[3][tid] = a3;
    __syncthreads();
    if (tid < 4) {
        float s = 0.f;
        for (int i = 0; i < 128; ++i) s += r4[tid][i];
        out[b * 4 + tid] = s + b_e[tid];
    }
}

// =====================================================================
extern "C" void kernel_launch(void* const* d_in, const int* in_sizes, int n_in,
                              void* d_out, int out_size, void* d_ws, size_t ws_size,
                              hipStream_t stream) {
    (void)in_sizes; (void)n_in; (void)out_size; (void)ws_size;
    const float* mfcc_t = (const float*)d_in[0];
    const float* mfcc_f = (const float*)d_in[1];
    const float* mfcc_c = (const float*)d_in[2];
    const int*   tokens = (const int*)d_in[3];
    const float *w1a = (const float*)d_in[5],  *b1a = (const float*)d_in[6],
                *g1a = (const float*)d_in[7],  *be1a = (const float*)d_in[8],
                *m1a = (const float*)d_in[9],  *v1a = (const float*)d_in[10];
    const float *w1b = (const float*)d_in[11], *b1b = (const float*)d_in[12],
                *g1b = (const float*)d_in[13], *be1b = (const float*)d_in[14],
                *m1b = (const float*)d_in[15], *v1b = (const float*)d_in[16];
    const float *w2 = (const float*)d_in[17], *b2 = (const float*)d_in[18],
                *g2 = (const float*)d_in[19], *be2 = (const float*)d_in[20],
                *m2 = (const float*)d_in[21], *v2 = (const float*)d_in[22];
    const float *w3 = (const float*)d_in[23], *b3 = (const float*)d_in[24],
                *g3 = (const float*)d_in[25], *be3 = (const float*)d_in[26],
                *m3 = (const float*)d_in[27], *v3 = (const float*)d_in[28];
    const float *w4 = (const float*)d_in[29], *b4 = (const float*)d_in[30],
                *g4 = (const float*)d_in[31], *be4 = (const float*)d_in[32],
                *m4 = (const float*)d_in[33], *v4 = (const float*)d_in[34];
    const float *wq_a1 = (const float*)d_in[35], *bq_a1 = (const float*)d_in[36],
                *wk_a1 = (const float*)d_in[37], *bk_a1 = (const float*)d_in[38],
                *wv_a1 = (const float*)d_in[39], *bv_a1 = (const float*)d_in[40];
    const float *wq_a2 = (const float*)d_in[41], *bq_a2 = (const float*)d_in[42],
                *wk_a2 = (const float*)d_in[43], *bk_a2 = (const float*)d_in[44],
                *wv_a2 = (const float*)d_in[45], *bv_a2 = (const float*)d_in[46];
    const float *emb  = (const float*)d_in[47];
    const float *w_ih = (const float*)d_in[48], *w_hh = (const float*)d_in[49],
                *b_ih = (const float*)d_in[50], *b_hh = (const float*)d_in[51];
    const float *wq_t1 = (const float*)d_in[52], *bq_t1 = (const float*)d_in[53],
                *wk_t1 = (const float*)d_in[54], *bk_t1 = (const float*)d_in[55],
                *wv_t1 = (const float*)d_in[56], *bv_t1 = (const float*)d_in[57];
    const float *wq_t2 = (const float*)d_in[58], *bq_t2 = (const float*)d_in[59],
                *wk_t2 = (const float*)d_in[60], *bk_t2 = (const float*)d_in[61],
                *wv_t2 = (const float*)d_in[62], *bv_t2 = (const float*)d_in[63];
    const float *w_fa = (const float*)d_in[64], *b_fa = (const float*)d_in[65],
                *w_ft = (const float*)d_in[66], *b_ft = (const float*)d_in[67],
                *w_e  = (const float*)d_in[68], *b_e  = (const float*)d_in[69];

    float* ws = (float*)d_ws;
    const size_t Z0 = 0;                 // GI -> P2 -> X4
    const size_t Z1 = 22091776ull;       // x1 -> P3
    const size_t OUTS  = 34072576ull;    // outs_T[b][c][t]
    const size_t AFEAT = 34712576ull;
    const size_t TFEAT = 34909184ull;    // conv-wT (early) then text features
    const size_t XGAP  = 35105792ull;
    const size_t WT    = 35118080ull;
    float* GI = ws + Z0;                 // dead after fat_stem_gru
    float* X1 = ws + Z1;
    float* P2 = ws + Z0;                 // fused conv2 output (overwrites GI)
    float* P3 = ws + Z1;                 // fused conv3 output (overwrites X1)
    float* X4 = ws + Z0;                 // conv4 output (overwrites P2)
    float* outsT = ws + OUTS;
    float* afeat = ws + AFEAT;
    float* tfeat = ws + TFEAT;
    float* xgap  = ws + XGAP;
    // audio transposed weights [n][c][o], 73728 floats each
    float* wqa1t = ws + WT;
    float* wka1t = wqa1t + 73728; float* wva1t = wka1t + 73728;
    float* wqa2t = wva1t + 73728; float* wka2t = wqa2t + 73728; float* wva2t = wka2t + 73728;
    // text transposed weights [n][c][o], 76800 floats each
    float* wqt1t = wva2t + 73728;
    float* wkt1t = wqt1t + 76800; float* wvt1t = wkt1t + 76800;
    float* wqt2t = wvt1t + 76800; float* wkt2t = wqt2t + 76800; float* wvt2t = wkt2t + 76800;
    // conv weight transposes parked in the tfeat region (dead until text_attn;
    // convs consume them before the text path writes tfeat)
    float* wT2 = tfeat;           //  6,912
    float* wT3 = tfeat + 6912;    // 18,432
    float* wT4 = tfeat + 25344;   // 55,296

    // ----- all weight transposes + afeat zero-fill in ONE launch -----
    TPack tp;
    tp.d[0]  = {wq_a1, wqa1t, 96, 96, 73728};
    tp.d[1]  = {wk_a1, wka1t, 96, 96, 73728};
    tp.d[2]  = {wv_a1, wva1t, 96, 96, 73728};
    tp.d[3]  = {wq_a2, wqa2t, 96, 96, 73728};
    tp.d[4]  = {wk_a2, wka2t, 96, 96, 73728};
    tp.d[5]  = {wv_a2, wva2t, 96, 96, 73728};
    tp.d[6]  = {w2, wT2, 32, 216, 6912};
    tp.d[7]  = {w3, wT3, 64, 288, 18432};
    tp.d[8]  = {w4, wT4, 96, 576, 55296};
    tp.d[9]  = {wq_t1, wqt1t, 96, 100, 76800};
    tp.d[10] = {wk_t1, wkt1t, 96, 100, 76800};
    tp.d[11] = {wv_t1, wvt1t, 96, 100, 76800};
    tp.d[12] = {wq_t2, wqt2t, 96, 100, 76800};
    tp.d[13] = {wk_t2, wkt2t, 96, 100, 76800};
    tp.d[14] = {wv_t2, wvt2t, 96, 100, 76800};
    k_transpose_pack<<<dim3(300, 16), 256, 0, stream>>>(tp, afeat);

    // ----- text-branch input GEMM (GI at Z0, dead after gru) -----
    k_gi<<<kB * kT / 8, 320, 0, stream>>>(tokens, emb, w_ih, b_ih, GI);

    // ----- FAT: gru (128 blocks, writes outs_T) + stem (46800 blocks) -----
    k_fat_stem_gru<<<46928, 256, 0, stream>>>(mfcc_t, mfcc_f, mfcc_c,
        w1a, b1a, g1a, be1a, m1a, v1a,
        w1b, b1b, g1b, be1b, m1b, v1b, X1, 11980800,
        GI, w_hh, b_hh, outsT);

    // ----- conv chain v2: 16-oc blocks, pools fused into conv2/conv3 -----
    // conv2+pool: rows 0..23 in 3x8-row tiles (row 24 dead), out P2 12x78x32
    k_conv16<24, 8, 25, 156, 8, 5, true><<<dim3(128, 3, 2), 256, 0, stream>>>(
        X1, wT2, b2, g2, be2, m2, v2, P2, 32, 12);
    // conv3+pool: out P3 6x39x64
    k_conv16<32, 8, 12, 78, 12, 4, true><<<dim3(128, 1, 4), 256, 0, stream>>>(
        P2, wT3, b3, g3, be3, m3, v3, P3, 64, 6);
    // conv4 (no pool): out X4 6x39x96
    k_conv16<64, 16, 6, 39, 6, 1, false><<<dim3(128, 1, 6), 256, 0, stream>>>(
        P3, wT4, b4, g4, be4, m4, v4, X4, 96, 0);

    // ----- text attention (audio-v10 clone) + xgap -----
    k_text_attn<<<dim3(kB, 2, 8), 256, 0, stream>>>(outsT,
        wqt1t, bq_t1, wkt1t, bk_t1, wvt1t, bv_t1,
        wqt2t, bq_t2, wkt2t, bk_t2, wvt2t, bv_t2, tfeat);
    k_xgap<<<kB, 256, 0, stream>>>(X4, xgap);

    // ----- audio attention v10 (standalone, proven ~390us) -----
    k_audio_attn<<<dim3(kB * 2, 8, 2), 256, 0, stream>>>(X4,
        wqa1t, bq_a1, wka1t, bk_a1, wva1t, bv_a1,
        wqa2t, bq_a2, wka2t, bk_a2, wva2t, bv_a2, afeat);

    // ----- fusion + logits -----
    k_final<<<kB, 128, 0, stream>>>(xgap, outsT, afeat, tfeat,
                                    w_fa, b_fa, w_ft, b_ft, w_e, b_e, (float*)d_out);
}

// Round 15
// 1295.425 us; speedup vs baseline: 1.2201x; 1.0028x over previous
//
#include <hip/hip_runtime.h>
#include <math.h>

// ---------------- constants ----------------
static constexpr int kB = 128;
static constexpr int kT = 50;

// ---------- packed transpose [N][O][C] -> [N][C][O] + afeat zero-fill ----------
struct TDesc { const float* src; float* dst; int O; int C; int total; };
struct TPack { TDesc d[15]; };
__global__ void k_transpose_pack(TPack p, float* __restrict__ za) {
    if (blockIdx.y == 15) {   // zero afeat (196608 floats, atomicAdd target)
        for (int i = blockIdx.x * 256 + threadIdx.x; i < 196608; i += 76800)
            za[i] = 0.f;
        return;
    }
    TDesc t = p.d[blockIdx.y];
    int idx = blockIdx.x * 256 + threadIdx.x;
    if (idx >= t.total) return;
    int o = idx % t.O; int r = idx / t.O; int c = r % t.C; int n = r / t.C;
    t.dst[idx] = t.src[((size_t)n * t.O + o) * t.C + c];
}

// ---------- embedding lookup + input-side GRU GEMM, 8 rows/block ----------
__global__ void __launch_bounds__(320) k_gi(const int* __restrict__ tokens,
        const float* __restrict__ emb, const float* __restrict__ w_ih,
        const float* __restrict__ b_ih, float* __restrict__ GI) {
    int r0 = blockIdx.x * 8;
    int tid = threadIdx.x;
    __shared__ float er[8][200];
    for (int e = tid; e < 1600; e += 320) {
        int r = e / 200, c = e - r * 200;
        er[r][c] = emb[(size_t)tokens[r0 + r] * 200 + c];
    }
    __syncthreads();
    if (tid < 300) {
        float acc[8];
        float bv = b_ih[tid];
        #pragma unroll
        for (int r = 0; r < 8; ++r) acc[r] = bv;
        for (int k4 = 0; k4 < 50; ++k4) {
            float4 w4 = *(const float4*)(w_ih + (size_t)tid * 200 + k4 * 4);
            #pragma unroll
            for (int r = 0; r < 8; ++r) {
                float4 x4 = *(const float4*)&er[r][k4 * 4];
                acc[r] += w4.x * x4.x + w4.y * x4.y + w4.z * x4.z + w4.w * x4.w;
            }
        }
        #pragma unroll
        for (int r = 0; r < 8; ++r)
            GI[(size_t)(r0 + r) * 300 + tid] = acc[r];
    }
}

// ---------- FAT: gru (blocks 0..127) + stem (blocks 128..) ----------
__global__ void __launch_bounds__(256) k_fat_stem_gru(
    const float* __restrict__ mt, const float* __restrict__ mf,
    const float* __restrict__ mc,
    const float* __restrict__ w1a, const float* __restrict__ b1a,
    const float* __restrict__ g1a, const float* __restrict__ be1a,
    const float* __restrict__ m1a, const float* __restrict__ v1a,
    const float* __restrict__ w1b, const float* __restrict__ b1b,
    const float* __restrict__ g1b, const float* __restrict__ be1b,
    const float* __restrict__ m1b, const float* __restrict__ v1b,
    float* __restrict__ out, int total,
    const float* __restrict__ GI, const float* __restrict__ w_hh,
    const float* __restrict__ b_hh, float* __restrict__ outsT) {
    if (blockIdx.x < 128) {
        // ================= gru path (writes outs TRANSPOSED) =================
        const int b = blockIdx.x, tid = threadIdx.x;
        __shared__ float hs[100];
        __shared__ float gH[300];
        const float bias0 = b_hh[tid];
        const float bias1 = (tid < 44) ? b_hh[256 + tid] : 0.f;
        if (tid < 100) hs[tid] = 0.f;
        __syncthreads();
        for (int t = 0; t < kT; ++t) {
            {
                float gh = bias0;
                const float* wr = w_hh + (size_t)tid * 100;
                #pragma unroll
                for (int k4 = 0; k4 < 25; ++k4) {
                    float4 w4 = *(const float4*)(wr + k4 * 4);
                    float4 h4 = *(const float4*)&hs[k4 * 4];
                    gh += w4.x * h4.x + w4.y * h4.y + w4.z * h4.z + w4.w * h4.w;
                }
                gH[tid] = gh;
            }
            if (tid < 44) {
                float gh = bias1;
                const float* wr = w_hh + (size_t)(256 + tid) * 100;
                #pragma unroll
                for (int k4 = 0; k4 < 25; ++k4) {
                    float4 w4 = *(const float4*)(wr + k4 * 4);
                    float4 h4 = *(const float4*)&hs[k4 * 4];
                    gh += w4.x * h4.x + w4.y * h4.y + w4.z * h4.z + w4.w * h4.w;
                }
                gH[256 + tid] = gh;
            }
            __syncthreads();
            if (tid < 100) {
                const float* gi = GI + ((size_t)b * kT + t) * 300;
                float r = 1.f / (1.f + expf(-(gi[tid] + gH[tid])));
                float z = 1.f / (1.f + expf(-(gi[100 + tid] + gH[100 + tid])));
                float nn = tanhf(gi[200 + tid] + r * gH[200 + tid]);
                float h2 = (1.f - z) * nn + z * hs[tid];
                hs[tid] = h2;
                outsT[((size_t)b * 100 + tid) * kT + t] = h2;   // transposed
            }
            __syncthreads();
        }
        return;
    }
    // ================= stem path =================
    int idx = (blockIdx.x - 128) * 256 + threadIdx.x;
    if (idx >= total) return;
    int ox = idx % 156; int t = idx / 156;
    int oy = t % 25; t /= 25;
    int ch = t % 24; int b = t / 24;
    int grp = ch >> 3, c = ch & 7;
    const float* src; int Hc, Wc;
    const float *wb, *cb, *g, *be, *m, *v;
    if (grp == 0) { src = mt; Hc = 196; Wc = 39; wb = w1a + c * 10;
                    cb = b1a; g = g1a; be = be1a; m = m1a; v = v1a; }
    else          { src = (grp == 1 ? mf : mc); Hc = 199; Wc = 35; wb = w1b + c * 12;
                    cb = b1b; g = g1b; be = be1b; m = m1b; v = v1b; }
    float s = g[c] * rsqrtf(v[c] + 1e-5f);
    float bias = (cb[c] - m[c]) * s + be[c];
    float sy = (oy + 0.5f) * ((float)Hc / 25.f) - 0.5f;
    float sx = (ox + 0.5f) * ((float)Wc / 156.f) - 0.5f;
    float fy0 = floorf(sy), fx0 = floorf(sx);
    float fy = sy - fy0, fx = sx - fx0;
    int y0 = (int)fy0, x0 = (int)fx0;
    int y0c = min(max(y0, 0), Hc - 1), y1c = min(max(y0 + 1, 0), Hc - 1);
    int x0c = min(max(x0, 0), Wc - 1), x1c = min(max(x0 + 1, 0), Wc - 1);
    bool xs = (x1c == x0c), ys = (y1c == y0c);
    const float* p = src + (size_t)b * 8000;   // input 200 x 40
    float t00, t01, t10, t11;
    if (grp == 0) {
        float W[6][3];
        #pragma unroll
        for (int r = 0; r < 6; ++r) {
            int rr = min(y0c + r, 199);
            #pragma unroll
            for (int cc = 0; cc < 3; ++cc)
                W[r][cc] = p[rr * 40 + min(x0c + cc, 39)];
        }
        float a00 = 0.f, a01 = 0.f, a10 = 0.f, a11 = 0.f;
        #pragma unroll
        for (int ky = 0; ky < 5; ++ky)
            #pragma unroll
            for (int kx = 0; kx < 2; ++kx) {
                float wv = wb[ky * 2 + kx];
                a00 += W[ky][kx] * wv;     a01 += W[ky][kx + 1] * wv;
                a10 += W[ky + 1][kx] * wv; a11 += W[ky + 1][kx + 1] * wv;
            }
        t00 = a00;
        t01 = xs ? a00 : a01;
        t10 = ys ? a00 : a10;
        t11 = xs ? (ys ? a00 : a10) : (ys ? a01 : a11);
    } else {
        float W[3][7];
        #pragma unroll
        for (int r = 0; r < 3; ++r) {
            int rr = min(y0c + r, 199);
            #pragma unroll
            for (int cc = 0; cc < 7; ++cc)
                W[r][cc] = p[rr * 40 + min(x0c + cc, 39)];
        }
        float a00 = 0.f, a01 = 0.f, a10 = 0.f, a11 = 0.f;
        #pragma unroll
        for (int ky = 0; ky < 2; ++ky)
            #pragma unroll
            for (int kx = 0; kx < 6; ++kx) {
                float wv = wb[ky * 6 + kx];
                a00 += W[ky][kx] * wv;     a01 += W[ky][kx + 1] * wv;
                a10 += W[ky + 1][kx] * wv; a11 += W[ky + 1][kx + 1] * wv;
            }
        t00 = a00;
        t01 = xs ? a00 : a01;
        t10 = ys ? a00 : a10;
        t11 = xs ? (ys ? a00 : a10) : (ys ? a01 : a11);
    }
    float r00 = fmaxf(t00 * s + bias, 0.f), r01 = fmaxf(t01 * s + bias, 0.f);
    float r10 = fmaxf(t10 * s + bias, 0.f), r11 = fmaxf(t11 * s + bias, 0.f);
    out[idx] = r00 * (1.f - fy) * (1.f - fx) + r01 * (1.f - fy) * fx
             + r10 * fy * (1.f - fx) + r11 * fy * fx;
}

// ---------- LDS-tiled 3x3 conv, pad 1, BN(eval)+ReLU, 16-oc blocks,
//            optional fused 2x2/2 maxpool (POOL) ----------
template<int CIN, int CI_T, int H, int W, int ROWS, int NPX, bool POOL>
__global__ void __launch_bounds__(256) k_conv16(
    const float* __restrict__ in, const float* __restrict__ wT,
    const float* __restrict__ cb, const float* __restrict__ g,
    const float* __restrict__ be, const float* __restrict__ m,
    const float* __restrict__ v, float* __restrict__ out, int COUT, int PHT) {
    constexpr int WP = W + 2;
    constexpr int RP = ROWS + 2;
    constexpr int STAGE = CI_T * RP * WP;
    __shared__ float sx[STAGE];
    __shared__ float sw[CI_T * 9 * 16];
    const int b = blockIdx.x, rt = blockIdx.y, oc0 = blockIdx.z * 16;
    const int row0 = rt * ROWS;
    const int tid = threadIdx.x;

    int off[NPX]; bool val[NPX];
    #pragma unroll
    for (int j = 0; j < NPX; ++j) {
        int px = tid + j * 256;
        int oy = px / W, ox = px - oy * W;
        bool ok = (px < ROWS * W) && (row0 + oy < H);
        val[j] = ok;
        off[j] = ok ? (oy * WP + ox) : 0;
    }

    float acc[NPX][16];
    #pragma unroll
    for (int j = 0; j < NPX; ++j)
        #pragma unroll
        for (int o = 0; o < 16; ++o) acc[j][o] = 0.f;

    for (int c0 = 0; c0 < CIN; c0 += CI_T) {
        __syncthreads();
        for (int e = tid; e < STAGE; e += 256) {
            int ci = e / (RP * WP);
            int rem = e - ci * RP * WP;
            int r = rem / WP;
            int xx = rem - r * WP;
            int iy = row0 - 1 + r;
            int ix = xx - 1;
            float vv = 0.f;
            if (iy >= 0 && iy < H && ix >= 0 && ix < W)
                vv = in[((size_t)(b * CIN + c0 + ci) * H + iy) * W + ix];
            sx[e] = vv;
        }
        for (int e = tid; e < CI_T * 9 * 16; e += 256) {
            int rk = e >> 4;
            int o = e & 15;
            sw[e] = wT[((size_t)c0 * 9 + rk) * COUT + oc0 + o];
        }
        __syncthreads();
        #pragma unroll 1
        for (int cl = 0; cl < CI_T; ++cl) {
            const float* sxc = sx + cl * RP * WP;
            #pragma unroll
            for (int k = 0; k < 9; ++k) {
                const int ky = k / 3, kx = k % 3;
                const float* wb_ = sw + (cl * 9 + k) * 16;
                const float4 wa = *(const float4*)(wb_);
                const float4 wb2 = *(const float4*)(wb_ + 4);
                const float4 wc = *(const float4*)(wb_ + 8);
                const float4 wd = *(const float4*)(wb_ + 12);
                #pragma unroll
                for (int j = 0; j < NPX; ++j) {
                    float xv = sxc[off[j] + ky * WP + kx];
                    acc[j][0]  += xv * wa.x;  acc[j][1]  += xv * wa.y;
                    acc[j][2]  += xv * wa.z;  acc[j][3]  += xv * wa.w;
                    acc[j][4]  += xv * wb2.x; acc[j][5]  += xv * wb2.y;
                    acc[j][6]  += xv * wb2.z; acc[j][7]  += xv * wb2.w;
                    acc[j][8]  += xv * wc.x;  acc[j][9]  += xv * wc.y;
                    acc[j][10] += xv * wc.z;  acc[j][11] += xv * wc.w;
                    acc[j][12] += xv * wd.x;  acc[j][13] += xv * wd.y;
                    acc[j][14] += xv * wd.z;  acc[j][15] += xv * wd.w;
                }
            }
        }
    }
    float sc[16], bi[16];
    #pragma unroll
    for (int o = 0; o < 16; ++o) {
        float s = g[oc0 + o] * rsqrtf(v[oc0 + o] + 1e-5f);
        sc[o] = s; bi[o] = (cb[oc0 + o] - m[oc0 + o]) * s + be[oc0 + o];
    }
    if (!POOL) {
        #pragma unroll
        for (int j = 0; j < NPX; ++j) if (val[j]) {
            int px = tid + j * 256;
            int oy = row0 + px / W, ox = px % W;
            #pragma unroll
            for (int o = 0; o < 16; ++o)
                out[((size_t)(b * COUT + oc0 + o) * H + oy) * W + ox] =
                    fmaxf(acc[j][o] * sc[o] + bi[o], 0.f);
        }
    } else {
        constexpr int PH = ROWS / 2, PW = W / 2, PT = PH * PW;
        const int prow0 = rt * PH;
        for (int o = 0; o < 16; ++o) {
            __syncthreads();   // previous oc's max-reads done before scatter
            #pragma unroll
            for (int j = 0; j < NPX; ++j) if (val[j]) {
                int px = tid + j * 256;
                sx[px] = fmaxf(acc[j][o] * sc[o] + bi[o], 0.f);
            }
            __syncthreads();
            for (int e = tid; e < PT; e += 256) {
                int py = e / PW, pxl = e - py * PW;
                const float* r0 = sx + (2 * py) * W + 2 * pxl;
                float mv = fmaxf(fmaxf(r0[0], r0[1]), fmaxf(r0[W], r0[W + 1]));
                out[((size_t)(b * COUT + oc0 + o) * PHT + prow0 + py) * PW + pxl] = mv;
            }
        }
    }
}

// ---------- FAT attn: audio v10 (0..4095) + text v14 (4096..6143) + xgap ----------
// Both attn paths now have IDENTICAL footprints (256 thr, ~28KB LDS,
// launch_bounds(256,2), 2 blocks/CU) — v12's merge failed because text was
// then 128thr/4.5KB and inherited audio's footprint; today inheritance is
// free. Saves 2 launches + 2 kernel drain-tails; text backfills audio drain.
__global__ void __launch_bounds__(256, 2) k_fat_attn(
    const float* __restrict__ x,
    const float* __restrict__ wq1, const float* __restrict__ bq1,
    const float* __restrict__ wk1, const float* __restrict__ bk1,
    const float* __restrict__ wv1, const float* __restrict__ bv1,
    const float* __restrict__ wq2, const float* __restrict__ bq2,
    const float* __restrict__ wk2, const float* __restrict__ bk2,
    const float* __restrict__ wv2, const float* __restrict__ bv2,
    float* __restrict__ afeat,
    const float* __restrict__ outsT,
    const float* __restrict__ wqt1, const float* __restrict__ bqt1,
    const float* __restrict__ wkt1, const float* __restrict__ bkt1,
    const float* __restrict__ wvt1, const float* __restrict__ bvt1,
    const float* __restrict__ wqt2, const float* __restrict__ bqt2,
    const float* __restrict__ wkt2, const float* __restrict__ bkt2,
    const float* __restrict__ wvt2, const float* __restrict__ bvt2,
    float* __restrict__ tfeat, float* __restrict__ xgap) {
    __shared__ float smem[7040];   // union: audio 2048+4608 | text 1280+5760
    const int bx = blockIdx.x;
    const int tid = threadIdx.x;

    if (bx >= 6144) {
        // ================= xgap path =================
        int b = bx - 6144;
        int wave = tid >> 6, lane = tid & 63;
        for (int c = wave; c < 96; c += 4) {
            const float* row = x + ((size_t)b * 96 + c) * 234;
            float s = 0.f;
            for (int p = lane; p < 234; p += 64) s += row[p];
            #pragma unroll
            for (int off = 1; off < 64; off <<= 1) s += __shfl_xor(s, off);
            if (lane == 0) xgap[b * 96 + c] = s * (1.f / 234.f);
        }
        return;
    }
    if (bx >= 4096) {
        // ================= text path (v14 body) =================
        int a = bx - 4096;
        const int b = a & 127;
        int rem = a >> 7;
        const int stage = rem & 1, n = rem >> 1;
        const float* wq = (stage ? wqt2 : wqt1) + n * 9600;
        const float* wk = (stage ? wkt2 : wkt1) + n * 9600;
        const float* wv = (stage ? wvt2 : wvt1) + n * 9600;
        const float* bqn = (stage ? bqt2 : bqt1) + n * 96;
        const float* bkn = (stage ? bkt2 : bkt1) + n * 96;
        const float* bvn = (stage ? bvt2 : bvt1) + n * 96;
        const int to = tid >> 4, tpg = tid & 15;
        const int ob = to * 6;
        const int tA = tpg * 4;
        float* sxc = smem;            // 1280 floats [20 c][64 t]
        float* sw = smem + 1280;      // 5760 floats [3 mats][20 c][96 o]
        float* sred = sw;             // epilogue overlay
        const float* xb = outsT + (size_t)b * (100 * kT);

        float qa[6][4], ka[6][4], va[6][4];
        #pragma unroll
        for (int j = 0; j < 6; ++j) {
            float bq_ = bqn[ob + j], bk_ = bkn[ob + j], bv_ = bvn[ob + j];
            #pragma unroll
            for (int i = 0; i < 4; ++i) { qa[j][i] = bq_; ka[j][i] = bk_; va[j][i] = bv_; }
        }
        for (int c0 = 0; c0 < 100; c0 += 20) {
            __syncthreads();
            for (int e = tid; e < 1280; e += 256) {
                int r = e >> 6, tt = e & 63;
                sxc[e] = (tt < kT) ? xb[(c0 + r) * kT + tt] : 0.f;
            }
            for (int e4 = tid; e4 < 1440; e4 += 256) {
                int mat = (e4 >= 960) ? 2 : (e4 >= 480 ? 1 : 0);
                int r4 = e4 - mat * 480;
                const float* wsrc = (mat == 0) ? wq : (mat == 1 ? wk : wv);
                *(float4*)(sw + mat * 1920 + r4 * 4) = *(const float4*)(wsrc + c0 * 96 + r4 * 4);
            }
            __syncthreads();
            #pragma unroll 4
            for (int cc = 0; cc < 20; ++cc) {
                float4 xa = *(const float4*)(sxc + cc * 64 + tA);
                const float* wr = sw + cc * 96 + ob;
                float2 q01 = *(const float2*)(wr);
                float2 q23 = *(const float2*)(wr + 2);
                float2 q45 = *(const float2*)(wr + 4);
                float2 k01 = *(const float2*)(wr + 1920);
                float2 k23 = *(const float2*)(wr + 1922);
                float2 k45 = *(const float2*)(wr + 1924);
                float2 v01 = *(const float2*)(wr + 3840);
                float2 v23 = *(const float2*)(wr + 3842);
                float2 v45 = *(const float2*)(wr + 3844);
                float wqv[6] = {q01.x, q01.y, q23.x, q23.y, q45.x, q45.y};
                float wkv[6] = {k01.x, k01.y, k23.x, k23.y, k45.x, k45.y};
                float wvv[6] = {v01.x, v01.y, v23.x, v23.y, v45.x, v45.y};
                #pragma unroll
                for (int j = 0; j < 6; ++j) {
                    qa[j][0] += wqv[j] * xa.x; qa[j][1] += wqv[j] * xa.y;
                    qa[j][2] += wqv[j] * xa.z; qa[j][3] += wqv[j] * xa.w;
                    ka[j][0] += wkv[j] * xa.x; ka[j][1] += wkv[j] * xa.y;
                    ka[j][2] += wkv[j] * xa.z; ka[j][3] += wkv[j] * xa.w;
                    va[j][0] += wvv[j] * xa.x; va[j][1] += wvv[j] * xa.y;
                    va[j][2] += wvv[j] * xa.z; va[j][3] += wvv[j] * xa.w;
                }
            }
        }
        float pmx[4] = {-1e30f, -1e30f, -1e30f, -1e30f};
        #pragma unroll
        for (int j = 0; j < 6; ++j)
            #pragma unroll
            for (int i = 0; i < 4; ++i) {
                float sv = qa[j][i] * ka[j][i];
                qa[j][i] = sv;
                pmx[i] = fmaxf(pmx[i], sv);
            }
        __syncthreads();
        #pragma unroll
        for (int i = 0; i < 4; ++i) sred[to * 64 + tA + i] = pmx[i];
        __syncthreads();
        float m_[4];
        #pragma unroll
        for (int i = 0; i < 4; ++i) {
            float mm = -1e30f;
            for (int t = 0; t < 16; ++t) mm = fmaxf(mm, sred[t * 64 + tA + i]);
            m_[i] = mm;
        }
        __syncthreads();
        float z[4] = {0.f, 0.f, 0.f, 0.f};
        #pragma unroll
        for (int j = 0; j < 6; ++j)
            #pragma unroll
            for (int i = 0; i < 4; ++i) {
                float e = __expf(qa[j][i] - m_[i]);
                qa[j][i] = e;
                z[i] += e;
            }
        #pragma unroll
        for (int i = 0; i < 4; ++i) sred[to * 64 + tA + i] = z[i];
        __syncthreads();
        float rz[4];
        #pragma unroll
        for (int i = 0; i < 4; ++i) {
            float zs = 0.f;
            for (int t = 0; t < 16; ++t) zs += sred[t * 64 + tA + i];
            rz[i] = (tA + i < kT) ? 1.f / zs : 0.f;
        }
        __syncthreads();
        #pragma unroll
        for (int j = 0; j < 6; ++j) {
            float po = qa[j][0] * rz[0] * va[j][0]
                     + qa[j][1] * rz[1] * va[j][1]
                     + qa[j][2] * rz[2] * va[j][2]
                     + qa[j][3] * rz[3] * va[j][3];
            sred[(ob + j) * 16 + tpg] = po;
        }
        __syncthreads();
        if (tid < 96) {
            float ssum = 0.f;
            #pragma unroll
            for (int t = 0; t < 16; ++t) ssum += sred[tid * 16 + t];
            tfeat[b * 1536 + stage * 768 + n * 96 + tid] = ssum;
        }
        return;
    }

    // ================= audio path (v10 body) =================
    const int a = bx;
    const int xp = a & 255;
    const int b = xp >> 1, pt = xp & 1;
    const int n = (a >> 8) & 7, stage = a >> 11;
    const float* wq = (stage ? wq2 : wq1) + n * 9216;
    const float* wk = (stage ? wk2 : wk1) + n * 9216;
    const float* wv = (stage ? wv2 : wv1) + n * 9216;
    const float* bqn = (stage ? bq2 : bq1) + n * 96;
    const float* bkn = (stage ? bk2 : bk1) + n * 96;
    const float* bvn = (stage ? bv2 : bv1) + n * 96;
    const int to = tid >> 4, tpg = tid & 15;
    const int ob = to * 6;
    const int pA = tpg * 4;
    const int p0 = pt * 128;

    float* sxc = smem;          // 2048 floats [16 c][128 p]
    float* sw = smem + 2048;    // 4608 floats [3 mats][16 c][96 o]
    float* sred = sw;           // epilogue overlay

    const float* xb = x + (size_t)b * (96 * 234) + p0;

    float qa[6][8], ka[6][8], va[6][8];
    #pragma unroll
    for (int j = 0; j < 6; ++j) {
        float bq_ = bqn[ob + j], bk_ = bkn[ob + j], bv_ = bvn[ob + j];
        #pragma unroll
        for (int i = 0; i < 8; ++i) { qa[j][i] = bq_; ka[j][i] = bk_; va[j][i] = bv_; }
    }

    for (int c0 = 0; c0 < 96; c0 += 16) {
        __syncthreads();
        {
            #pragma unroll
            for (int it = 0; it < 4; ++it) {
                int e2 = tid + it * 256;
                int r = e2 >> 6, c2 = (e2 & 63) * 2;
                float2 v = make_float2(0.f, 0.f);
                if (p0 + c2 < 234) v = *(const float2*)(xb + (c0 + r) * 234 + c2);
                *(float2*)(sxc + r * 128 + c2) = v;
            }
        }
        for (int e4 = tid; e4 < 1152; e4 += 256) {
            int mat = (e4 >= 768) ? 2 : (e4 >= 384 ? 1 : 0);
            int r4 = e4 - mat * 384;
            const float* wsrc = (mat == 0) ? wq : (mat == 1 ? wk : wv);
            *(float4*)(sw + mat * 1536 + r4 * 4) = *(const float4*)(wsrc + c0 * 96 + r4 * 4);
        }
        __syncthreads();
        #pragma unroll 2
        for (int cc = 0; cc < 16; ++cc) {
            float4 xa = *(const float4*)(sxc + cc * 128 + pA);
            float4 xc = *(const float4*)(sxc + cc * 128 + 64 + pA);
            const float* wr = sw + cc * 96 + ob;
            float2 q01 = *(const float2*)(wr);
            float2 q23 = *(const float2*)(wr + 2);
            float2 q45 = *(const float2*)(wr + 4);
            float2 k01 = *(const float2*)(wr + 1536);
            float2 k23 = *(const float2*)(wr + 1538);
            float2 k45 = *(const float2*)(wr + 1540);
            float2 v01 = *(const float2*)(wr + 3072);
            float2 v23 = *(const float2*)(wr + 3074);
            float2 v45 = *(const float2*)(wr + 3076);
            float wqv[6] = {q01.x, q01.y, q23.x, q23.y, q45.x, q45.y};
            float wkv[6] = {k01.x, k01.y, k23.x, k23.y, k45.x, k45.y};
            float wvv[6] = {v01.x, v01.y, v23.x, v23.y, v45.x, v45.y};
            #pragma unroll
            for (int j = 0; j < 6; ++j) {
                qa[j][0] += wqv[j] * xa.x; qa[j][1] += wqv[j] * xa.y;
                qa[j][2] += wqv[j] * xa.z; qa[j][3] += wqv[j] * xa.w;
                qa[j][4] += wqv[j] * xc.x; qa[j][5] += wqv[j] * xc.y;
                qa[j][6] += wqv[j] * xc.z; qa[j][7] += wqv[j] * xc.w;
                ka[j][0] += wkv[j] * xa.x; ka[j][1] += wkv[j] * xa.y;
                ka[j][2] += wkv[j] * xa.z; ka[j][3] += wkv[j] * xa.w;
                ka[j][4] += wkv[j] * xc.x; ka[j][5] += wkv[j] * xc.y;
                ka[j][6] += wkv[j] * xc.z; ka[j][7] += wkv[j] * xc.w;
                va[j][0] += wvv[j] * xa.x; va[j][1] += wvv[j] * xa.y;
                va[j][2] += wvv[j] * xa.z; va[j][3] += wvv[j] * xa.w;
                va[j][4] += wvv[j] * xc.x; va[j][5] += wvv[j] * xc.y;
                va[j][6] += wvv[j] * xc.z; va[j][7] += wvv[j] * xc.w;
            }
        }
    }

    int col[8];
    #pragma unroll
    for (int i = 0; i < 4; ++i) { col[i] = pA + i; col[4 + i] = 64 + pA + i; }

    float pmx[8];
    #pragma unroll
    for (int i = 0; i < 8; ++i) pmx[i] = -1e30f;
    #pragma unroll
    for (int j = 0; j < 6; ++j)
        #pragma unroll
        for (int i = 0; i < 8; ++i) {
            float sv = qa[j][i] * ka[j][i];
            qa[j][i] = sv;
            pmx[i] = fmaxf(pmx[i], sv);
        }
    __syncthreads();
    #pragma unroll
    for (int i = 0; i < 8; ++i) sred[to * 128 + col[i]] = pmx[i];
    __syncthreads();
    float m_[8];
    #pragma unroll
    for (int i = 0; i < 8; ++i) {
        float mm = -1e30f;
        for (int t = 0; t < 16; ++t) mm = fmaxf(mm, sred[t * 128 + col[i]]);
        m_[i] = mm;
    }
    __syncthreads();
    float z[8];
    #pragma unroll
    for (int i = 0; i < 8; ++i) z[i] = 0.f;
    #pragma unroll
    for (int j = 0; j < 6; ++j)
        #pragma unroll
        for (int i = 0; i < 8; ++i) {
            float e = __expf(qa[j][i] - m_[i]);
            qa[j][i] = e;
            z[i] += e;
        }
    #pragma unroll
    for (int i = 0; i < 8; ++i) sred[to * 128 + col[i]] = z[i];
    __syncthreads();
    float rz[8];
    #pragma unroll
    for (int i = 0; i < 8; ++i) {
        float zs = 0.f;
        for (int t = 0; t < 16; ++t) zs += sred[t * 128 + col[i]];
        rz[i] = (p0 + col[i] < 234) ? 1.f / zs : 0.f;
    }
    __syncthreads();
    #pragma unroll
    for (int j = 0; j < 6; ++j) {
        float po = 0.f;
        #pragma unroll
        for (int i = 0; i < 8; ++i) po += qa[j][i] * rz[i] * va[j][i];
        sred[(ob + j) * 16 + tpg] = po;
    }
    __syncthreads();
    if (tid < 96) {
        float ssum = 0.f;
        #pragma unroll
        for (int t = 0; t < 16; ++t) ssum += sred[tid * 16 + t];
        atomicAdd(afeat + b * 1536 + n * 192 + stage * 96 + tid, ssum * (1.f / 234.f));
    }
}

// ---------- cross-modal gated fusion + final logits ----------
__global__ void __launch_bounds__(128) k_final(const float* __restrict__ xgap,
    const float* __restrict__ outsT, const float* __restrict__ afeat,
    const float* __restrict__ tfeat,
    const float* __restrict__ w_fa, const float* __restrict__ b_fa,
    const float* __restrict__ w_ft, const float* __restrict__ b_ft,
    const float* __restrict__ w_e, const float* __restrict__ b_e,
    float* __restrict__ out) {
    int b = blockIdx.x; int tid = threadIdx.x;
    __shared__ float xg[96], hv[100], st[100], sa[96], aat[96], atba[100];
    __shared__ float redm[2], reds[2];
    if (tid < 96) xg[tid] = xgap[b * 96 + tid];
    if (tid < 100) hv[tid] = outsT[((size_t)b * 100 + tid) * kT + (kT - 1)];
    __syncthreads();
    if (tid < 100) {
        float acc = b_fa[tid];
        const float* wr = w_fa + tid * 96;
        for (int c = 0; c < 96; ++c) acc += wr[c] * xg[c];
        st[tid] = acc;
    }
    if (tid < 96) {
        float acc = b_ft[tid];
        const float* wr = w_ft + tid * 100;
        for (int c = 0; c < 100; ++c) acc += wr[c] * hv[c];
        sa[tid] = acc;
    }
    __syncthreads();
    if (tid == 0) {
        float mxv = -1e30f; for (int i = 0; i < 100; ++i) mxv = fmaxf(mxv, st[i]);
        float s = 0.f; for (int i = 0; i < 100; ++i) s += expf(st[i] - mxv);
        redm[0] = mxv; reds[0] = s;
    }
    if (tid == 1) {
        float mxv = -1e30f; for (int i = 0; i < 96; ++i) mxv = fmaxf(mxv, sa[i]);
        float s = 0.f; for (int i = 0; i < 96; ++i) s += expf(sa[i] - mxv);
        redm[1] = mxv; reds[1] = s;
    }
    __syncthreads();
    if (tid < 100) atba[tid] = expf(st[tid] - redm[0]) / reds[0] * hv[tid];
    if (tid < 96)  aat[tid]  = expf(sa[tid] - redm[1]) / reds[1] * xg[tid];
    __syncthreads();
    float a0 = 0.f, a1 = 0.f, a2 = 0.f, a3 = 0.f;
    for (int col = tid; col < 3268; col += 128) {
        float f;
        if (col < 1536)      f = afeat[b * 1536 + col];
        else if (col < 3072) f = tfeat[b * 1536 + col - 1536];
        else if (col < 3168) f = aat[col - 3072];
        else                 f = atba[col - 3168];
        a0 += w_e[col] * f;            a1 += w_e[3268 + col] * f;
        a2 += w_e[2 * 3268 + col] * f; a3 += w_e[3 * 3268 + col] * f;
    }
    __shared__ float r4[4][128];
    r4[0][tid] = a0; r4[1][tid] = a1; r4[2][tid] = a2; r4[3][tid] = a3;
    __syncthreads();
    if (tid < 4) {
        float s = 0.f;
        for (int i = 0; i < 128; ++i) s += r4[tid][i];
        out[b * 4 + tid] = s + b_e[tid];
    }
}

// =====================================================================
extern "C" void kernel_launch(void* const* d_in, const int* in_sizes, int n_in,
                              void* d_out, int out_size, void* d_ws, size_t ws_size,
                              hipStream_t stream) {
    (void)in_sizes; (void)n_in; (void)out_size; (void)ws_size;
    const float* mfcc_t = (const float*)d_in[0];
    const float* mfcc_f = (const float*)d_in[1];
    const float* mfcc_c = (const float*)d_in[2];
    const int*   tokens = (const int*)d_in[3];
    const float *w1a = (const float*)d_in[5],  *b1a = (const float*)d_in[6],
                *g1a = (const float*)d_in[7],  *be1a = (const float*)d_in[8],
                *m1a = (const float*)d_in[9],  *v1a = (const float*)d_in[10];
    const float *w1b = (const float*)d_in[11], *b1b = (const float*)d_in[12],
                *g1b = (const float*)d_in[13], *be1b = (const float*)d_in[14],
                *m1b = (const float*)d_in[15], *v1b = (const float*)d_in[16];
    const float *w2 = (const float*)d_in[17], *b2 = (const float*)d_in[18],
                *g2 = (const float*)d_in[19], *be2 = (const float*)d_in[20],
                *m2 = (const float*)d_in[21], *v2 = (const float*)d_in[22];
    const float *w3 = (const float*)d_in[23], *b3 = (const float*)d_in[24],
                *g3 = (const float*)d_in[25], *be3 = (const float*)d_in[26],
                *m3 = (const float*)d_in[27], *v3 = (const float*)d_in[28];
    const float *w4 = (const float*)d_in[29], *b4 = (const float*)d_in[30],
                *g4 = (const float*)d_in[31], *be4 = (const float*)d_in[32],
                *m4 = (const float*)d_in[33], *v4 = (const float*)d_in[34];
    const float *wq_a1 = (const float*)d_in[35], *bq_a1 = (const float*)d_in[36],
                *wk_a1 = (const float*)d_in[37], *bk_a1 = (const float*)d_in[38],
                *wv_a1 = (const float*)d_in[39], *bv_a1 = (const float*)d_in[40];
    const float *wq_a2 = (const float*)d_in[41], *bq_a2 = (const float*)d_in[42],
                *wk_a2 = (const float*)d_in[43], *bk_a2 = (const float*)d_in[44],
                *wv_a2 = (const float*)d_in[45], *bv_a2 = (const float*)d_in[46];
    const float *emb  = (const float*)d_in[47];
    const float *w_ih = (const float*)d_in[48], *w_hh = (const float*)d_in[49],
                *b_ih = (const float*)d_in[50], *b_hh = (const float*)d_in[51];
    const float *wq_t1 = (const float*)d_in[52], *bq_t1 = (const float*)d_in[53],
                *wk_t1 = (const float*)d_in[54], *bk_t1 = (const float*)d_in[55],
                *wv_t1 = (const float*)d_in[56], *bv_t1 = (const float*)d_in[57];
    const float *wq_t2 = (const float*)d_in[58], *bq_t2 = (const float*)d_in[59],
                *wk_t2 = (const float*)d_in[60], *bk_t2 = (const float*)d_in[61],
                *wv_t2 = (const float*)d_in[62], *bv_t2 = (const float*)d_in[63];
    const float *w_fa = (const float*)d_in[64], *b_fa = (const float*)d_in[65],
                *w_ft = (const float*)d_in[66], *b_ft = (const float*)d_in[67],
                *w_e  = (const float*)d_in[68], *b_e  = (const float*)d_in[69];

    float* ws = (float*)d_ws;
    const size_t Z0 = 0;                 // GI -> P2 -> X4
    const size_t Z1 = 22091776ull;       // x1 -> P3
    const size_t OUTS  = 34072576ull;    // outs_T[b][c][t]
    const size_t AFEAT = 34712576ull;
    const size_t TFEAT = 34909184ull;    // conv-wT (early) then text features
    const size_t XGAP  = 35105792ull;
    const size_t WT    = 35118080ull;
    float* GI = ws + Z0;                 // dead after fat_stem_gru
    float* X1 = ws + Z1;
    float* P2 = ws + Z0;                 // fused conv2 output (overwrites GI)
    float* P3 = ws + Z1;                 // fused conv3 output (overwrites X1)
    float* X4 = ws + Z0;                 // conv4 output (overwrites P2)
    float* outsT = ws + OUTS;
    float* afeat = ws + AFEAT;
    float* tfeat = ws + TFEAT;
    float* xgap  = ws + XGAP;
    // audio transposed weights [n][c][o], 73728 floats each
    float* wqa1t = ws + WT;
    float* wka1t = wqa1t + 73728; float* wva1t = wka1t + 73728;
    float* wqa2t = wva1t + 73728; float* wka2t = wqa2t + 73728; float* wva2t = wka2t + 73728;
    // text transposed weights [n][c][o], 76800 floats each
    float* wqt1t = wva2t + 73728;
    float* wkt1t = wqt1t + 76800; float* wvt1t = wkt1t + 76800;
    float* wqt2t = wvt1t + 76800; float* wkt2t = wqt2t + 76800; float* wvt2t = wkt2t + 76800;
    // conv weight transposes parked in the tfeat region (dead until fat_attn;
    // convs consume them before the text path writes tfeat)
    float* wT2 = tfeat;           //  6,912
    float* wT3 = tfeat + 6912;    // 18,432
    float* wT4 = tfeat + 25344;   // 55,296

    // ----- all weight transposes + afeat zero-fill in ONE launch -----
    TPack tp;
    tp.d[0]  = {wq_a1, wqa1t, 96, 96, 73728};
    tp.d[1]  = {wk_a1, wka1t, 96, 96, 73728};
    tp.d[2]  = {wv_a1, wva1t, 96, 96, 73728};
    tp.d[3]  = {wq_a2, wqa2t, 96, 96, 73728};
    tp.d[4]  = {wk_a2, wka2t, 96, 96, 73728};
    tp.d[5]  = {wv_a2, wva2t, 96, 96, 73728};
    tp.d[6]  = {w2, wT2, 32, 216, 6912};
    tp.d[7]  = {w3, wT3, 64, 288, 18432};
    tp.d[8]  = {w4, wT4, 96, 576, 55296};
    tp.d[9]  = {wq_t1, wqt1t, 96, 100, 76800};
    tp.d[10] = {wk_t1, wkt1t, 96, 100, 76800};
    tp.d[11] = {wv_t1, wvt1t, 96, 100, 76800};
    tp.d[12] = {wq_t2, wqt2t, 96, 100, 76800};
    tp.d[13] = {wk_t2, wkt2t, 96, 100, 76800};
    tp.d[14] = {wv_t2, wvt2t, 96, 100, 76800};
    k_transpose_pack<<<dim3(300, 16), 256, 0, stream>>>(tp, afeat);

    // ----- text-branch input GEMM (GI at Z0, dead after gru) -----
    k_gi<<<kB * kT / 8, 320, 0, stream>>>(tokens, emb, w_ih, b_ih, GI);

    // ----- FAT: gru (128 blocks, writes outs_T) + stem (46800 blocks) -----
    k_fat_stem_gru<<<46928, 256, 0, stream>>>(mfcc_t, mfcc_f, mfcc_c,
        w1a, b1a, g1a, be1a, m1a, v1a,
        w1b, b1b, g1b, be1b, m1b, v1b, X1, 11980800,
        GI, w_hh, b_hh, outsT);

    // ----- conv chain v2: 16-oc blocks, pools fused into conv2/conv3 -----
    k_conv16<24, 8, 25, 156, 8, 5, true><<<dim3(128, 3, 2), 256, 0, stream>>>(
        X1, wT2, b2, g2, be2, m2, v2, P2, 32, 12);
    k_conv16<32, 8, 12, 78, 12, 4, true><<<dim3(128, 1, 4), 256, 0, stream>>>(
        P2, wT3, b3, g3, be3, m3, v3, P3, 64, 6);
    k_conv16<64, 16, 6, 39, 6, 1, false><<<dim3(128, 1, 6), 256, 0, stream>>>(
        P3, wT4, b4, g4, be4, m4, v4, X4, 96, 0);

    // ----- FAT attn: audio (first) + text + xgap, identical footprints -----
    k_fat_attn<<<6272, 256, 0, stream>>>(X4,
        wqa1t, bq_a1, wka1t, bk_a1, wva1t, bv_a1,
        wqa2t, bq_a2, wka2t, bk_a2, wva2t, bv_a2, afeat,
        outsT,
        wqt1t, bq_t1, wkt1t, bk_t1, wvt1t, bv_t1,
        wqt2t, bq_t2, wkt2t, bk_t2, wvt2t, bv_t2, tfeat, xgap);

    // ----- fusion + logits -----
    k_final<<<kB, 128, 0, stream>>>(xgap, outsT, afeat, tfeat,
                                    w_fa, b_fa, w_ft, b_ft, w_e, b_e, (float*)d_out);
}

// Round 16
// 1280.840 us; speedup vs baseline: 1.2340x; 1.0114x over previous
//
#include <hip/hip_runtime.h>
#include <math.h>

// ---------------- constants ----------------
static constexpr int kB = 128;
static constexpr int kT = 50;

// ---------- packed transpose [N][O][C] -> [N][C][O] + afeat zero-fill ----------
struct TDesc { const float* src; float* dst; int O; int C; int total; };
struct TPack { TDesc d[15]; };
__global__ void k_transpose_pack(TPack p, float* __restrict__ za) {
    if (blockIdx.y == 15) {   // zero afeat (196608 floats, atomicAdd target)
        for (int i = blockIdx.x * 256 + threadIdx.x; i < 196608; i += 76800)
            za[i] = 0.f;
        return;
    }
    TDesc t = p.d[blockIdx.y];
    int idx = blockIdx.x * 256 + threadIdx.x;
    if (idx >= t.total) return;
    int o = idx % t.O; int r = idx / t.O; int c = r % t.C; int n = r / t.C;
    t.dst[idx] = t.src[((size_t)n * t.O + o) * t.C + c];
}

// ---------- embedding lookup + input-side GRU GEMM, 8 rows/block ----------
__global__ void __launch_bounds__(320) k_gi(const int* __restrict__ tokens,
        const float* __restrict__ emb, const float* __restrict__ w_ih,
        const float* __restrict__ b_ih, float* __restrict__ GI) {
    int r0 = blockIdx.x * 8;
    int tid = threadIdx.x;
    __shared__ float er[8][200];
    for (int e = tid; e < 1600; e += 320) {
        int r = e / 200, c = e - r * 200;
        er[r][c] = emb[(size_t)tokens[r0 + r] * 200 + c];
    }
    __syncthreads();
    if (tid < 300) {
        float acc[8];
        float bv = b_ih[tid];
        #pragma unroll
        for (int r = 0; r < 8; ++r) acc[r] = bv;
        for (int k4 = 0; k4 < 50; ++k4) {
            float4 w4 = *(const float4*)(w_ih + (size_t)tid * 200 + k4 * 4);
            #pragma unroll
            for (int r = 0; r < 8; ++r) {
                float4 x4 = *(const float4*)&er[r][k4 * 4];
                acc[r] += w4.x * x4.x + w4.y * x4.y + w4.z * x4.z + w4.w * x4.w;
            }
        }
        #pragma unroll
        for (int r = 0; r < 8; ++r)
            GI[(size_t)(r0 + r) * 300 + tid] = acc[r];
    }
}

// ---------- FAT: gru (blocks 0..127) + stem v2 (blocks 128..) ----------
// stem v2: thread = (b, grp, oy, ox) computing ALL 8 channels of the group.
// The 18-21-element source window is loaded ONCE (was 8x redundant across the
// old per-channel threads); per c only weights (L1-broadcast) + 40 FMAs + BN
// + bilinear. Global window traffic /8, per-output mem ops ~30 -> ~15,
// address/clamp math amortized 8x. Writes coalesced (lanes adjacent in ox).
__global__ void __launch_bounds__(256) k_fat_stem_gru(
    const float* __restrict__ mt, const float* __restrict__ mf,
    const float* __restrict__ mc,
    const float* __restrict__ w1a, const float* __restrict__ b1a,
    const float* __restrict__ g1a, const float* __restrict__ be1a,
    const float* __restrict__ m1a, const float* __restrict__ v1a,
    const float* __restrict__ w1b, const float* __restrict__ b1b,
    const float* __restrict__ g1b, const float* __restrict__ be1b,
    const float* __restrict__ m1b, const float* __restrict__ v1b,
    float* __restrict__ out, int total,
    const float* __restrict__ GI, const float* __restrict__ w_hh,
    const float* __restrict__ b_hh, float* __restrict__ outsT) {
    if (blockIdx.x < 128) {
        // ================= gru path (writes outs TRANSPOSED) =================
        const int b = blockIdx.x, tid = threadIdx.x;
        __shared__ float hs[100];
        __shared__ float gH[300];
        const float bias0 = b_hh[tid];
        const float bias1 = (tid < 44) ? b_hh[256 + tid] : 0.f;
        if (tid < 100) hs[tid] = 0.f;
        __syncthreads();
        for (int t = 0; t < kT; ++t) {
            {
                float gh = bias0;
                const float* wr = w_hh + (size_t)tid * 100;
                #pragma unroll
                for (int k4 = 0; k4 < 25; ++k4) {
                    float4 w4 = *(const float4*)(wr + k4 * 4);
                    float4 h4 = *(const float4*)&hs[k4 * 4];
                    gh += w4.x * h4.x + w4.y * h4.y + w4.z * h4.z + w4.w * h4.w;
                }
                gH[tid] = gh;
            }
            if (tid < 44) {
                float gh = bias1;
                const float* wr = w_hh + (size_t)(256 + tid) * 100;
                #pragma unroll
                for (int k4 = 0; k4 < 25; ++k4) {
                    float4 w4 = *(const float4*)(wr + k4 * 4);
                    float4 h4 = *(const float4*)&hs[k4 * 4];
                    gh += w4.x * h4.x + w4.y * h4.y + w4.z * h4.z + w4.w * h4.w;
                }
                gH[256 + tid] = gh;
            }
            __syncthreads();
            if (tid < 100) {
                const float* gi = GI + ((size_t)b * kT + t) * 300;
                float r = 1.f / (1.f + expf(-(gi[tid] + gH[tid])));
                float z = 1.f / (1.f + expf(-(gi[100 + tid] + gH[100 + tid])));
                float nn = tanhf(gi[200 + tid] + r * gH[200 + tid]);
                float h2 = (1.f - z) * nn + z * hs[tid];
                hs[tid] = h2;
                outsT[((size_t)b * 100 + tid) * kT + t] = h2;   // transposed
            }
            __syncthreads();
        }
        return;
    }
    // ================= stem v2 path =================
    int idx = (blockIdx.x - 128) * 256 + threadIdx.x;
    if (idx >= total) return;           // total = 128*3*25*156 = 1497600
    int ox = idx % 156; int t = idx / 156;
    int oy = t % 25; t /= 25;
    int grp = t % 3; int b = t / 3;
    const float* src; int Hc, Wc;
    const float *wb0, *cb, *g, *be, *m, *v;
    if (grp == 0) { src = mt; Hc = 196; Wc = 39; wb0 = w1a;
                    cb = b1a; g = g1a; be = be1a; m = m1a; v = v1a; }
    else          { src = (grp == 1 ? mf : mc); Hc = 199; Wc = 35; wb0 = w1b;
                    cb = b1b; g = g1b; be = be1b; m = m1b; v = v1b; }
    float sy = (oy + 0.5f) * ((float)Hc / 25.f) - 0.5f;
    float sx = (ox + 0.5f) * ((float)Wc / 156.f) - 0.5f;
    float fy0 = floorf(sy), fx0 = floorf(sx);
    float fy = sy - fy0, fx = sx - fx0;
    int y0 = (int)fy0, x0 = (int)fx0;
    int y0c = min(max(y0, 0), Hc - 1), y1c = min(max(y0 + 1, 0), Hc - 1);
    int x0c = min(max(x0, 0), Wc - 1), x1c = min(max(x0 + 1, 0), Wc - 1);
    bool xs = (x1c == x0c), ys = (y1c == y0c);
    const float* p = src + (size_t)b * 8000;   // input 200 x 40
    float* ob_ = out + (((size_t)b * 24 + grp * 8) * 25 + oy) * 156 + ox;
    const float w00 = (1.f - fy) * (1.f - fx), w01 = (1.f - fy) * fx;
    const float w10 = fy * (1.f - fx),         w11 = fy * fx;
    if (grp == 0) {
        float W[6][3];
        #pragma unroll
        for (int r = 0; r < 6; ++r) {
            int rr = min(y0c + r, 199);
            #pragma unroll
            for (int cc = 0; cc < 3; ++cc)
                W[r][cc] = p[rr * 40 + min(x0c + cc, 39)];
        }
        #pragma unroll
        for (int c = 0; c < 8; ++c) {
            const float* wb = wb0 + c * 10;
            float a00 = 0.f, a01 = 0.f, a10 = 0.f, a11 = 0.f;
            #pragma unroll
            for (int ky = 0; ky < 5; ++ky)
                #pragma unroll
                for (int kx = 0; kx < 2; ++kx) {
                    float wv = wb[ky * 2 + kx];
                    a00 += W[ky][kx] * wv;     a01 += W[ky][kx + 1] * wv;
                    a10 += W[ky + 1][kx] * wv; a11 += W[ky + 1][kx + 1] * wv;
                }
            float t00 = a00;
            float t01 = xs ? a00 : a01;
            float t10 = ys ? a00 : a10;
            float t11 = xs ? (ys ? a00 : a10) : (ys ? a01 : a11);
            float s = g[c] * rsqrtf(v[c] + 1e-5f);
            float bias = (cb[c] - m[c]) * s + be[c];
            float r00 = fmaxf(t00 * s + bias, 0.f), r01 = fmaxf(t01 * s + bias, 0.f);
            float r10 = fmaxf(t10 * s + bias, 0.f), r11 = fmaxf(t11 * s + bias, 0.f);
            ob_[c * 3900] = r00 * w00 + r01 * w01 + r10 * w10 + r11 * w11;
        }
    } else {
        float W[3][7];
        #pragma unroll
        for (int r = 0; r < 3; ++r) {
            int rr = min(y0c + r, 199);
            #pragma unroll
            for (int cc = 0; cc < 7; ++cc)
                W[r][cc] = p[rr * 40 + min(x0c + cc, 39)];
        }
        #pragma unroll
        for (int c = 0; c < 8; ++c) {
            const float* wb = wb0 + c * 12;
            float a00 = 0.f, a01 = 0.f, a10 = 0.f, a11 = 0.f;
            #pragma unroll
            for (int ky = 0; ky < 2; ++ky)
                #pragma unroll
                for (int kx = 0; kx < 6; ++kx) {
                    float wv = wb[ky * 6 + kx];
                    a00 += W[ky][kx] * wv;     a01 += W[ky][kx + 1] * wv;
                    a10 += W[ky + 1][kx] * wv; a11 += W[ky + 1][kx + 1] * wv;
                }
            float t00 = a00;
            float t01 = xs ? a00 : a01;
            float t10 = ys ? a00 : a10;
            float t11 = xs ? (ys ? a00 : a10) : (ys ? a01 : a11);
            float s = g[c] * rsqrtf(v[c] + 1e-5f);
            float bias = (cb[c] - m[c]) * s + be[c];
            float r00 = fmaxf(t00 * s + bias, 0.f), r01 = fmaxf(t01 * s + bias, 0.f);
            float r10 = fmaxf(t10 * s + bias, 0.f), r11 = fmaxf(t11 * s + bias, 0.f);
            ob_[c * 3900] = r00 * w00 + r01 * w01 + r10 * w10 + r11 * w11;
        }
    }
}

// ---------- LDS-tiled 3x3 conv, pad 1, BN(eval)+ReLU, 16-oc blocks,
//            optional fused 2x2/2 maxpool (POOL) ----------
template<int CIN, int CI_T, int H, int W, int ROWS, int NPX, bool POOL>
__global__ void __launch_bounds__(256) k_conv16(
    const float* __restrict__ in, const float* __restrict__ wT,
    const float* __restrict__ cb, const float* __restrict__ g,
    const float* __restrict__ be, const float* __restrict__ m,
    const float* __restrict__ v, float* __restrict__ out, int COUT, int PHT) {
    constexpr int WP = W + 2;
    constexpr int RP = ROWS + 2;
    constexpr int STAGE = CI_T * RP * WP;
    __shared__ float sx[STAGE];
    __shared__ float sw[CI_T * 9 * 16];
    const int b = blockIdx.x, rt = blockIdx.y, oc0 = blockIdx.z * 16;
    const int row0 = rt * ROWS;
    const int tid = threadIdx.x;

    int off[NPX]; bool val[NPX];
    #pragma unroll
    for (int j = 0; j < NPX; ++j) {
        int px = tid + j * 256;
        int oy = px / W, ox = px - oy * W;
        bool ok = (px < ROWS * W) && (row0 + oy < H);
        val[j] = ok;
        off[j] = ok ? (oy * WP + ox) : 0;
    }

    float acc[NPX][16];
    #pragma unroll
    for (int j = 0; j < NPX; ++j)
        #pragma unroll
        for (int o = 0; o < 16; ++o) acc[j][o] = 0.f;

    for (int c0 = 0; c0 < CIN; c0 += CI_T) {
        __syncthreads();
        for (int e = tid; e < STAGE; e += 256) {
            int ci = e / (RP * WP);
            int rem = e - ci * RP * WP;
            int r = rem / WP;
            int xx = rem - r * WP;
            int iy = row0 - 1 + r;
            int ix = xx - 1;
            float vv = 0.f;
            if (iy >= 0 && iy < H && ix >= 0 && ix < W)
                vv = in[((size_t)(b * CIN + c0 + ci) * H + iy) * W + ix];
            sx[e] = vv;
        }
        for (int e = tid; e < CI_T * 9 * 16; e += 256) {
            int rk = e >> 4;
            int o = e & 15;
            sw[e] = wT[((size_t)c0 * 9 + rk) * COUT + oc0 + o];
        }
        __syncthreads();
        #pragma unroll 1
        for (int cl = 0; cl < CI_T; ++cl) {
            const float* sxc = sx + cl * RP * WP;
            #pragma unroll
            for (int k = 0; k < 9; ++k) {
                const int ky = k / 3, kx = k % 3;
                const float* wb_ = sw + (cl * 9 + k) * 16;
                const float4 wa = *(const float4*)(wb_);
                const float4 wb2 = *(const float4*)(wb_ + 4);
                const float4 wc = *(const float4*)(wb_ + 8);
                const float4 wd = *(const float4*)(wb_ + 12);
                #pragma unroll
                for (int j = 0; j < NPX; ++j) {
                    float xv = sxc[off[j] + ky * WP + kx];
                    acc[j][0]  += xv * wa.x;  acc[j][1]  += xv * wa.y;
                    acc[j][2]  += xv * wa.z;  acc[j][3]  += xv * wa.w;
                    acc[j][4]  += xv * wb2.x; acc[j][5]  += xv * wb2.y;
                    acc[j][6]  += xv * wb2.z; acc[j][7]  += xv * wb2.w;
                    acc[j][8]  += xv * wc.x;  acc[j][9]  += xv * wc.y;
                    acc[j][10] += xv * wc.z;  acc[j][11] += xv * wc.w;
                    acc[j][12] += xv * wd.x;  acc[j][13] += xv * wd.y;
                    acc[j][14] += xv * wd.z;  acc[j][15] += xv * wd.w;
                }
            }
        }
    }
    float sc[16], bi[16];
    #pragma unroll
    for (int o = 0; o < 16; ++o) {
        float s = g[oc0 + o] * rsqrtf(v[oc0 + o] + 1e-5f);
        sc[o] = s; bi[o] = (cb[oc0 + o] - m[oc0 + o]) * s + be[oc0 + o];
    }
    if (!POOL) {
        #pragma unroll
        for (int j = 0; j < NPX; ++j) if (val[j]) {
            int px = tid + j * 256;
            int oy = row0 + px / W, ox = px % W;
            #pragma unroll
            for (int o = 0; o < 16; ++o)
                out[((size_t)(b * COUT + oc0 + o) * H + oy) * W + ox] =
                    fmaxf(acc[j][o] * sc[o] + bi[o], 0.f);
        }
    } else {
        constexpr int PH = ROWS / 2, PW = W / 2, PT = PH * PW;
        const int prow0 = rt * PH;
        for (int o = 0; o < 16; ++o) {
            __syncthreads();   // previous oc's max-reads done before scatter
            #pragma unroll
            for (int j = 0; j < NPX; ++j) if (val[j]) {
                int px = tid + j * 256;
                sx[px] = fmaxf(acc[j][o] * sc[o] + bi[o], 0.f);
            }
            __syncthreads();
            for (int e = tid; e < PT; e += 256) {
                int py = e / PW, pxl = e - py * PW;
                const float* r0 = sx + (2 * py) * W + 2 * pxl;
                float mv = fmaxf(fmaxf(r0[0], r0[1]), fmaxf(r0[W], r0[W + 1]));
                out[((size_t)(b * COUT + oc0 + o) * PHT + prow0 + py) * PW + pxl] = mv;
            }
        }
    }
}

// ---------- FAT attn: audio v10 (0..4095) + text v14 (4096..6143) + xgap ----------
__global__ void __launch_bounds__(256, 2) k_fat_attn(
    const float* __restrict__ x,
    const float* __restrict__ wq1, const float* __restrict__ bq1,
    const float* __restrict__ wk1, const float* __restrict__ bk1,
    const float* __restrict__ wv1, const float* __restrict__ bv1,
    const float* __restrict__ wq2, const float* __restrict__ bq2,
    const float* __restrict__ wk2, const float* __restrict__ bk2,
    const float* __restrict__ wv2, const float* __restrict__ bv2,
    float* __restrict__ afeat,
    const float* __restrict__ outsT,
    const float* __restrict__ wqt1, const float* __restrict__ bqt1,
    const float* __restrict__ wkt1, const float* __restrict__ bkt1,
    const float* __restrict__ wvt1, const float* __restrict__ bvt1,
    const float* __restrict__ wqt2, const float* __restrict__ bqt2,
    const float* __restrict__ wkt2, const float* __restrict__ bkt2,
    const float* __restrict__ wvt2, const float* __restrict__ bvt2,
    float* __restrict__ tfeat, float* __restrict__ xgap) {
    __shared__ float smem[7040];   // union: audio 2048+4608 | text 1280+5760
    const int bx = blockIdx.x;
    const int tid = threadIdx.x;

    if (bx >= 6144) {
        // ================= xgap path =================
        int b = bx - 6144;
        int wave = tid >> 6, lane = tid & 63;
        for (int c = wave; c < 96; c += 4) {
            const float* row = x + ((size_t)b * 96 + c) * 234;
            float s = 0.f;
            for (int p = lane; p < 234; p += 64) s += row[p];
            #pragma unroll
            for (int off = 1; off < 64; off <<= 1) s += __shfl_xor(s, off);
            if (lane == 0) xgap[b * 96 + c] = s * (1.f / 234.f);
        }
        return;
    }
    if (bx >= 4096) {
        // ================= text path (v14 body) =================
        int a = bx - 4096;
        const int b = a & 127;
        int rem = a >> 7;
        const int stage = rem & 1, n = rem >> 1;
        const float* wq = (stage ? wqt2 : wqt1) + n * 9600;
        const float* wk = (stage ? wkt2 : wkt1) + n * 9600;
        const float* wv = (stage ? wvt2 : wvt1) + n * 9600;
        const float* bqn = (stage ? bqt2 : bqt1) + n * 96;
        const float* bkn = (stage ? bkt2 : bkt1) + n * 96;
        const float* bvn = (stage ? bvt2 : bvt1) + n * 96;
        const int to = tid >> 4, tpg = tid & 15;
        const int ob = to * 6;
        const int tA = tpg * 4;
        float* sxc = smem;            // 1280 floats [20 c][64 t]
        float* sw = smem + 1280;      // 5760 floats [3 mats][20 c][96 o]
        float* sred = sw;             // epilogue overlay
        const float* xb = outsT + (size_t)b * (100 * kT);

        float qa[6][4], ka[6][4], va[6][4];
        #pragma unroll
        for (int j = 0; j < 6; ++j) {
            float bq_ = bqn[ob + j], bk_ = bkn[ob + j], bv_ = bvn[ob + j];
            #pragma unroll
            for (int i = 0; i < 4; ++i) { qa[j][i] = bq_; ka[j][i] = bk_; va[j][i] = bv_; }
        }
        for (int c0 = 0; c0 < 100; c0 += 20) {
            __syncthreads();
            for (int e = tid; e < 1280; e += 256) {
                int r = e >> 6, tt = e & 63;
                sxc[e] = (tt < kT) ? xb[(c0 + r) * kT + tt] : 0.f;
            }
            for (int e4 = tid; e4 < 1440; e4 += 256) {
                int mat = (e4 >= 960) ? 2 : (e4 >= 480 ? 1 : 0);
                int r4 = e4 - mat * 480;
                const float* wsrc = (mat == 0) ? wq : (mat == 1 ? wk : wv);
                *(float4*)(sw + mat * 1920 + r4 * 4) = *(const float4*)(wsrc + c0 * 96 + r4 * 4);
            }
            __syncthreads();
            #pragma unroll 4
            for (int cc = 0; cc < 20; ++cc) {
                float4 xa = *(const float4*)(sxc + cc * 64 + tA);
                const float* wr = sw + cc * 96 + ob;
                float2 q01 = *(const float2*)(wr);
                float2 q23 = *(const float2*)(wr + 2);
                float2 q45 = *(const float2*)(wr + 4);
                float2 k01 = *(const float2*)(wr + 1920);
                float2 k23 = *(const float2*)(wr + 1922);
                float2 k45 = *(const float2*)(wr + 1924);
                float2 v01 = *(const float2*)(wr + 3840);
                float2 v23 = *(const float2*)(wr + 3842);
                float2 v45 = *(const float2*)(wr + 3844);
                float wqv[6] = {q01.x, q01.y, q23.x, q23.y, q45.x, q45.y};
                float wkv[6] = {k01.x, k01.y, k23.x, k23.y, k45.x, k45.y};
                float wvv[6] = {v01.x, v01.y, v23.x, v23.y, v45.x, v45.y};
                #pragma unroll
                for (int j = 0; j < 6; ++j) {
                    qa[j][0] += wqv[j] * xa.x; qa[j][1] += wqv[j] * xa.y;
                    qa[j][2] += wqv[j] * xa.z; qa[j][3] += wqv[j] * xa.w;
                    ka[j][0] += wkv[j] * xa.x; ka[j][1] += wkv[j] * xa.y;
                    ka[j][2] += wkv[j] * xa.z; ka[j][3] += wkv[j] * xa.w;
                    va[j][0] += wvv[j] * xa.x; va[j][1] += wvv[j] * xa.y;
                    va[j][2] += wvv[j] * xa.z; va[j][3] += wvv[j] * xa.w;
                }
            }
        }
        float pmx[4] = {-1e30f, -1e30f, -1e30f, -1e30f};
        #pragma unroll
        for (int j = 0; j < 6; ++j)
            #pragma unroll
            for (int i = 0; i < 4; ++i) {
                float sv = qa[j][i] * ka[j][i];
                qa[j][i] = sv;
                pmx[i] = fmaxf(pmx[i], sv);
            }
        __syncthreads();
        #pragma unroll
        for (int i = 0; i < 4; ++i) sred[to * 64 + tA + i] = pmx[i];
        __syncthreads();
        float m_[4];
        #pragma unroll
        for (int i = 0; i < 4; ++i) {
            float mm = -1e30f;
            for (int t = 0; t < 16; ++t) mm = fmaxf(mm, sred[t * 64 + tA + i]);
            m_[i] = mm;
        }
        __syncthreads();
        float z[4] = {0.f, 0.f, 0.f, 0.f};
        #pragma unroll
        for (int j = 0; j < 6; ++j)
            #pragma unroll
            for (int i = 0; i < 4; ++i) {
                float e = __expf(qa[j][i] - m_[i]);
                qa[j][i] = e;
                z[i] += e;
            }
        #pragma unroll
        for (int i = 0; i < 4; ++i) sred[to * 64 + tA + i] = z[i];
        __syncthreads();
        float rz[4];
        #pragma unroll
        for (int i = 0; i < 4; ++i) {
            float zs = 0.f;
            for (int t = 0; t < 16; ++t) zs += sred[t * 64 + tA + i];
            rz[i] = (tA + i < kT) ? 1.f / zs : 0.f;
        }
        __syncthreads();
        #pragma unroll
        for (int j = 0; j < 6; ++j) {
            float po = qa[j][0] * rz[0] * va[j][0]
                     + qa[j][1] * rz[1] * va[j][1]
                     + qa[j][2] * rz[2] * va[j][2]
                     + qa[j][3] * rz[3] * va[j][3];
            sred[(ob + j) * 16 + tpg] = po;
        }
        __syncthreads();
        if (tid < 96) {
            float ssum = 0.f;
            #pragma unroll
            for (int t = 0; t < 16; ++t) ssum += sred[tid * 16 + t];
            tfeat[b * 1536 + stage * 768 + n * 96 + tid] = ssum;
        }
        return;
    }

    // ================= audio path (v10 body) =================
    const int a = bx;
    const int xp = a & 255;
    const int b = xp >> 1, pt = xp & 1;
    const int n = (a >> 8) & 7, stage = a >> 11;
    const float* wq = (stage ? wq2 : wq1) + n * 9216;
    const float* wk = (stage ? wk2 : wk1) + n * 9216;
    const float* wv = (stage ? wv2 : wv1) + n * 9216;
    const float* bqn = (stage ? bq2 : bq1) + n * 96;
    const float* bkn = (stage ? bk2 : bk1) + n * 96;
    const float* bvn = (stage ? bv2 : bv1) + n * 96;
    const int to = tid >> 4, tpg = tid & 15;
    const int ob = to * 6;
    const int pA = tpg * 4;
    const int p0 = pt * 128;

    float* sxc = smem;          // 2048 floats [16 c][128 p]
    float* sw = smem + 2048;    // 4608 floats [3 mats][16 c][96 o]
    float* sred = sw;           // epilogue overlay

    const float* xb = x + (size_t)b * (96 * 234) + p0;

    float qa[6][8], ka[6][8], va[6][8];
    #pragma unroll
    for (int j = 0; j < 6; ++j) {
        float bq_ = bqn[ob + j], bk_ = bkn[ob + j], bv_ = bvn[ob + j];
        #pragma unroll
        for (int i = 0; i < 8; ++i) { qa[j][i] = bq_; ka[j][i] = bk_; va[j][i] = bv_; }
    }

    for (int c0 = 0; c0 < 96; c0 += 16) {
        __syncthreads();
        {
            #pragma unroll
            for (int it = 0; it < 4; ++it) {
                int e2 = tid + it * 256;
                int r = e2 >> 6, c2 = (e2 & 63) * 2;
                float2 v = make_float2(0.f, 0.f);
                if (p0 + c2 < 234) v = *(const float2*)(xb + (c0 + r) * 234 + c2);
                *(float2*)(sxc + r * 128 + c2) = v;
            }
        }
        for (int e4 = tid; e4 < 1152; e4 += 256) {
            int mat = (e4 >= 768) ? 2 : (e4 >= 384 ? 1 : 0);
            int r4 = e4 - mat * 384;
            const float* wsrc = (mat == 0) ? wq : (mat == 1 ? wk : wv);
            *(float4*)(sw + mat * 1536 + r4 * 4) = *(const float4*)(wsrc + c0 * 96 + r4 * 4);
        }
        __syncthreads();
        #pragma unroll 2
        for (int cc = 0; cc < 16; ++cc) {
            float4 xa = *(const float4*)(sxc + cc * 128 + pA);
            float4 xc = *(const float4*)(sxc + cc * 128 + 64 + pA);
            const float* wr = sw + cc * 96 + ob;
            float2 q01 = *(const float2*)(wr);
            float2 q23 = *(const float2*)(wr + 2);
            float2 q45 = *(const float2*)(wr + 4);
            float2 k01 = *(const float2*)(wr + 1536);
            float2 k23 = *(const float2*)(wr + 1538);
            float2 k45 = *(const float2*)(wr + 1540);
            float2 v01 = *(const float2*)(wr + 3072);
            float2 v23 = *(const float2*)(wr + 3074);
            float2 v45 = *(const float2*)(wr + 3076);
            float wqv[6] = {q01.x, q01.y, q23.x, q23.y, q45.x, q45.y};
            float wkv[6] = {k01.x, k01.y, k23.x, k23.y, k45.x, k45.y};
            float wvv[6] = {v01.x, v01.y, v23.x, v23.y, v45.x, v45.y};
            #pragma unroll
            for (int j = 0; j < 6; ++j) {
                qa[j][0] += wqv[j] * xa.x; qa[j][1] += wqv[j] * xa.y;
                qa[j][2] += wqv[j] * xa.z; qa[j][3] += wqv[j] * xa.w;
                qa[j][4] += wqv[j] * xc.x; qa[j][5] += wqv[j] * xc.y;
                qa[j][6] += wqv[j] * xc.z; qa[j][7] += wqv[j] * xc.w;
                ka[j][0] += wkv[j] * xa.x; ka[j][1] += wkv[j] * xa.y;
                ka[j][2] += wkv[j] * xa.z; ka[j][3] += wkv[j] * xa.w;
                ka[j][4] += wkv[j] * xc.x; ka[j][5] += wkv[j] * xc.y;
                ka[j][6] += wkv[j] * xc.z; ka[j][7] += wkv[j] * xc.w;
                va[j][0] += wvv[j] * xa.x; va[j][1] += wvv[j] * xa.y;
                va[j][2] += wvv[j] * xa.z; va[j][3] += wvv[j] * xa.w;
                va[j][4] += wvv[j] * xc.x; va[j][5] += wvv[j] * xc.y;
                va[j][6] += wvv[j] * xc.z; va[j][7] += wvv[j] * xc.w;
            }
        }
    }

    int col[8];
    #pragma unroll
    for (int i = 0; i < 4; ++i) { col[i] = pA + i; col[4 + i] = 64 + pA + i; }

    float pmx[8];
    #pragma unroll
    for (int i = 0; i < 8; ++i) pmx[i] = -1e30f;
    #pragma unroll
    for (int j = 0; j < 6; ++j)
        #pragma unroll
        for (int i = 0; i < 8; ++i) {
            float sv = qa[j][i] * ka[j][i];
            qa[j][i] = sv;
            pmx[i] = fmaxf(pmx[i], sv);
        }
    __syncthreads();
    #pragma unroll
    for (int i = 0; i < 8; ++i) sred[to * 128 + col[i]] = pmx[i];
    __syncthreads();
    float m_[8];
    #pragma unroll
    for (int i = 0; i < 8; ++i) {
        float mm = -1e30f;
        for (int t = 0; t < 16; ++t) mm = fmaxf(mm, sred[t * 128 + col[i]]);
        m_[i] = mm;
    }
    __syncthreads();
    float z[8];
    #pragma unroll
    for (int i = 0; i < 8; ++i) z[i] = 0.f;
    #pragma unroll
    for (int j = 0; j < 6; ++j)
        #pragma unroll
        for (int i = 0; i < 8; ++i) {
            float e = __expf(qa[j][i] - m_[i]);
            qa[j][i] = e;
            z[i] += e;
        }
    #pragma unroll
    for (int i = 0; i < 8; ++i) sred[to * 128 + col[i]] = z[i];
    __syncthreads();
    float rz[8];
    #pragma unroll
    for (int i = 0; i < 8; ++i) {
        float zs = 0.f;
        for (int t = 0; t < 16; ++t) zs += sred[t * 128 + col[i]];
        rz[i] = (p0 + col[i] < 234) ? 1.f / zs : 0.f;
    }
    __syncthreads();
    #pragma unroll
    for (int j = 0; j < 6; ++j) {
        float po = 0.f;
        #pragma unroll
        for (int i = 0; i < 8; ++i) po += qa[j][i] * rz[i] * va[j][i];
        sred[(ob + j) * 16 + tpg] = po;
    }
    __syncthreads();
    if (tid < 96) {
        float ssum = 0.f;
        #pragma unroll
        for (int t = 0; t < 16; ++t) ssum += sred[tid * 16 + t];
        atomicAdd(afeat + b * 1536 + n * 192 + stage * 96 + tid, ssum * (1.f / 234.f));
    }
}

// ---------- cross-modal gated fusion + final logits ----------
__global__ void __launch_bounds__(128) k_final(const float* __restrict__ xgap,
    const float* __restrict__ outsT, const float* __restrict__ afeat,
    const float* __restrict__ tfeat,
    const float* __restrict__ w_fa, const float* __restrict__ b_fa,
    const float* __restrict__ w_ft, const float* __restrict__ b_ft,
    const float* __restrict__ w_e, const float* __restrict__ b_e,
    float* __restrict__ out) {
    int b = blockIdx.x; int tid = threadIdx.x;
    __shared__ float xg[96], hv[100], st[100], sa[96], aat[96], atba[100];
    __shared__ float redm[2], reds[2];
    if (tid < 96) xg[tid] = xgap[b * 96 + tid];
    if (tid < 100) hv[tid] = outsT[((size_t)b * 100 + tid) * kT + (kT - 1)];
    __syncthreads();
    if (tid < 100) {
        float acc = b_fa[tid];
        const float* wr = w_fa + tid * 96;
        for (int c = 0; c < 96; ++c) acc += wr[c] * xg[c];
        st[tid] = acc;
    }
    if (tid < 96) {
        float acc = b_ft[tid];
        const float* wr = w_ft + tid * 100;
        for (int c = 0; c < 100; ++c) acc += wr[c] * hv[c];
        sa[tid] = acc;
    }
    __syncthreads();
    if (tid == 0) {
        float mxv = -1e30f; for (int i = 0; i < 100; ++i) mxv = fmaxf(mxv, st[i]);
        float s = 0.f; for (int i = 0; i < 100; ++i) s += expf(st[i] - mxv);
        redm[0] = mxv; reds[0] = s;
    }
    if (tid == 1) {
        float mxv = -1e30f; for (int i = 0; i < 96; ++i) mxv = fmaxf(mxv, sa[i]);
        float s = 0.f; for (int i = 0; i < 96; ++i) s += expf(sa[i] - mxv);
        redm[1] = mxv; reds[1] = s;
    }
    __syncthreads();
    if (tid < 100) atba[tid] = expf(st[tid] - redm[0]) / reds[0] * hv[tid];
    if (tid < 96)  aat[tid]  = expf(sa[tid] - redm[1]) / reds[1] * xg[tid];
    __syncthreads();
    float a0 = 0.f, a1 = 0.f, a2 = 0.f, a3 = 0.f;
    for (int col = tid; col < 3268; col += 128) {
        float f;
        if (col < 1536)      f = afeat[b * 1536 + col];
        else if (col < 3072) f = tfeat[b * 1536 + col - 1536];
        else if (col < 3168) f = aat[col - 3072];
        else                 f = atba[col - 3168];
        a0 += w_e[col] * f;            a1 += w_e[3268 + col] * f;
        a2 += w_e[2 * 3268 + col] * f; a3 += w_e[3 * 3268 + col] * f;
    }
    __shared__ float r4[4][128];
    r4[0][tid] = a0; r4[1][tid] = a1; r4[2][tid] = a2; r4[3][tid] = a3;
    __syncthreads();
    if (tid < 4) {
        float s = 0.f;
        for (int i = 0; i < 128; ++i) s += r4[tid][i];
        out[b * 4 + tid] = s + b_e[tid];
    }
}

// =====================================================================
extern "C" void kernel_launch(void* const* d_in, const int* in_sizes, int n_in,
                              void* d_out, int out_size, void* d_ws, size_t ws_size,
                              hipStream_t stream) {
    (void)in_sizes; (void)n_in; (void)out_size; (void)ws_size;
    const float* mfcc_t = (const float*)d_in[0];
    const float* mfcc_f = (const float*)d_in[1];
    const float* mfcc_c = (const float*)d_in[2];
    const int*   tokens = (const int*)d_in[3];
    const float *w1a = (const float*)d_in[5],  *b1a = (const float*)d_in[6],
                *g1a = (const float*)d_in[7],  *be1a = (const float*)d_in[8],
                *m1a = (const float*)d_in[9],  *v1a = (const float*)d_in[10];
    const float *w1b = (const float*)d_in[11], *b1b = (const float*)d_in[12],
                *g1b = (const float*)d_in[13], *be1b = (const float*)d_in[14],
                *m1b = (const float*)d_in[15], *v1b = (const float*)d_in[16];
    const float *w2 = (const float*)d_in[17], *b2 = (const float*)d_in[18],
                *g2 = (const float*)d_in[19], *be2 = (const float*)d_in[20],
                *m2 = (const float*)d_in[21], *v2 = (const float*)d_in[22];
    const float *w3 = (const float*)d_in[23], *b3 = (const float*)d_in[24],
                *g3 = (const float*)d_in[25], *be3 = (const float*)d_in[26],
                *m3 = (const float*)d_in[27], *v3 = (const float*)d_in[28];
    const float *w4 = (const float*)d_in[29], *b4 = (const float*)d_in[30],
                *g4 = (const float*)d_in[31], *be4 = (const float*)d_in[32],
                *m4 = (const float*)d_in[33], *v4 = (const float*)d_in[34];
    const float *wq_a1 = (const float*)d_in[35], *bq_a1 = (const float*)d_in[36],
                *wk_a1 = (const float*)d_in[37], *bk_a1 = (const float*)d_in[38],
                *wv_a1 = (const float*)d_in[39], *bv_a1 = (const float*)d_in[40];
    const float *wq_a2 = (const float*)d_in[41], *bq_a2 = (const float*)d_in[42],
                *wk_a2 = (const float*)d_in[43], *bk_a2 = (const float*)d_in[44],
                *wv_a2 = (const float*)d_in[45], *bv_a2 = (const float*)d_in[46];
    const float *emb  = (const float*)d_in[47];
    const float *w_ih = (const float*)d_in[48], *w_hh = (const float*)d_in[49],
                *b_ih = (const float*)d_in[50], *b_hh = (const float*)d_in[51];
    const float *wq_t1 = (const float*)d_in[52], *bq_t1 = (const float*)d_in[53],
                *wk_t1 = (const float*)d_in[54], *bk_t1 = (const float*)d_in[55],
                *wv_t1 = (const float*)d_in[56], *bv_t1 = (const float*)d_in[57];
    const float *wq_t2 = (const float*)d_in[58], *bq_t2 = (const float*)d_in[59],
                *wk_t2 = (const float*)d_in[60], *bk_t2 = (const float*)d_in[61],
                *wv_t2 = (const float*)d_in[62], *bv_t2 = (const float*)d_in[63];
    const float *w_fa = (const float*)d_in[64], *b_fa = (const float*)d_in[65],
                *w_ft = (const float*)d_in[66], *b_ft = (const float*)d_in[67],
                *w_e  = (const float*)d_in[68], *b_e  = (const float*)d_in[69];

    float* ws = (float*)d_ws;
    const size_t Z0 = 0;                 // GI -> P2 -> X4
    const size_t Z1 = 22091776ull;       // x1 -> P3
    const size_t OUTS  = 34072576ull;    // outs_T[b][c][t]
    const size_t AFEAT = 34712576ull;
    const size_t TFEAT = 34909184ull;    // conv-wT (early) then text features
    const size_t XGAP  = 35105792ull;
    const size_t WT    = 35118080ull;
    float* GI = ws + Z0;                 // dead after fat_stem_gru
    float* X1 = ws + Z1;
    float* P2 = ws + Z0;                 // fused conv2 output (overwrites GI)
    float* P3 = ws + Z1;                 // fused conv3 output (overwrites X1)
    float* X4 = ws + Z0;                 // conv4 output (overwrites P2)
    float* outsT = ws + OUTS;
    float* afeat = ws + AFEAT;
    float* tfeat = ws + TFEAT;
    float* xgap  = ws + XGAP;
    // audio transposed weights [n][c][o], 73728 floats each
    float* wqa1t = ws + WT;
    float* wka1t = wqa1t + 73728; float* wva1t = wka1t + 73728;
    float* wqa2t = wva1t + 73728; float* wka2t = wqa2t + 73728; float* wva2t = wka2t + 73728;
    // text transposed weights [n][c][o], 76800 floats each
    float* wqt1t = wva2t + 73728;
    float* wkt1t = wqt1t + 76800; float* wvt1t = wkt1t + 76800;
    float* wqt2t = wvt1t + 76800; float* wkt2t = wqt2t + 76800; float* wvt2t = wkt2t + 76800;
    // conv weight transposes parked in the tfeat region (dead until fat_attn;
    // convs consume them before the text path writes tfeat)
    float* wT2 = tfeat;           //  6,912
    float* wT3 = tfeat + 6912;    // 18,432
    float* wT4 = tfeat + 25344;   // 55,296

    // ----- all weight transposes + afeat zero-fill in ONE launch -----
    TPack tp;
    tp.d[0]  = {wq_a1, wqa1t, 96, 96, 73728};
    tp.d[1]  = {wk_a1, wka1t, 96, 96, 73728};
    tp.d[2]  = {wv_a1, wva1t, 96, 96, 73728};
    tp.d[3]  = {wq_a2, wqa2t, 96, 96, 73728};
    tp.d[4]  = {wk_a2, wka2t, 96, 96, 73728};
    tp.d[5]  = {wv_a2, wva2t, 96, 96, 73728};
    tp.d[6]  = {w2, wT2, 32, 216, 6912};
    tp.d[7]  = {w3, wT3, 64, 288, 18432};
    tp.d[8]  = {w4, wT4, 96, 576, 55296};
    tp.d[9]  = {wq_t1, wqt1t, 96, 100, 76800};
    tp.d[10] = {wk_t1, wkt1t, 96, 100, 76800};
    tp.d[11] = {wv_t1, wvt1t, 96, 100, 76800};
    tp.d[12] = {wq_t2, wqt2t, 96, 100, 76800};
    tp.d[13] = {wk_t2, wkt2t, 96, 100, 76800};
    tp.d[14] = {wv_t2, wvt2t, 96, 100, 76800};
    k_transpose_pack<<<dim3(300, 16), 256, 0, stream>>>(tp, afeat);

    // ----- text-branch input GEMM (GI at Z0, dead after gru) -----
    k_gi<<<kB * kT / 8, 320, 0, stream>>>(tokens, emb, w_ih, b_ih, GI);

    // ----- FAT: gru (128 blocks) + stem v2 (5850 blocks, 8 ch/thread) -----
    k_fat_stem_gru<<<5978, 256, 0, stream>>>(mfcc_t, mfcc_f, mfcc_c,
        w1a, b1a, g1a, be1a, m1a, v1a,
        w1b, b1b, g1b, be1b, m1b, v1b, X1, 1497600,
        GI, w_hh, b_hh, outsT);

    // ----- conv chain v2: 16-oc blocks, pools fused into conv2/conv3 -----
    k_conv16<24, 8, 25, 156, 8, 5, true><<<dim3(128, 3, 2), 256, 0, stream>>>(
        X1, wT2, b2, g2, be2, m2, v2, P2, 32, 12);
    k_conv16<32, 8, 12, 78, 12, 4, true><<<dim3(128, 1, 4), 256, 0, stream>>>(
        P2, wT3, b3, g3, be3, m3, v3, P3, 64, 6);
    k_conv16<64, 16, 6, 39, 6, 1, false><<<dim3(128, 1, 6), 256, 0, stream>>>(
        P3, wT4, b4, g4, be4, m4, v4, X4, 96, 0);

    // ----- FAT attn: audio (first) + text + xgap -----
    k_fat_attn<<<6272, 256, 0, stream>>>(X4,
        wqa1t, bq_a1, wka1t, bk_a1, wva1t, bv_a1,
        wqa2t, bq_a2, wka2t, bk_a2, wva2t, bv_a2, afeat,
        outsT,
        wqt1t, bq_t1, wkt1t, bk_t1, wvt1t, bv_t1,
        wqt2t, bq_t2, wkt2t, bk_t2, wvt2t, bv_t2, tfeat, xgap);

    // ----- fusion + logits -----
    k_final<<<kB, 128, 0, stream>>>(xgap, outsT, afeat, tfeat,
                                    w_fa, b_fa, w_ft, b_ft, w_e, b_e, (float*)d_out);
}